// Round 1
// baseline (354.073 us; speedup 1.0000x reference)
//
#include <hip/hip_runtime.h>
#include <math.h>

// Problem constants
#define B_  512
#define C_  64
#define T_  512
#define H_  128
#define N_  (B_*C_)   // 32768

// Workspace byte offsets (total 34,144,256 bytes)
#define OFF_SIMF64   0u                       // 4096 * 8 = 32768
#define OFF_M        32768u                   // 4096 * 4 = 16384
#define OFF_SS1      49152u                   // 256 * 4
#define OFF_SS2      50176u
#define OFF_SS3      51200u
#define OFF_BNPART   52224u                   // 512*256*4 = 524288 -> ends 576512
#define OFF_REGA     589824u                  // 16MB region: simpart (8MB), later Z2
#define OFF_REGB     (589824u + 16777216u)    // 16MB region: Z1 / Z3

// ---------------------------------------------------------------------------
// Kernel 1: per-batch channel-gram partials, scaled by per-row inverse norms.
// grid 512 (one batch), 256 threads as 16x16, each owns a 4x4 (c,d) tile.
// simpart[b][c*64+d] = dot(x[b,c],x[b,d]) / (||x[b,c]|| * ||x[b,d]||)  (f32)
// ---------------------------------------------------------------------------
__global__ __launch_bounds__(256) void k_simpart(const float* __restrict__ x,
                                                 float* __restrict__ simpart)
{
    __shared__ float  shX[64 * 133];
    __shared__ double rn[64];
    const int b  = blockIdx.x;
    const int t  = threadIdx.x;
    const int ti = t >> 4, tj = t & 15;

    double D[4][4];
#pragma unroll
    for (int q = 0; q < 4; ++q)
#pragma unroll
        for (int p = 0; p < 4; ++p) D[q][p] = 0.0;

    const float* xb = x + (size_t)b * (C_ * T_);

    for (int ch = 0; ch < 4; ++ch) {
        // stage x[b][c][128*ch + kk] ; lanes -> kk (coalesced, conflict-free)
        for (int i = t; i < 64 * 128; i += 256) {
            int kk = i & 127, c = i >> 7;
            shX[c * 133 + kk] = xb[c * T_ + ch * 128 + kk];
        }
        __syncthreads();

        float Cc[4][4];
#pragma unroll
        for (int q = 0; q < 4; ++q)
#pragma unroll
            for (int p = 0; p < 4; ++p) Cc[q][p] = 0.f;

#pragma unroll 2
        for (int kk = 0; kk < 128; ++kk) {
            float a[4], bb[4];
#pragma unroll
            for (int q = 0; q < 4; ++q) a[q]  = shX[(4 * ti + q) * 133 + kk];
#pragma unroll
            for (int p = 0; p < 4; ++p) bb[p] = shX[(4 * tj + p) * 133 + kk];
#pragma unroll
            for (int q = 0; q < 4; ++q)
#pragma unroll
                for (int p = 0; p < 4; ++p)
                    Cc[q][p] = fmaf(a[q], bb[p], Cc[q][p]);
        }
#pragma unroll
        for (int q = 0; q < 4; ++q)
#pragma unroll
            for (int p = 0; p < 4; ++p) D[q][p] += (double)Cc[q][p];
        __syncthreads();
    }

    // diagonal threads publish inverse norms
    if (ti == tj) {
#pragma unroll
        for (int q = 0; q < 4; ++q)
            rn[4 * ti + q] = 1.0 / fmax(sqrt(D[q][q]), 1e-12);
    }
    __syncthreads();

    float* sp = simpart + (size_t)b * 4096;
#pragma unroll
    for (int q = 0; q < 4; ++q) {
        float4 v;
        v.x = (float)(D[q][0] * rn[4 * ti + q] * rn[4 * tj + 0]);
        v.y = (float)(D[q][1] * rn[4 * ti + q] * rn[4 * tj + 1]);
        v.z = (float)(D[q][2] * rn[4 * ti + q] * rn[4 * tj + 2]);
        v.w = (float)(D[q][3] * rn[4 * ti + q] * rn[4 * tj + 3]);
        *(float4*)&sp[(4 * ti + q) * 64 + 4 * tj] = v;
    }
}

// ---------------------------------------------------------------------------
// Kernel 2: deterministic f64 reduction over batches -> sim (4096 doubles)
// ---------------------------------------------------------------------------
__global__ __launch_bounds__(256) void k_simreduce(const float* __restrict__ simpart,
                                                   double* __restrict__ simf64)
{
    int e = blockIdx.x * 256 + threadIdx.x;   // 16 blocks * 256 = 4096
    double s = 0.0;
    for (int b = 0; b < B_; ++b) s += (double)simpart[(size_t)b * 4096 + e];
    simf64[e] = s * (1.0 / 512.0);
}

// ---------------------------------------------------------------------------
// Kernel 3: top-K per row, degrees, and the dense 64x64 mixing matrix M.
// M[d][c] = ([d in nbr(c)] + [d==c]) * dinv[c] * dinv[d]
// ---------------------------------------------------------------------------
__global__ __launch_bounds__(256) void k_graph(const double* __restrict__ simf64,
                                               float* __restrict__ Mout)
{
    __shared__ double sd[64 * 65];            // pad 65 to avoid bank conflicts
    __shared__ unsigned long long nbrm[64];
    __shared__ int   degS[64];
    __shared__ float dv[64];
    const int t = threadIdx.x;

    if (t < 64) degS[t] = 1;                  // self-loop
    for (int i = t; i < 4096; i += 256)
        sd[(i >> 6) * 65 + (i & 63)] = simf64[i];
    __syncthreads();

    if (t < 64) {
        unsigned long long chosen = 0ull;
        for (int k = 0; k < 16; ++k) {
            double best = -1e300; int bi = 0;
            for (int d = 0; d < 64; ++d) {
                if ((chosen >> d) & 1ull) continue;
                double v = sd[t * 65 + d];
                if (v > best) { best = v; bi = d; }   // strict > : lowest index wins ties
            }
            chosen |= (1ull << bi);
        }
        nbrm[t] = chosen;
    }
    __syncthreads();
    if (t < 64) {
        unsigned long long chosen = nbrm[t];
        while (chosen) {
            int d = (int)__builtin_ctzll(chosen);
            atomicAdd(&degS[d], 1);
            chosen &= chosen - 1;
        }
    }
    __syncthreads();
    if (t < 64) dv[t] = 1.0f / sqrtf((float)degS[t]);
    __syncthreads();

    for (int e = t; e < 4096; e += 256) {
        int d = e >> 6, c = e & 63;
        float w = (float)((int)((nbrm[c] >> d) & 1ull) + (d == c ? 1 : 0));
        Mout[e] = w * dv[c] * dv[d];
    }
}

// ---------------------------------------------------------------------------
// Shared GCN epilogue: Y(64x128 in regs) -> Z = M@Y + bias ; BN partial sums ;
// Z written to global. shA/shB are the GEMM's LDS buffers (reused).
// ---------------------------------------------------------------------------
__device__ __forceinline__ void gcn_epilogue(int b, int t, float acc[4][8],
    const float* __restrict__ M, const float* __restrict__ bias,
    float* shA, float* shB,
    float* __restrict__ Zout, float* __restrict__ bnpart)
{
    const int tr = t >> 4, tc = t & 15;

    // Y -> shB [c][f], stride 132
#pragma unroll
    for (int q = 0; q < 4; ++q) {
        *(float4*)&shB[(4 * tr + q) * 132 + 8 * tc] =
            make_float4(acc[q][0], acc[q][1], acc[q][2], acc[q][3]);
        *(float4*)&shB[(4 * tr + q) * 132 + 8 * tc + 4] =
            make_float4(acc[q][4], acc[q][5], acc[q][6], acc[q][7]);
    }
    // M -> shA, stride 65 (conflict-free strided reads later)
    for (int i = t; i < 4096; i += 256) shA[(i >> 6) * 65 + (i & 63)] = M[i];
    __syncthreads();

    float z[4][8];
#pragma unroll
    for (int u = 0; u < 8; ++u) {
        float bv = bias[8 * tc + u];
#pragma unroll
        for (int q = 0; q < 4; ++q) z[q][u] = bv;
    }
    for (int c = 0; c < 64; ++c) {
        float4 ya = *(const float4*)&shB[c * 132 + 8 * tc];
        float4 yb = *(const float4*)&shB[c * 132 + 8 * tc + 4];
        float y[8] = {ya.x, ya.y, ya.z, ya.w, yb.x, yb.y, yb.z, yb.w};
#pragma unroll
        for (int q = 0; q < 4; ++q) {
            float mv = shA[(4 * tr + q) * 65 + c];
#pragma unroll
            for (int u = 0; u < 8; ++u) z[q][u] = fmaf(mv, y[u], z[q][u]);
        }
    }
    __syncthreads();   // all threads done reading Y before overwriting shB

    // BN partials: sums at shB[tr][f], squares at shB[16+tr][f]
#pragma unroll
    for (int u = 0; u < 8; ++u) {
        float s = 0.f, s2 = 0.f;
#pragma unroll
        for (int q = 0; q < 4; ++q) { s += z[q][u]; s2 += z[q][u] * z[q][u]; }
        shB[tr * 132 + 8 * tc + u]        = s;
        shB[(16 + tr) * 132 + 8 * tc + u] = s2;
    }
    __syncthreads();
    if (t < 128) {
        float s = 0.f, s2 = 0.f;
#pragma unroll
        for (int g = 0; g < 16; ++g) {
            s  += shB[g * 132 + t];
            s2 += shB[(16 + g) * 132 + t];
        }
        bnpart[b * 256 + t]       = s;
        bnpart[b * 256 + 128 + t] = s2;
    }

#pragma unroll
    for (int q = 0; q < 4; ++q) {
        size_t o = ((size_t)(b * 64 + 4 * tr + q)) * 128 + 8 * tc;
        *(float4*)&Zout[o]     = make_float4(z[q][0], z[q][1], z[q][2], z[q][3]);
        *(float4*)&Zout[o + 4] = make_float4(z[q][4], z[q][5], z[q][6], z[q][7]);
    }
}

// ---------------------------------------------------------------------------
// Layer 1 GEMM: A = permuted view of x  (A[r][64m+kk] = x[b][kk][8r+m]),
// W1 (512x128). One block per batch; 256 threads; acc 4x8 per thread.
// ---------------------------------------------------------------------------
__global__ __launch_bounds__(256) void k_gemm1(const float* __restrict__ x,
    const float* __restrict__ W, const float* __restrict__ bias,
    const float* __restrict__ M, float* __restrict__ Zout, float* __restrict__ bnpart)
{
    __shared__ float shA[64 * 68];    // Ast[kk][r], stride 68 (16B-aligned rows)
    __shared__ float shB[64 * 132];   // Ws[kk][f],  stride 132
    const int b = blockIdx.x;
    const int t = threadIdx.x;
    const int tr = t >> 4, tc = t & 15;

    float acc[4][8];
#pragma unroll
    for (int q = 0; q < 4; ++q)
#pragma unroll
        for (int u = 0; u < 8; ++u) acc[q][u] = 0.f;

    const float* xb = x + (size_t)b * (C_ * T_);

    for (int m = 0; m < 8; ++m) {
        for (int i = t; i < 4096; i += 256) {       // A chunk: lanes -> r
            int r = i & 63, kk = i >> 6;
            shA[kk * 68 + r] = xb[kk * T_ + 8 * r + m];
        }
        for (int i = t; i < 8192; i += 256) {       // W chunk: lanes -> f (coalesced)
            int f = i & 127, kk = i >> 7;
            shB[kk * 132 + f] = W[(64 * m + kk) * H_ + f];
        }
        __syncthreads();
#pragma unroll 4
        for (int kk = 0; kk < 64; ++kk) {
            const float4 av  = *(const float4*)&shA[kk * 68 + 4 * tr];
            const float4 bv0 = *(const float4*)&shB[kk * 132 + 8 * tc];
            const float4 bv1 = *(const float4*)&shB[kk * 132 + 8 * tc + 4];
            const float a[4]  = {av.x, av.y, av.z, av.w};
            const float bb[8] = {bv0.x, bv0.y, bv0.z, bv0.w, bv1.x, bv1.y, bv1.z, bv1.w};
#pragma unroll
            for (int q = 0; q < 4; ++q)
#pragma unroll
                for (int u = 0; u < 8; ++u)
                    acc[q][u] = fmaf(a[q], bb[u], acc[q][u]);
        }
        __syncthreads();
    }
    gcn_epilogue(b, t, acc, M, bias, shA, shB, Zout, bnpart);
}

// ---------------------------------------------------------------------------
// Layers 2/3 GEMM: A = relu(Zin*scale + shift) (BN folded into staging),
// W (128x128). Row-major A in LDS; scalar A-reads (conflict-free).
// ---------------------------------------------------------------------------
__global__ __launch_bounds__(256) void k_gemm23(const float* __restrict__ Zin,
    const float* __restrict__ ss,   /* scale[128] then shift[128] */
    const float* __restrict__ W, const float* __restrict__ bias,
    const float* __restrict__ M, float* __restrict__ Zout, float* __restrict__ bnpart)
{
    __shared__ float shA[64 * 68];    // As[r][kk], stride 68
    __shared__ float shB[64 * 132];   // Ws[kk][f], stride 132
    const int b = blockIdx.x;
    const int t = threadIdx.x;
    const int tr = t >> 4, tc = t & 15;

    float acc[4][8];
#pragma unroll
    for (int q = 0; q < 4; ++q)
#pragma unroll
        for (int u = 0; u < 8; ++u) acc[q][u] = 0.f;

    for (int m = 0; m < 2; ++m) {
        for (int i = t; i < 4096; i += 256) {       // lanes -> kk (coalesced global)
            int kk = i & 63, r = i >> 6;
            int f = 64 * m + kk;
            float v = Zin[((size_t)(b * 64 + r)) * 128 + f];
            v = fmaxf(fmaf(v, ss[f], ss[128 + f]), 0.f);
            shA[r * 68 + kk] = v;
        }
        for (int i = t; i < 8192; i += 256) {
            int f = i & 127, kk = i >> 7;
            shB[kk * 132 + f] = W[(64 * m + kk) * H_ + f];
        }
        __syncthreads();
#pragma unroll 4
        for (int kk = 0; kk < 64; ++kk) {
            float a[4];
#pragma unroll
            for (int q = 0; q < 4; ++q) a[q] = shA[(4 * tr + q) * 68 + kk];
            const float4 bv0 = *(const float4*)&shB[kk * 132 + 8 * tc];
            const float4 bv1 = *(const float4*)&shB[kk * 132 + 8 * tc + 4];
            const float bb[8] = {bv0.x, bv0.y, bv0.z, bv0.w, bv1.x, bv1.y, bv1.z, bv1.w};
#pragma unroll
            for (int q = 0; q < 4; ++q)
#pragma unroll
                for (int u = 0; u < 8; ++u)
                    acc[q][u] = fmaf(a[q], bb[u], acc[q][u]);
        }
        __syncthreads();
    }
    gcn_epilogue(b, t, acc, M, bias, shA, shB, Zout, bnpart);
}

// ---------------------------------------------------------------------------
// BN finalize: reduce 512 block partials (f64), emit scale/shift per feature.
// ---------------------------------------------------------------------------
__global__ __launch_bounds__(256) void k_bnfin(const float* __restrict__ bnpart,
    const float* __restrict__ g, const float* __restrict__ be, float* __restrict__ ss)
{
    __shared__ double sums[256];
    const int t = threadIdx.x;
    double a = 0.0;
    for (int blk = 0; blk < 512; ++blk) a += (double)bnpart[blk * 256 + t];
    sums[t] = a;
    __syncthreads();
    if (t < 128) {
        double s = sums[t], s2 = sums[128 + t];
        double mean = s * (1.0 / 32768.0);
        double var  = s2 * (1.0 / 32768.0) - mean * mean;
        double rstd = 1.0 / sqrt(var + 1e-5);
        float sc = (float)((double)g[t] * rstd);
        ss[t]       = sc;
        ss[128 + t] = (float)((double)be[t] - mean * (double)sc);
    }
}

// ---------------------------------------------------------------------------
// Final BN + ReLU elementwise -> d_out
// ---------------------------------------------------------------------------
__global__ __launch_bounds__(256) void k_out(const float* __restrict__ Z,
    const float* __restrict__ ss, float* __restrict__ out)
{
    int i = blockIdx.x * 256 + threadIdx.x;    // float4 index; 1,048,576 total
    int f4 = i & 31;                            // ((4i)&127)>>2
    float4 z  = ((const float4*)Z)[i];
    float4 sc = ((const float4*)ss)[f4];
    float4 sh = ((const float4*)(ss + 128))[f4];
    float4 o;
    o.x = fmaxf(fmaf(z.x, sc.x, sh.x), 0.f);
    o.y = fmaxf(fmaf(z.y, sc.y, sh.y), 0.f);
    o.z = fmaxf(fmaf(z.z, sc.z, sh.z), 0.f);
    o.w = fmaxf(fmaf(z.w, sc.w, sh.w), 0.f);
    ((float4*)out)[i] = o;
}

// ---------------------------------------------------------------------------
extern "C" void kernel_launch(void* const* d_in, const int* in_sizes, int n_in,
                              void* d_out, int out_size, void* d_ws, size_t ws_size,
                              hipStream_t stream)
{
    (void)in_sizes; (void)n_in; (void)out_size; (void)ws_size;

    const float* x   = (const float*)d_in[0];
    const float* W1  = (const float*)d_in[9];
    const float* b1  = (const float*)d_in[10];
    const float* g1  = (const float*)d_in[11];
    const float* be1 = (const float*)d_in[12];
    const float* W2  = (const float*)d_in[13];
    const float* b2  = (const float*)d_in[14];
    const float* g2  = (const float*)d_in[15];
    const float* be2 = (const float*)d_in[16];
    const float* W3  = (const float*)d_in[17];
    const float* b3  = (const float*)d_in[18];
    const float* g3  = (const float*)d_in[19];
    const float* be3 = (const float*)d_in[20];

    char* ws = (char*)d_ws;
    double* simf64 = (double*)(ws + OFF_SIMF64);
    float*  Mmat   = (float*)(ws + OFF_M);
    float*  ss1    = (float*)(ws + OFF_SS1);
    float*  ss2    = (float*)(ws + OFF_SS2);
    float*  ss3    = (float*)(ws + OFF_SS3);
    float*  bnpart = (float*)(ws + OFF_BNPART);
    float*  regA   = (float*)(ws + OFF_REGA);   // simpart, later Z2
    float*  regB   = (float*)(ws + OFF_REGB);   // Z1, later Z3
    float*  out    = (float*)d_out;

    k_simpart<<<dim3(512), dim3(256), 0, stream>>>(x, regA);
    k_simreduce<<<dim3(16), dim3(256), 0, stream>>>(regA, simf64);
    k_graph<<<dim3(1), dim3(256), 0, stream>>>(simf64, Mmat);

    k_gemm1<<<dim3(512), dim3(256), 0, stream>>>(x, W1, b1, Mmat, regB, bnpart);
    k_bnfin<<<dim3(1), dim3(256), 0, stream>>>(bnpart, g1, be1, ss1);

    k_gemm23<<<dim3(512), dim3(256), 0, stream>>>(regB, ss1, W2, b2, Mmat, regA, bnpart);
    k_bnfin<<<dim3(1), dim3(256), 0, stream>>>(bnpart, g2, be2, ss2);

    k_gemm23<<<dim3(512), dim3(256), 0, stream>>>(regA, ss2, W3, b3, Mmat, regB, bnpart);
    k_bnfin<<<dim3(1), dim3(256), 0, stream>>>(bnpart, g3, be3, ss3);

    k_out<<<dim3(4096), dim3(256), 0, stream>>>(regB, ss3, out);
}

// Round 2
// 231.012 us; speedup vs baseline: 1.5327x; 1.5327x over previous
//
#include <hip/hip_runtime.h>
#include <math.h>

// Problem constants
#define B_  512
#define C_  64
#define T_  512
#define H_  128
#define N_  (B_*C_)   // 32768

typedef unsigned int   uint_;
typedef unsigned short ushort_;

typedef __attribute__((ext_vector_type(8))) short bf8v;   // 8 bf16 (4 VGPRs)
typedef __attribute__((ext_vector_type(4))) float f4v;    // MFMA accumulator

// Workspace byte offsets (total ~24.7 MB)
#define OFF_SIMP   0u            // 512*4096*4 = 8,388,608 ; reused as Z2 later
#define OFF_Z2     0u
#define OFF_Z1     8388608u      // 8,388,608 (bf16 32768x128)
#define OFF_Z3     16777216u     // 8,388,608
#define OFF_WT1    25165824u     // 128*512*2 = 131,072
#define OFF_WT2    25296896u     // 32,768
#define OFF_WT3    25329664u     // 32,768
#define OFF_SIMF64 25362432u     // 32,768
#define OFF_MB     25395200u     // 8,192
#define OFF_SS1    25403392u
#define OFF_SS2    25404416u
#define OFF_SS3    25405440u
#define OFF_BNPART 25406464u     // 524,288 -> end 25,930,752

__device__ __forceinline__ ushort_ f2bf(float f) {
    uint_ u = __float_as_uint(f);
    u = (u + 0x7FFFu + ((u >> 16) & 1u)) >> 16;    // RNE (finite values only)
    return (ushort_)u;
}
__device__ __forceinline__ float bf2f(ushort_ s) {
    return __uint_as_float(((uint_)s) << 16);
}

// ---------------------------------------------------------------------------
// Kernel 1: per-batch channel-gram partials scaled by inverse norms (f32/f64).
// UNCHANGED from round 1 (top-k numerics must stay exact).
// ---------------------------------------------------------------------------
__global__ __launch_bounds__(256) void k_simpart(const float* __restrict__ x,
                                                 float* __restrict__ simpart)
{
    __shared__ float  shX[64 * 133];
    __shared__ double rn[64];
    const int b  = blockIdx.x;
    const int t  = threadIdx.x;
    const int ti = t >> 4, tj = t & 15;

    double D[4][4];
#pragma unroll
    for (int q = 0; q < 4; ++q)
#pragma unroll
        for (int p = 0; p < 4; ++p) D[q][p] = 0.0;

    const float* xb = x + (size_t)b * (C_ * T_);

    for (int ch = 0; ch < 4; ++ch) {
        for (int i = t; i < 64 * 128; i += 256) {
            int kk = i & 127, c = i >> 7;
            shX[c * 133 + kk] = xb[c * T_ + ch * 128 + kk];
        }
        __syncthreads();

        float Cc[4][4];
#pragma unroll
        for (int q = 0; q < 4; ++q)
#pragma unroll
            for (int p = 0; p < 4; ++p) Cc[q][p] = 0.f;

#pragma unroll 2
        for (int kk = 0; kk < 128; ++kk) {
            float a[4], bb[4];
#pragma unroll
            for (int q = 0; q < 4; ++q) a[q]  = shX[(4 * ti + q) * 133 + kk];
#pragma unroll
            for (int p = 0; p < 4; ++p) bb[p] = shX[(4 * tj + p) * 133 + kk];
#pragma unroll
            for (int q = 0; q < 4; ++q)
#pragma unroll
                for (int p = 0; p < 4; ++p)
                    Cc[q][p] = fmaf(a[q], bb[p], Cc[q][p]);
        }
#pragma unroll
        for (int q = 0; q < 4; ++q)
#pragma unroll
            for (int p = 0; p < 4; ++p) D[q][p] += (double)Cc[q][p];
        __syncthreads();
    }

    if (ti == tj) {
#pragma unroll
        for (int q = 0; q < 4; ++q)
            rn[4 * ti + q] = 1.0 / fmax(sqrt(D[q][q]), 1e-12);
    }
    __syncthreads();

    float* sp = simpart + (size_t)b * 4096;
#pragma unroll
    for (int q = 0; q < 4; ++q) {
        float4 v;
        v.x = (float)(D[q][0] * rn[4 * ti + q] * rn[4 * tj + 0]);
        v.y = (float)(D[q][1] * rn[4 * ti + q] * rn[4 * tj + 1]);
        v.z = (float)(D[q][2] * rn[4 * ti + q] * rn[4 * tj + 2]);
        v.w = (float)(D[q][3] * rn[4 * ti + q] * rn[4 * tj + 3]);
        *(float4*)&sp[(4 * ti + q) * 64 + 4 * tj] = v;
    }
}

// ---------------------------------------------------------------------------
// Kernel 2: deterministic f64 reduction over batches
// ---------------------------------------------------------------------------
__global__ __launch_bounds__(256) void k_simreduce(const float* __restrict__ simpart,
                                                   double* __restrict__ simf64)
{
    int e = blockIdx.x * 256 + threadIdx.x;
    double s = 0.0;
    for (int b = 0; b < B_; ++b) s += (double)simpart[(size_t)b * 4096 + e];
    simf64[e] = s * (1.0 / 512.0);
}

// ---------------------------------------------------------------------------
// Kernel 3: top-K, degrees, mixing matrix M -> bf16 Mb[d][c]
// ---------------------------------------------------------------------------
__global__ __launch_bounds__(256) void k_graph(const double* __restrict__ simf64,
                                               ushort_* __restrict__ Mbout)
{
    __shared__ double sd[64 * 65];
    __shared__ unsigned long long nbrm[64];
    __shared__ int   degS[64];
    __shared__ float dv[64];
    const int t = threadIdx.x;

    if (t < 64) degS[t] = 1;
    for (int i = t; i < 4096; i += 256)
        sd[(i >> 6) * 65 + (i & 63)] = simf64[i];
    __syncthreads();

    if (t < 64) {
        unsigned long long chosen = 0ull;
        for (int k = 0; k < 16; ++k) {
            double best = -1e300; int bi = 0;
            for (int d = 0; d < 64; ++d) {
                if ((chosen >> d) & 1ull) continue;
                double v = sd[t * 65 + d];
                if (v > best) { best = v; bi = d; }
            }
            chosen |= (1ull << bi);
        }
        nbrm[t] = chosen;
    }
    __syncthreads();
    if (t < 64) {
        unsigned long long chosen = nbrm[t];
        while (chosen) {
            int d = (int)__builtin_ctzll(chosen);
            atomicAdd(&degS[d], 1);
            chosen &= chosen - 1;
        }
    }
    __syncthreads();
    if (t < 64) dv[t] = 1.0f / sqrtf((float)degS[t]);
    __syncthreads();

    for (int e = t; e < 4096; e += 256) {
        int d = e >> 6, c = e & 63;
        float w = (float)((int)((nbrm[c] >> d) & 1ull) + (d == c ? 1 : 0));
        Mbout[e] = f2bf(w * dv[c] * dv[d]);   // Mb[d*64+c]
    }
}

// ---------------------------------------------------------------------------
// Weight prep: bf16 transposed weights.
//   blocks 0-7 : Wt1p[f][kappa], kappa = c*8+m  <- W1[64m+c][f]   (permuted K)
//   blocks 8-9 : Wt2[f][k] <- W2[k][f]
//   blocks 10-11: Wt3[f][k] <- W3[k][f]
// ---------------------------------------------------------------------------
__global__ __launch_bounds__(256) void k_prepw(const float* __restrict__ W1,
    const float* __restrict__ W2, const float* __restrict__ W3,
    ushort_* __restrict__ Wt1, ushort_* __restrict__ Wt2, ushort_* __restrict__ Wt3)
{
    __shared__ float L[64 * 132];
    const int blk = blockIdx.x, t = threadIdx.x;

    if (blk < 8) {
        // load 64 rows: row_idx = m*8 + c_rel -> global k = 64m + 8*blk + c_rel
        for (int it = 0; it < 8; ++it) {
            int i = t + 256 * it;
            int ri = i >> 5, f4 = i & 31;
            int m = ri >> 3, cr = ri & 7;
            *(float4*)&L[ri * 132 + 4 * f4] =
                *(const float4*)&W1[(size_t)(64 * m + 8 * blk + cr) * H_ + 4 * f4];
        }
        __syncthreads();
        int f = t >> 1, half = t & 1;
        uint_ buf[16];
#pragma unroll
        for (int jj = 0; jj < 16; ++jj) {
            int k0 = 32 * half + 2 * jj;
            int c0 = k0 >> 3, m0 = k0 & 7;
            int c1 = (k0 + 1) >> 3, m1 = (k0 + 1) & 7;
            buf[jj] = (uint_)f2bf(L[(m0 * 8 + c0) * 132 + f]) |
                      ((uint_)f2bf(L[(m1 * 8 + c1) * 132 + f]) << 16);
        }
        ushort_* dst = Wt1 + (size_t)f * 512 + 64 * blk + 32 * half;
#pragma unroll
        for (int q = 0; q < 4; ++q) {
            uint4 vv = {buf[4 * q], buf[4 * q + 1], buf[4 * q + 2], buf[4 * q + 3]};
            *(uint4*)&dst[8 * q] = vv;
        }
    } else {
        const float* W = (blk < 10) ? W2 : W3;
        ushort_*     O = (blk < 10) ? Wt2 : Wt3;
        int kb = (blk - 8) & 1;
        for (int it = 0; it < 8; ++it) {
            int i = t + 256 * it;
            int ri = i >> 5, f4 = i & 31;
            *(float4*)&L[ri * 132 + 4 * f4] =
                *(const float4*)&W[(size_t)(64 * kb + ri) * H_ + 4 * f4];
        }
        __syncthreads();
        int f = t >> 1, half = t & 1;
        uint_ buf[16];
#pragma unroll
        for (int jj = 0; jj < 16; ++jj) {
            int k0 = 32 * half + 2 * jj;
            buf[jj] = (uint_)f2bf(L[k0 * 132 + f]) |
                      ((uint_)f2bf(L[(k0 + 1) * 132 + f]) << 16);
        }
        ushort_* dst = O + (size_t)f * 128 + 64 * kb + 32 * half;
#pragma unroll
        for (int q = 0; q < 4; ++q) {
            uint4 vv = {buf[4 * q], buf[4 * q + 1], buf[4 * q + 2], buf[4 * q + 3]};
            *(uint4*)&dst[8 * q] = vv;
        }
    }
}

// ---------------------------------------------------------------------------
// Shared MFMA epilogue: acc[nt] = Y frags (f32) -> Z = M@Y + bias (MFMA bf16),
// BN partials, Z -> global bf16.  Uses smem regions: Yt [0,22528),
// Ml [22528,33792), Zst [33792,51200).
// ---------------------------------------------------------------------------
__device__ __forceinline__ void mfma_epilogue(char* smem, int b, int t,
    f4v acc[8], const float* __restrict__ bias, const ushort_* __restrict__ Mb,
    ushort_* __restrict__ Zout, float* __restrict__ bnpart)
{
    const int l = t & 63, w = t >> 6;
    const int lr = l & 15, lg = l >> 4;

    ushort_* Yt  = (ushort_*)smem;             // [128][88]
    ushort_* Ml  = (ushort_*)(smem + 22528);   // [64][88]
    ushort_* Zst = (ushort_*)(smem + 33792);   // [64][136]

    // Y (C-frag: row=16w+4lg+reg, col f=16nt+lr) -> Yt[f][row] bf16
#pragma unroll
    for (int nt = 0; nt < 8; ++nt) {
        uint2 p;
        p.x = (uint_)f2bf(acc[nt][0]) | ((uint_)f2bf(acc[nt][1]) << 16);
        p.y = (uint_)f2bf(acc[nt][2]) | ((uint_)f2bf(acc[nt][3]) << 16);
        *(uint2*)&Yt[(16 * nt + lr) * 88 + 16 * w + 4 * lg] = p;
    }
    // stage Mb -> Ml
#pragma unroll
    for (int it = 0; it < 2; ++it) {
        int i = t + 256 * it;
        int d = i >> 3, seg = i & 7;
        *(uint4*)&Ml[d * 88 + 8 * seg] = *(const uint4*)&Mb[d * 64 + 8 * seg];
    }
    __syncthreads();

    f4v z[8];
#pragma unroll
    for (int nt = 0; nt < 8; ++nt) z[nt] = (f4v)0.f;
#pragma unroll
    for (int cs = 0; cs < 2; ++cs) {
        bf8v mf = *(const bf8v*)&Ml[(16 * w + lr) * 88 + 32 * cs + 8 * lg];
#pragma unroll
        for (int nt = 0; nt < 8; ++nt) {
            bf8v yf = *(const bf8v*)&Yt[(16 * nt + lr) * 88 + 32 * cs + 8 * lg];
            z[nt] = __builtin_amdgcn_mfma_f32_16x16x32_bf16(mf, yf, z[nt], 0, 0, 0);
        }
    }

    // bias + bf16 -> Zst
#pragma unroll
    for (int nt = 0; nt < 8; ++nt) {
        float bv = bias[16 * nt + lr];
#pragma unroll
        for (int reg = 0; reg < 4; ++reg)
            Zst[(16 * w + 4 * lg + reg) * 136 + 16 * nt + lr] = f2bf(z[nt][reg] + bv);
    }
    __syncthreads();

    // BN partials (from the bf16 Z actually used downstream)
    if (t < 128) {
        float s = 0.f, s2 = 0.f;
        for (int r = 0; r < 64; ++r) {
            float v = bf2f(Zst[r * 136 + t]);
            s += v; s2 += v * v;
        }
        bnpart[b * 256 + t]       = s;
        bnpart[b * 256 + 128 + t] = s2;
    }
    // coalesced Z write
#pragma unroll
    for (int it = 0; it < 4; ++it) {
        int i = t + 256 * it;
        int r = i >> 4, seg = i & 15;
        *(uint4*)&Zout[((size_t)(b * 64 + r)) * 128 + 8 * seg] =
            *(const uint4*)&Zst[r * 136 + 8 * seg];
    }
}

// ---------------------------------------------------------------------------
// Layer 1: A = nodes (permuted x view), K reordered as kappa = c*8+m so each
// K-chunk is a contiguous channel band of x[b] (coalesced, read exactly once).
// ---------------------------------------------------------------------------
__global__ __launch_bounds__(256) void k_mgemm1(const float* __restrict__ x,
    const ushort_* __restrict__ Wt,     /* [128][512] kappa-permuted bf16 */
    const float* __restrict__ bias, const ushort_* __restrict__ Mb,
    ushort_* __restrict__ Zout, float* __restrict__ bnpart)
{
    __shared__ __align__(16) char smem[51456];
    ushort_* Al = (ushort_*)smem;              // [16][520] per chunk
    ushort_* Wl = (ushort_*)(smem + 16640);    // [128][136] per chunk

    const int b = blockIdx.x;
    const int t = threadIdx.x;
    const int l = t & 63, w = t >> 6;
    const int lr = l & 15, lg = l >> 4;

    f4v acc[8];
#pragma unroll
    for (int nt = 0; nt < 8; ++nt) acc[nt] = (f4v)0.f;

    const float* xb = x + (size_t)b * (C_ * T_);

    for (int j = 0; j < 4; ++j) {
        // stage A: channels [16j,16j+16) x full T, f32->bf16
#pragma unroll
        for (int it = 0; it < 8; ++it) {
            int i = t + 256 * it;               // 16*128 float4s
            int cr = i >> 7, t4 = i & 127;
            float4 v = *(const float4*)&xb[(size_t)(16 * j + cr) * T_ + 4 * t4];
            uint2 p;
            p.x = (uint_)f2bf(v.x) | ((uint_)f2bf(v.y) << 16);
            p.y = (uint_)f2bf(v.z) | ((uint_)f2bf(v.w) << 16);
            *(uint2*)&Al[cr * 520 + 4 * t4] = p;
        }
        // stage W chunk: kappa in [128j, 128j+128)
#pragma unroll
        for (int it = 0; it < 8; ++it) {
            int i = t + 256 * it;               // 128*16 uint4s
            int f = i >> 4, seg = i & 15;
            *(uint4*)&Wl[f * 136 + 8 * seg] =
                *(const uint4*)&Wt[(size_t)f * 512 + 128 * j + 8 * seg];
        }
        __syncthreads();
#pragma unroll
        for (int s = 0; s < 4; ++s) {
            bf8v af = *(const bf8v*)&Al[(4 * s + lg) * 520 + 128 * w + 8 * lr];
#pragma unroll
            for (int nt = 0; nt < 8; ++nt) {
                bf8v bfv = *(const bf8v*)&Wl[(16 * nt + lr) * 136 + 32 * s + 8 * lg];
                acc[nt] = __builtin_amdgcn_mfma_f32_16x16x32_bf16(af, bfv, acc[nt], 0, 0, 0);
            }
        }
        __syncthreads();
    }
    mfma_epilogue(smem, b, t, acc, bias, Mb, Zout, bnpart);
}

// ---------------------------------------------------------------------------
// Layers 2/3: A = relu(Z*sc+sh) from bf16 Z (BN folded in staging), K=128.
// ---------------------------------------------------------------------------
__global__ __launch_bounds__(256) void k_mgemm23(const ushort_* __restrict__ Zin,
    const float* __restrict__ ss, const ushort_* __restrict__ Wt,
    const float* __restrict__ bias, const ushort_* __restrict__ Mb,
    ushort_* __restrict__ Zout, float* __restrict__ bnpart)
{
    __shared__ __align__(16) char smem[52224];
    __shared__ float ssL[256];
    ushort_* Al = (ushort_*)smem;              // [64][136]
    ushort_* Wl = (ushort_*)(smem + 17408);    // [128][136]

    const int b = blockIdx.x;
    const int t = threadIdx.x;
    const int l = t & 63, w = t >> 6;
    const int lr = l & 15, lg = l >> 4;

    ssL[t] = ss[t];
    __syncthreads();

    f4v acc[8];
#pragma unroll
    for (int nt = 0; nt < 8; ++nt) acc[nt] = (f4v)0.f;

    // stage A with BN fold + relu
#pragma unroll
    for (int it = 0; it < 4; ++it) {
        int i = t + 256 * it;
        int r = i >> 4, seg = i & 15;
        uint4 v = *(const uint4*)&Zin[((size_t)(b * 64 + r)) * 128 + 8 * seg];
        uint_ w0[4] = {v.x, v.y, v.z, v.w};
        uint_ o[4];
#pragma unroll
        for (int p = 0; p < 4; ++p) {
            int f0 = 8 * seg + 2 * p;
            float z0 = bf2f((ushort_)(w0[p] & 0xFFFF));
            float z1 = bf2f((ushort_)(w0[p] >> 16));
            float h0 = fmaxf(fmaf(z0, ssL[f0],     ssL[128 + f0]),     0.f);
            float h1 = fmaxf(fmaf(z1, ssL[f0 + 1], ssL[128 + f0 + 1]), 0.f);
            o[p] = (uint_)f2bf(h0) | ((uint_)f2bf(h1) << 16);
        }
        uint4 ov = {o[0], o[1], o[2], o[3]};
        *(uint4*)&Al[r * 136 + 8 * seg] = ov;
    }
    // stage W full [128][128]
#pragma unroll
    for (int it = 0; it < 8; ++it) {
        int i = t + 256 * it;
        int f = i >> 4, seg = i & 15;
        *(uint4*)&Wl[f * 136 + 8 * seg] =
            *(const uint4*)&Wt[(size_t)f * 128 + 8 * seg];
    }
    __syncthreads();
#pragma unroll
    for (int s = 0; s < 4; ++s) {
        bf8v af = *(const bf8v*)&Al[(16 * w + lr) * 136 + 32 * s + 8 * lg];
#pragma unroll
        for (int nt = 0; nt < 8; ++nt) {
            bf8v bfv = *(const bf8v*)&Wl[(16 * nt + lr) * 136 + 32 * s + 8 * lg];
            acc[nt] = __builtin_amdgcn_mfma_f32_16x16x32_bf16(af, bfv, acc[nt], 0, 0, 0);
        }
    }
    __syncthreads();
    mfma_epilogue(smem, b, t, acc, bias, Mb, Zout, bnpart);
}

// ---------------------------------------------------------------------------
// BN finalize (unchanged)
// ---------------------------------------------------------------------------
__global__ __launch_bounds__(256) void k_bnfin(const float* __restrict__ bnpart,
    const float* __restrict__ g, const float* __restrict__ be, float* __restrict__ ss)
{
    __shared__ double sums[256];
    const int t = threadIdx.x;
    double a = 0.0;
    for (int blk = 0; blk < 512; ++blk) a += (double)bnpart[blk * 256 + t];
    sums[t] = a;
    __syncthreads();
    if (t < 128) {
        double s = sums[t], s2 = sums[128 + t];
        double mean = s * (1.0 / 32768.0);
        double var  = s2 * (1.0 / 32768.0) - mean * mean;
        double rstd = 1.0 / sqrt(var + 1e-5);
        float sc = (float)((double)g[t] * rstd);
        ss[t]       = sc;
        ss[128 + t] = (float)((double)be[t] - mean * (double)sc);
    }
}

// ---------------------------------------------------------------------------
// Final BN + ReLU: bf16 Z3 -> f32 out
// ---------------------------------------------------------------------------
__global__ __launch_bounds__(256) void k_out(const ushort_* __restrict__ Z,
    const float* __restrict__ ss, float* __restrict__ out)
{
    int i = blockIdx.x * 256 + threadIdx.x;    // 524288 threads, 8 outputs each
    int n = i >> 4, seg = i & 15;
    uint4 v = *(const uint4*)&Z[(size_t)n * 128 + 8 * seg];
    float4 sc0 = *(const float4*)&ss[8 * seg];
    float4 sc1 = *(const float4*)&ss[8 * seg + 4];
    float4 sh0 = *(const float4*)&ss[128 + 8 * seg];
    float4 sh1 = *(const float4*)&ss[128 + 8 * seg + 4];
    uint_ wv[4] = {v.x, v.y, v.z, v.w};
    float zz[8];
#pragma unroll
    for (int p = 0; p < 4; ++p) {
        zz[2 * p]     = bf2f((ushort_)(wv[p] & 0xFFFF));
        zz[2 * p + 1] = bf2f((ushort_)(wv[p] >> 16));
    }
    float4 o0, o1;
    o0.x = fmaxf(fmaf(zz[0], sc0.x, sh0.x), 0.f);
    o0.y = fmaxf(fmaf(zz[1], sc0.y, sh0.y), 0.f);
    o0.z = fmaxf(fmaf(zz[2], sc0.z, sh0.z), 0.f);
    o0.w = fmaxf(fmaf(zz[3], sc0.w, sh0.w), 0.f);
    o1.x = fmaxf(fmaf(zz[4], sc1.x, sh1.x), 0.f);
    o1.y = fmaxf(fmaf(zz[5], sc1.y, sh1.y), 0.f);
    o1.z = fmaxf(fmaf(zz[6], sc1.z, sh1.z), 0.f);
    o1.w = fmaxf(fmaf(zz[7], sc1.w, sh1.w), 0.f);
    *(float4*)&out[(size_t)n * 128 + 8 * seg]     = o0;
    *(float4*)&out[(size_t)n * 128 + 8 * seg + 4] = o1;
}

// ---------------------------------------------------------------------------
extern "C" void kernel_launch(void* const* d_in, const int* in_sizes, int n_in,
                              void* d_out, int out_size, void* d_ws, size_t ws_size,
                              hipStream_t stream)
{
    (void)in_sizes; (void)n_in; (void)out_size; (void)ws_size;

    const float* x   = (const float*)d_in[0];
    const float* W1  = (const float*)d_in[9];
    const float* b1  = (const float*)d_in[10];
    const float* g1  = (const float*)d_in[11];
    const float* be1 = (const float*)d_in[12];
    const float* W2  = (const float*)d_in[13];
    const float* b2  = (const float*)d_in[14];
    const float* g2  = (const float*)d_in[15];
    const float* be2 = (const float*)d_in[16];
    const float* W3  = (const float*)d_in[17];
    const float* b3  = (const float*)d_in[18];
    const float* g3  = (const float*)d_in[19];
    const float* be3 = (const float*)d_in[20];

    char* ws = (char*)d_ws;
    float*   simp   = (float*)(ws + OFF_SIMP);
    double*  simf64 = (double*)(ws + OFF_SIMF64);
    ushort_* Mb     = (ushort_*)(ws + OFF_MB);
    ushort_* Wt1    = (ushort_*)(ws + OFF_WT1);
    ushort_* Wt2    = (ushort_*)(ws + OFF_WT2);
    ushort_* Wt3    = (ushort_*)(ws + OFF_WT3);
    float*   ss1    = (float*)(ws + OFF_SS1);
    float*   ss2    = (float*)(ws + OFF_SS2);
    float*   ss3    = (float*)(ws + OFF_SS3);
    float*   bnpart = (float*)(ws + OFF_BNPART);
    ushort_* Z1     = (ushort_*)(ws + OFF_Z1);
    ushort_* Z2     = (ushort_*)(ws + OFF_Z2);   // reuses simpart region
    ushort_* Z3     = (ushort_*)(ws + OFF_Z3);
    float*   out    = (float*)d_out;

    k_prepw<<<dim3(12), dim3(256), 0, stream>>>(W1, W2, W3, Wt1, Wt2, Wt3);
    k_simpart<<<dim3(512), dim3(256), 0, stream>>>(x, simp);
    k_simreduce<<<dim3(16), dim3(256), 0, stream>>>(simp, simf64);
    k_graph<<<dim3(1), dim3(256), 0, stream>>>(simf64, Mb);

    k_mgemm1<<<dim3(512), dim3(256), 0, stream>>>(x, Wt1, b1, Mb, Z1, bnpart);
    k_bnfin<<<dim3(1), dim3(256), 0, stream>>>(bnpart, g1, be1, ss1);

    k_mgemm23<<<dim3(512), dim3(256), 0, stream>>>(Z1, ss1, Wt2, b2, Mb, Z2, bnpart);
    k_bnfin<<<dim3(1), dim3(256), 0, stream>>>(bnpart, g2, be2, ss2);

    k_mgemm23<<<dim3(512), dim3(256), 0, stream>>>(Z2, ss2, Wt3, b3, Mb, Z3, bnpart);
    k_bnfin<<<dim3(1), dim3(256), 0, stream>>>(bnpart, g3, be3, ss3);

    k_out<<<dim3(2048), dim3(256), 0, stream>>>(Z3, ss3, out);
}

// Round 3
// 160.111 us; speedup vs baseline: 2.2114x; 1.4428x over previous
//
#include <hip/hip_runtime.h>
#include <math.h>

// Problem constants
#define B_  512
#define C_  64
#define T_  512
#define H_  128
#define N_  (B_*C_)   // 32768

typedef unsigned int   uint_;
typedef unsigned short ushort_;

typedef __attribute__((ext_vector_type(8))) short bf8v;   // 8 bf16 (4 VGPRs)
typedef __attribute__((ext_vector_type(4))) float f4v;    // MFMA accumulator

// Workspace byte offsets (total ~26 MB; harness provides >= 34 MB)
#define OFF_SIMP   0u            // 512*4096*4 = 8,388,608 ; reused as Z2 later
#define OFF_Z2     0u
#define OFF_Z1     8388608u      // 8,388,608 (bf16 32768x128)
#define OFF_Z3     16777216u     // 8,388,608
#define OFF_WT1    25165824u     // 128*512*2 = 131,072
#define OFF_WT2    25296896u     // 32,768
#define OFF_WT3    25329664u     // 32,768
#define OFF_SIMF64 25362432u     // 32,768
#define OFF_MB     25395200u     // 8,192
#define OFF_SS1    25403392u
#define OFF_SS2    25404416u
#define OFF_SS3    25405440u
#define OFF_BNPART 25406464u     // 512*256*4 = 524,288 -> end 25,930,752
#define OFF_BNP2   25930752u     // 32*256*8  = 65,536  -> end 25,996,288

__device__ __forceinline__ ushort_ f2bf(float f) {
    uint_ u = __float_as_uint(f);
    u = (u + 0x7FFFu + ((u >> 16) & 1u)) >> 16;    // RNE (finite values only)
    return (ushort_)u;
}
__device__ __forceinline__ float bf2f(ushort_ s) {
    return __uint_as_float(((uint_)s) << 16);
}

// ---------------------------------------------------------------------------
// Kernel 1 (NEW): per-batch cosine gram via split-precision bf16 MFMA.
// x = hi + lo (bf16 each); G = Xh*Xh^T + Xh*Xl^T + Xl*Xh^T  (error ~3e-7 rel,
// far below top-k order gaps ~1e-5..1e-3). Norms/normalization in f64.
// 512 blocks (one batch), 256 threads = 4 waves; wave w owns 2x2 16x16 tiles:
// rows 32*(w>>1)+{0,16}, cols 32*(w&1)+{0,16}.
// ---------------------------------------------------------------------------
__global__ __launch_bounds__(256) void k_gram(const float* __restrict__ x,
                                              float* __restrict__ simpart)
{
    __shared__ ushort_ Xh[64 * 136];
    __shared__ ushort_ Xl[64 * 136];
    __shared__ float  gd[64];
    __shared__ double rn[64];

    const int b = blockIdx.x;
    const int t = threadIdx.x;
    const int w = t >> 6, l = t & 63;
    const int lr = l & 15, lg = l >> 4;
    const int r0 = (w >> 1) * 2, c0 = (w & 1) * 2;   // tile-pair origins

    f4v acc[2][2];
#pragma unroll
    for (int i = 0; i < 2; ++i)
#pragma unroll
        for (int j = 0; j < 2; ++j) acc[i][j] = (f4v)0.f;

    const float* xb = x + (size_t)b * (C_ * T_);

    for (int j = 0; j < 4; ++j) {
        // stage chunk: all 64 channels x t-window [128j, 128j+128), hi+lo bf16
#pragma unroll
        for (int it = 0; it < 8; ++it) {
            int i = t + 256 * it;              // 2048 float4s
            int c = i >> 5, t4 = i & 31;
            float4 v = *(const float4*)&xb[(size_t)c * T_ + 128 * j + 4 * t4];
            ushort_ h0 = f2bf(v.x), h1 = f2bf(v.y), h2 = f2bf(v.z), h3 = f2bf(v.w);
            uint2 ph;
            ph.x = (uint_)h0 | ((uint_)h1 << 16);
            ph.y = (uint_)h2 | ((uint_)h3 << 16);
            float e0 = v.x - bf2f(h0), e1 = v.y - bf2f(h1);
            float e2 = v.z - bf2f(h2), e3 = v.w - bf2f(h3);
            uint2 pl;
            pl.x = (uint_)f2bf(e0) | ((uint_)f2bf(e1) << 16);
            pl.y = (uint_)f2bf(e2) | ((uint_)f2bf(e3) << 16);
            *(uint2*)&Xh[c * 136 + 4 * t4] = ph;
            *(uint2*)&Xl[c * 136 + 4 * t4] = pl;
        }
        __syncthreads();

#pragma unroll
        for (int s = 0; s < 4; ++s) {
            bf8v ah[2], al[2], bh[2], bl[2];
#pragma unroll
            for (int i = 0; i < 2; ++i) {
                ah[i] = *(const bf8v*)&Xh[(16 * (r0 + i) + lr) * 136 + 32 * s + 8 * lg];
                al[i] = *(const bf8v*)&Xl[(16 * (r0 + i) + lr) * 136 + 32 * s + 8 * lg];
                bh[i] = *(const bf8v*)&Xh[(16 * (c0 + i) + lr) * 136 + 32 * s + 8 * lg];
                bl[i] = *(const bf8v*)&Xl[(16 * (c0 + i) + lr) * 136 + 32 * s + 8 * lg];
            }
#pragma unroll
            for (int i = 0; i < 2; ++i)
#pragma unroll
                for (int jj = 0; jj < 2; ++jj) {
                    acc[i][jj] = __builtin_amdgcn_mfma_f32_16x16x32_bf16(ah[i], bh[jj], acc[i][jj], 0, 0, 0);
                    acc[i][jj] = __builtin_amdgcn_mfma_f32_16x16x32_bf16(ah[i], bl[jj], acc[i][jj], 0, 0, 0);
                    acc[i][jj] = __builtin_amdgcn_mfma_f32_16x16x32_bf16(al[i], bh[jj], acc[i][jj], 0, 0, 0);
                }
        }
        __syncthreads();
    }

    // diagonal extraction (waves 0 and 3 own diagonal tiles)
    if (r0 == c0) {
#pragma unroll
        for (int d = 0; d < 2; ++d)
            if (lg == (lr >> 2)) gd[16 * (r0 + d) + lr] = acc[d][d][lr & 3];
    }
    __syncthreads();
    if (t < 64) rn[t] = 1.0 / fmax(sqrt((double)gd[t]), 1e-12);
    __syncthreads();

    float* sp = simpart + (size_t)b * 4096;
#pragma unroll
    for (int i = 0; i < 2; ++i)
#pragma unroll
        for (int jj = 0; jj < 2; ++jj)
#pragma unroll
            for (int reg = 0; reg < 4; ++reg) {
                int rc = 16 * (r0 + i) + 4 * lg + reg;
                int cc = 16 * (c0 + jj) + lr;
                sp[rc * 64 + cc] = (float)((double)acc[i][jj][reg] * rn[rc] * rn[cc]);
            }
}

// ---------------------------------------------------------------------------
// Kernel 2 (parallelized): deterministic f64 reduction over batches.
// 256 blocks; block owns 16 e-values; 256 thr = (16 e) x (16 b-lanes);
// each lane sums 32 batches in fixed order, then per-e serial 16-lane tree.
// ---------------------------------------------------------------------------
__global__ __launch_bounds__(256) void k_simreduce(const float* __restrict__ simpart,
                                                   double* __restrict__ simf64)
{
    __shared__ double s[16][17];
    const int t = threadIdx.x;
    const int el = t & 15, bl = t >> 4;
    const int e0 = blockIdx.x * 16;
    double a = 0.0;
    for (int i = 0; i < 32; ++i) {
        int b = bl + (i << 4);
        a += (double)simpart[(size_t)b * 4096 + e0 + el];
    }
    s[el][bl] = a;
    __syncthreads();
    if (t < 16) {
        double r = 0.0;
        for (int q = 0; q < 16; ++q) r += s[t][q];
        simf64[e0 + t] = r * (1.0 / 512.0);
    }
}

// ---------------------------------------------------------------------------
// Kernel 3: top-K, degrees, mixing matrix M -> bf16 Mb[d][c]  (unchanged)
// ---------------------------------------------------------------------------
__global__ __launch_bounds__(256) void k_graph(const double* __restrict__ simf64,
                                               ushort_* __restrict__ Mbout)
{
    __shared__ double sd[64 * 65];
    __shared__ unsigned long long nbrm[64];
    __shared__ int   degS[64];
    __shared__ float dv[64];
    const int t = threadIdx.x;

    if (t < 64) degS[t] = 1;
    for (int i = t; i < 4096; i += 256)
        sd[(i >> 6) * 65 + (i & 63)] = simf64[i];
    __syncthreads();

    if (t < 64) {
        unsigned long long chosen = 0ull;
        for (int k = 0; k < 16; ++k) {
            double best = -1e300; int bi = 0;
            for (int d = 0; d < 64; ++d) {
                if ((chosen >> d) & 1ull) continue;
                double v = sd[t * 65 + d];
                if (v > best) { best = v; bi = d; }
            }
            chosen |= (1ull << bi);
        }
        nbrm[t] = chosen;
    }
    __syncthreads();
    if (t < 64) {
        unsigned long long chosen = nbrm[t];
        while (chosen) {
            int d = (int)__builtin_ctzll(chosen);
            atomicAdd(&degS[d], 1);
            chosen &= chosen - 1;
        }
    }
    __syncthreads();
    if (t < 64) dv[t] = 1.0f / sqrtf((float)degS[t]);
    __syncthreads();

    for (int e = t; e < 4096; e += 256) {
        int d = e >> 6, c = e & 63;
        float w = (float)((int)((nbrm[c] >> d) & 1ull) + (d == c ? 1 : 0));
        Mbout[e] = f2bf(w * dv[c] * dv[d]);   // Mb[d*64+c]
    }
}

// ---------------------------------------------------------------------------
// Weight prep (unchanged): bf16 transposed weights.
// ---------------------------------------------------------------------------
__global__ __launch_bounds__(256) void k_prepw(const float* __restrict__ W1,
    const float* __restrict__ W2, const float* __restrict__ W3,
    ushort_* __restrict__ Wt1, ushort_* __restrict__ Wt2, ushort_* __restrict__ Wt3)
{
    __shared__ float L[64 * 132];
    const int blk = blockIdx.x, t = threadIdx.x;

    if (blk < 8) {
        for (int it = 0; it < 8; ++it) {
            int i = t + 256 * it;
            int ri = i >> 5, f4 = i & 31;
            int m = ri >> 3, cr = ri & 7;
            *(float4*)&L[ri * 132 + 4 * f4] =
                *(const float4*)&W1[(size_t)(64 * m + 8 * blk + cr) * H_ + 4 * f4];
        }
        __syncthreads();
        int f = t >> 1, half = t & 1;
        uint_ buf[16];
#pragma unroll
        for (int jj = 0; jj < 16; ++jj) {
            int k0 = 32 * half + 2 * jj;
            int c0 = k0 >> 3, m0 = k0 & 7;
            int c1 = (k0 + 1) >> 3, m1 = (k0 + 1) & 7;
            buf[jj] = (uint_)f2bf(L[(m0 * 8 + c0) * 132 + f]) |
                      ((uint_)f2bf(L[(m1 * 8 + c1) * 132 + f]) << 16);
        }
        ushort_* dst = Wt1 + (size_t)f * 512 + 64 * blk + 32 * half;
#pragma unroll
        for (int q = 0; q < 4; ++q) {
            uint4 vv = {buf[4 * q], buf[4 * q + 1], buf[4 * q + 2], buf[4 * q + 3]};
            *(uint4*)&dst[8 * q] = vv;
        }
    } else {
        const float* W = (blk < 10) ? W2 : W3;
        ushort_*     O = (blk < 10) ? Wt2 : Wt3;
        int kb = (blk - 8) & 1;
        for (int it = 0; it < 8; ++it) {
            int i = t + 256 * it;
            int ri = i >> 5, f4 = i & 31;
            *(float4*)&L[ri * 132 + 4 * f4] =
                *(const float4*)&W[(size_t)(64 * kb + ri) * H_ + 4 * f4];
        }
        __syncthreads();
        int f = t >> 1, half = t & 1;
        uint_ buf[16];
#pragma unroll
        for (int jj = 0; jj < 16; ++jj) {
            int k0 = 32 * half + 2 * jj;
            buf[jj] = (uint_)f2bf(L[k0 * 132 + f]) |
                      ((uint_)f2bf(L[(k0 + 1) * 132 + f]) << 16);
        }
        ushort_* dst = O + (size_t)f * 128 + 64 * kb + 32 * half;
#pragma unroll
        for (int q = 0; q < 4; ++q) {
            uint4 vv = {buf[4 * q], buf[4 * q + 1], buf[4 * q + 2], buf[4 * q + 3]};
            *(uint4*)&dst[8 * q] = vv;
        }
    }
}

// ---------------------------------------------------------------------------
// Shared MFMA epilogue (unchanged)
// ---------------------------------------------------------------------------
__device__ __forceinline__ void mfma_epilogue(char* smem, int b, int t,
    f4v acc[8], const float* __restrict__ bias, const ushort_* __restrict__ Mb,
    ushort_* __restrict__ Zout, float* __restrict__ bnpart)
{
    const int l = t & 63, w = t >> 6;
    const int lr = l & 15, lg = l >> 4;

    ushort_* Yt  = (ushort_*)smem;             // [128][88]
    ushort_* Ml  = (ushort_*)(smem + 22528);   // [64][88]
    ushort_* Zst = (ushort_*)(smem + 33792);   // [64][136]

#pragma unroll
    for (int nt = 0; nt < 8; ++nt) {
        uint2 p;
        p.x = (uint_)f2bf(acc[nt][0]) | ((uint_)f2bf(acc[nt][1]) << 16);
        p.y = (uint_)f2bf(acc[nt][2]) | ((uint_)f2bf(acc[nt][3]) << 16);
        *(uint2*)&Yt[(16 * nt + lr) * 88 + 16 * w + 4 * lg] = p;
    }
#pragma unroll
    for (int it = 0; it < 2; ++it) {
        int i = t + 256 * it;
        int d = i >> 3, seg = i & 7;
        *(uint4*)&Ml[d * 88 + 8 * seg] = *(const uint4*)&Mb[d * 64 + 8 * seg];
    }
    __syncthreads();

    f4v z[8];
#pragma unroll
    for (int nt = 0; nt < 8; ++nt) z[nt] = (f4v)0.f;
#pragma unroll
    for (int cs = 0; cs < 2; ++cs) {
        bf8v mf = *(const bf8v*)&Ml[(16 * w + lr) * 88 + 32 * cs + 8 * lg];
#pragma unroll
        for (int nt = 0; nt < 8; ++nt) {
            bf8v yf = *(const bf8v*)&Yt[(16 * nt + lr) * 88 + 32 * cs + 8 * lg];
            z[nt] = __builtin_amdgcn_mfma_f32_16x16x32_bf16(mf, yf, z[nt], 0, 0, 0);
        }
    }

#pragma unroll
    for (int nt = 0; nt < 8; ++nt) {
        float bv = bias[16 * nt + lr];
#pragma unroll
        for (int reg = 0; reg < 4; ++reg)
            Zst[(16 * w + 4 * lg + reg) * 136 + 16 * nt + lr] = f2bf(z[nt][reg] + bv);
    }
    __syncthreads();

    if (t < 128) {
        float s = 0.f, s2 = 0.f;
        for (int r = 0; r < 64; ++r) {
            float v = bf2f(Zst[r * 136 + t]);
            s += v; s2 += v * v;
        }
        bnpart[b * 256 + t]       = s;
        bnpart[b * 256 + 128 + t] = s2;
    }
#pragma unroll
    for (int it = 0; it < 4; ++it) {
        int i = t + 256 * it;
        int r = i >> 4, seg = i & 15;
        *(uint4*)&Zout[((size_t)(b * 64 + r)) * 128 + 8 * seg] =
            *(const uint4*)&Zst[r * 136 + 8 * seg];
    }
}

// ---------------------------------------------------------------------------
// Layer 1 (unchanged): kappa-permuted K so x[b] is read contiguously once.
// ---------------------------------------------------------------------------
__global__ __launch_bounds__(256) void k_mgemm1(const float* __restrict__ x,
    const ushort_* __restrict__ Wt, const float* __restrict__ bias,
    const ushort_* __restrict__ Mb, ushort_* __restrict__ Zout,
    float* __restrict__ bnpart)
{
    __shared__ __align__(16) char smem[51456];
    ushort_* Al = (ushort_*)smem;              // [16][520] per chunk
    ushort_* Wl = (ushort_*)(smem + 16640);    // [128][136] per chunk

    const int b = blockIdx.x;
    const int t = threadIdx.x;
    const int l = t & 63, w = t >> 6;
    const int lr = l & 15, lg = l >> 4;

    f4v acc[8];
#pragma unroll
    for (int nt = 0; nt < 8; ++nt) acc[nt] = (f4v)0.f;

    const float* xb = x + (size_t)b * (C_ * T_);

    for (int j = 0; j < 4; ++j) {
#pragma unroll
        for (int it = 0; it < 8; ++it) {
            int i = t + 256 * it;
            int cr = i >> 7, t4 = i & 127;
            float4 v = *(const float4*)&xb[(size_t)(16 * j + cr) * T_ + 4 * t4];
            uint2 p;
            p.x = (uint_)f2bf(v.x) | ((uint_)f2bf(v.y) << 16);
            p.y = (uint_)f2bf(v.z) | ((uint_)f2bf(v.w) << 16);
            *(uint2*)&Al[cr * 520 + 4 * t4] = p;
        }
#pragma unroll
        for (int it = 0; it < 8; ++it) {
            int i = t + 256 * it;
            int f = i >> 4, seg = i & 15;
            *(uint4*)&Wl[f * 136 + 8 * seg] =
                *(const uint4*)&Wt[(size_t)f * 512 + 128 * j + 8 * seg];
        }
        __syncthreads();
#pragma unroll
        for (int s = 0; s < 4; ++s) {
            bf8v af = *(const bf8v*)&Al[(4 * s + lg) * 520 + 128 * w + 8 * lr];
#pragma unroll
            for (int nt = 0; nt < 8; ++nt) {
                bf8v bfv = *(const bf8v*)&Wl[(16 * nt + lr) * 136 + 32 * s + 8 * lg];
                acc[nt] = __builtin_amdgcn_mfma_f32_16x16x32_bf16(af, bfv, acc[nt], 0, 0, 0);
            }
        }
        __syncthreads();
    }
    mfma_epilogue(smem, b, t, acc, bias, Mb, Zout, bnpart);
}

// ---------------------------------------------------------------------------
// Layers 2/3 (unchanged)
// ---------------------------------------------------------------------------
__global__ __launch_bounds__(256) void k_mgemm23(const ushort_* __restrict__ Zin,
    const float* __restrict__ ss, const ushort_* __restrict__ Wt,
    const float* __restrict__ bias, const ushort_* __restrict__ Mb,
    ushort_* __restrict__ Zout, float* __restrict__ bnpart)
{
    __shared__ __align__(16) char smem[52224];
    __shared__ float ssL[256];
    ushort_* Al = (ushort_*)smem;              // [64][136]
    ushort_* Wl = (ushort_*)(smem + 17408);    // [128][136]

    const int b = blockIdx.x;
    const int t = threadIdx.x;
    const int l = t & 63, w = t >> 6;
    const int lr = l & 15, lg = l >> 4;

    ssL[t] = ss[t];
    __syncthreads();

    f4v acc[8];
#pragma unroll
    for (int nt = 0; nt < 8; ++nt) acc[nt] = (f4v)0.f;

#pragma unroll
    for (int it = 0; it < 4; ++it) {
        int i = t + 256 * it;
        int r = i >> 4, seg = i & 15;
        uint4 v = *(const uint4*)&Zin[((size_t)(b * 64 + r)) * 128 + 8 * seg];
        uint_ w0[4] = {v.x, v.y, v.z, v.w};
        uint_ o[4];
#pragma unroll
        for (int p = 0; p < 4; ++p) {
            int f0 = 8 * seg + 2 * p;
            float z0 = bf2f((ushort_)(w0[p] & 0xFFFF));
            float z1 = bf2f((ushort_)(w0[p] >> 16));
            float h0 = fmaxf(fmaf(z0, ssL[f0],     ssL[128 + f0]),     0.f);
            float h1 = fmaxf(fmaf(z1, ssL[f0 + 1], ssL[128 + f0 + 1]), 0.f);
            o[p] = (uint_)f2bf(h0) | ((uint_)f2bf(h1) << 16);
        }
        uint4 ov = {o[0], o[1], o[2], o[3]};
        *(uint4*)&Al[r * 136 + 8 * seg] = ov;
    }
#pragma unroll
    for (int it = 0; it < 8; ++it) {
        int i = t + 256 * it;
        int f = i >> 4, seg = i & 15;
        *(uint4*)&Wl[f * 136 + 8 * seg] =
            *(const uint4*)&Wt[(size_t)f * 128 + 8 * seg];
    }
    __syncthreads();
#pragma unroll
    for (int s = 0; s < 4; ++s) {
        bf8v af = *(const bf8v*)&Al[(16 * w + lr) * 136 + 32 * s + 8 * lg];
#pragma unroll
        for (int nt = 0; nt < 8; ++nt) {
            bf8v bfv = *(const bf8v*)&Wl[(16 * nt + lr) * 136 + 32 * s + 8 * lg];
            acc[nt] = __builtin_amdgcn_mfma_f32_16x16x32_bf16(af, bfv, acc[nt], 0, 0, 0);
        }
    }
    __syncthreads();
    mfma_epilogue(smem, b, t, acc, bias, Mb, Zout, bnpart);
}

// ---------------------------------------------------------------------------
// BN reduce stage A: 32 blocks, each sums 16 gemm-blocks' partials (f64).
// ---------------------------------------------------------------------------
__global__ __launch_bounds__(256) void k_bnA(const float* __restrict__ bnpart,
                                             double* __restrict__ bnp2)
{
    const int t = threadIdx.x, g = blockIdx.x;
    double a = 0.0;
    for (int i = 0; i < 16; ++i)
        a += (double)bnpart[(size_t)(16 * g + i) * 256 + t];
    bnp2[(size_t)g * 256 + t] = a;
}

// ---------------------------------------------------------------------------
// BN reduce stage B + finalize: 1 block sums 32 partials, emits scale/shift.
// ---------------------------------------------------------------------------
__global__ __launch_bounds__(256) void k_bnB(const double* __restrict__ bnp2,
    const float* __restrict__ g, const float* __restrict__ be, float* __restrict__ ss)
{
    __shared__ double sums[256];
    const int t = threadIdx.x;
    double a = 0.0;
    for (int q = 0; q < 32; ++q) a += bnp2[(size_t)q * 256 + t];
    sums[t] = a;
    __syncthreads();
    if (t < 128) {
        double s = sums[t], s2 = sums[128 + t];
        double mean = s * (1.0 / 32768.0);
        double var  = s2 * (1.0 / 32768.0) - mean * mean;
        double rstd = 1.0 / sqrt(var + 1e-5);
        float sc = (float)((double)g[t] * rstd);
        ss[t]       = sc;
        ss[128 + t] = (float)((double)be[t] - mean * (double)sc);
    }
}

// ---------------------------------------------------------------------------
// Final BN + ReLU (unchanged)
// ---------------------------------------------------------------------------
__global__ __launch_bounds__(256) void k_out(const ushort_* __restrict__ Z,
    const float* __restrict__ ss, float* __restrict__ out)
{
    int i = blockIdx.x * 256 + threadIdx.x;
    int n = i >> 4, seg = i & 15;
    uint4 v = *(const uint4*)&Z[(size_t)n * 128 + 8 * seg];
    float4 sc0 = *(const float4*)&ss[8 * seg];
    float4 sc1 = *(const float4*)&ss[8 * seg + 4];
    float4 sh0 = *(const float4*)&ss[128 + 8 * seg];
    float4 sh1 = *(const float4*)&ss[128 + 8 * seg + 4];
    uint_ wv[4] = {v.x, v.y, v.z, v.w};
    float zz[8];
#pragma unroll
    for (int p = 0; p < 4; ++p) {
        zz[2 * p]     = bf2f((ushort_)(wv[p] & 0xFFFF));
        zz[2 * p + 1] = bf2f((ushort_)(wv[p] >> 16));
    }
    float4 o0, o1;
    o0.x = fmaxf(fmaf(zz[0], sc0.x, sh0.x), 0.f);
    o0.y = fmaxf(fmaf(zz[1], sc0.y, sh0.y), 0.f);
    o0.z = fmaxf(fmaf(zz[2], sc0.z, sh0.z), 0.f);
    o0.w = fmaxf(fmaf(zz[3], sc0.w, sh0.w), 0.f);
    o1.x = fmaxf(fmaf(zz[4], sc1.x, sh1.x), 0.f);
    o1.y = fmaxf(fmaf(zz[5], sc1.y, sh1.y), 0.f);
    o1.z = fmaxf(fmaf(zz[6], sc1.z, sh1.z), 0.f);
    o1.w = fmaxf(fmaf(zz[7], sc1.w, sh1.w), 0.f);
    *(float4*)&out[(size_t)n * 128 + 8 * seg]     = o0;
    *(float4*)&out[(size_t)n * 128 + 8 * seg + 4] = o1;
}

// ---------------------------------------------------------------------------
extern "C" void kernel_launch(void* const* d_in, const int* in_sizes, int n_in,
                              void* d_out, int out_size, void* d_ws, size_t ws_size,
                              hipStream_t stream)
{
    (void)in_sizes; (void)n_in; (void)out_size; (void)ws_size;

    const float* x   = (const float*)d_in[0];
    const float* W1  = (const float*)d_in[9];
    const float* b1  = (const float*)d_in[10];
    const float* g1  = (const float*)d_in[11];
    const float* be1 = (const float*)d_in[12];
    const float* W2  = (const float*)d_in[13];
    const float* b2  = (const float*)d_in[14];
    const float* g2  = (const float*)d_in[15];
    const float* be2 = (const float*)d_in[16];
    const float* W3  = (const float*)d_in[17];
    const float* b3  = (const float*)d_in[18];
    const float* g3  = (const float*)d_in[19];
    const float* be3 = (const float*)d_in[20];

    char* ws = (char*)d_ws;
    float*   simp   = (float*)(ws + OFF_SIMP);
    double*  simf64 = (double*)(ws + OFF_SIMF64);
    ushort_* Mb     = (ushort_*)(ws + OFF_MB);
    ushort_* Wt1    = (ushort_*)(ws + OFF_WT1);
    ushort_* Wt2    = (ushort_*)(ws + OFF_WT2);
    ushort_* Wt3    = (ushort_*)(ws + OFF_WT3);
    float*   ss1    = (float*)(ws + OFF_SS1);
    float*   ss2    = (float*)(ws + OFF_SS2);
    float*   ss3    = (float*)(ws + OFF_SS3);
    float*   bnpart = (float*)(ws + OFF_BNPART);
    double*  bnp2   = (double*)(ws + OFF_BNP2);
    ushort_* Z1     = (ushort_*)(ws + OFF_Z1);
    ushort_* Z2     = (ushort_*)(ws + OFF_Z2);   // reuses simpart region
    ushort_* Z3     = (ushort_*)(ws + OFF_Z3);
    float*   out    = (float*)d_out;

    k_prepw<<<dim3(12), dim3(256), 0, stream>>>(W1, W2, W3, Wt1, Wt2, Wt3);
    k_gram<<<dim3(512), dim3(256), 0, stream>>>(x, simp);
    k_simreduce<<<dim3(256), dim3(256), 0, stream>>>(simp, simf64);
    k_graph<<<dim3(1), dim3(256), 0, stream>>>(simf64, Mb);

    k_mgemm1<<<dim3(512), dim3(256), 0, stream>>>(x, Wt1, b1, Mb, Z1, bnpart);
    k_bnA<<<dim3(32), dim3(256), 0, stream>>>(bnpart, bnp2);
    k_bnB<<<dim3(1), dim3(256), 0, stream>>>(bnp2, g1, be1, ss1);

    k_mgemm23<<<dim3(512), dim3(256), 0, stream>>>(Z1, ss1, Wt2, b2, Mb, Z2, bnpart);
    k_bnA<<<dim3(32), dim3(256), 0, stream>>>(bnpart, bnp2);
    k_bnB<<<dim3(1), dim3(256), 0, stream>>>(bnp2, g2, be2, ss2);

    k_mgemm23<<<dim3(512), dim3(256), 0, stream>>>(Z2, ss2, Wt3, b3, Mb, Z3, bnpart);
    k_bnA<<<dim3(32), dim3(256), 0, stream>>>(bnpart, bnp2);
    k_bnB<<<dim3(1), dim3(256), 0, stream>>>(bnp2, g3, be3, ss3);

    k_out<<<dim3(2048), dim3(256), 0, stream>>>(Z3, ss3, out);
}

// Round 4
// 153.991 us; speedup vs baseline: 2.2993x; 1.0397x over previous
//
#include <hip/hip_runtime.h>
#include <math.h>

// Problem constants
#define B_  512
#define C_  64
#define T_  512
#define H_  128
#define N_  (B_*C_)   // 32768

typedef unsigned int   uint_;
typedef unsigned short ushort_;

typedef __attribute__((ext_vector_type(8))) short bf8v;   // 8 bf16 (4 VGPRs)
typedef __attribute__((ext_vector_type(4))) float f4v;    // MFMA accumulator

// Workspace byte offsets (total ~26 MB; harness provides >= 34 MB)
#define OFF_SIMP   0u            // 512*4096*4 = 8,388,608 ; reused as Z2 later
#define OFF_Z2     0u
#define OFF_Z1     8388608u      // 8,388,608 (bf16 32768x128)
#define OFF_Z3     16777216u     // 8,388,608
#define OFF_WT1    25165824u     // 128*512*2 = 131,072
#define OFF_WT2    25296896u     // 32,768
#define OFF_WT3    25329664u     // 32,768
#define OFF_SIMF64 25362432u     // 32,768
#define OFF_MB     25395200u     // 8,192
#define OFF_SS1    25403392u
#define OFF_SS2    25404416u
#define OFF_SS3    25405440u
#define OFF_BNPART 25406464u     // 512*256*4 = 524,288 -> end 25,930,752
#define OFF_BNP2   25930752u     // 32*256*8  = 65,536  -> end 25,996,288

__device__ __forceinline__ ushort_ f2bf(float f) {
    uint_ u = __float_as_uint(f);
    u = (u + 0x7FFFu + ((u >> 16) & 1u)) >> 16;    // RNE (finite values only)
    return (ushort_)u;
}
__device__ __forceinline__ float bf2f(ushort_ s) {
    return __uint_as_float(((uint_)s) << 16);
}

// ---------------------------------------------------------------------------
// Kernel 1: per-batch cosine gram via split-precision bf16 MFMA (unchanged).
// ---------------------------------------------------------------------------
__global__ __launch_bounds__(256) void k_gram(const float* __restrict__ x,
                                              float* __restrict__ simpart)
{
    __shared__ ushort_ Xh[64 * 136];
    __shared__ ushort_ Xl[64 * 136];
    __shared__ float  gd[64];
    __shared__ double rn[64];

    const int b = blockIdx.x;
    const int t = threadIdx.x;
    const int w = t >> 6, l = t & 63;
    const int lr = l & 15, lg = l >> 4;
    const int r0 = (w >> 1) * 2, c0 = (w & 1) * 2;   // tile-pair origins

    f4v acc[2][2];
#pragma unroll
    for (int i = 0; i < 2; ++i)
#pragma unroll
        for (int j = 0; j < 2; ++j) acc[i][j] = (f4v)0.f;

    const float* xb = x + (size_t)b * (C_ * T_);

    for (int j = 0; j < 4; ++j) {
#pragma unroll
        for (int it = 0; it < 8; ++it) {
            int i = t + 256 * it;              // 2048 float4s
            int c = i >> 5, t4 = i & 31;
            float4 v = *(const float4*)&xb[(size_t)c * T_ + 128 * j + 4 * t4];
            ushort_ h0 = f2bf(v.x), h1 = f2bf(v.y), h2 = f2bf(v.z), h3 = f2bf(v.w);
            uint2 ph;
            ph.x = (uint_)h0 | ((uint_)h1 << 16);
            ph.y = (uint_)h2 | ((uint_)h3 << 16);
            float e0 = v.x - bf2f(h0), e1 = v.y - bf2f(h1);
            float e2 = v.z - bf2f(h2), e3 = v.w - bf2f(h3);
            uint2 pl;
            pl.x = (uint_)f2bf(e0) | ((uint_)f2bf(e1) << 16);
            pl.y = (uint_)f2bf(e2) | ((uint_)f2bf(e3) << 16);
            *(uint2*)&Xh[c * 136 + 4 * t4] = ph;
            *(uint2*)&Xl[c * 136 + 4 * t4] = pl;
        }
        __syncthreads();

#pragma unroll
        for (int s = 0; s < 4; ++s) {
            bf8v ah[2], al[2], bh[2], bl[2];
#pragma unroll
            for (int i = 0; i < 2; ++i) {
                ah[i] = *(const bf8v*)&Xh[(16 * (r0 + i) + lr) * 136 + 32 * s + 8 * lg];
                al[i] = *(const bf8v*)&Xl[(16 * (r0 + i) + lr) * 136 + 32 * s + 8 * lg];
                bh[i] = *(const bf8v*)&Xh[(16 * (c0 + i) + lr) * 136 + 32 * s + 8 * lg];
                bl[i] = *(const bf8v*)&Xl[(16 * (c0 + i) + lr) * 136 + 32 * s + 8 * lg];
            }
#pragma unroll
            for (int i = 0; i < 2; ++i)
#pragma unroll
                for (int jj = 0; jj < 2; ++jj) {
                    acc[i][jj] = __builtin_amdgcn_mfma_f32_16x16x32_bf16(ah[i], bh[jj], acc[i][jj], 0, 0, 0);
                    acc[i][jj] = __builtin_amdgcn_mfma_f32_16x16x32_bf16(ah[i], bl[jj], acc[i][jj], 0, 0, 0);
                    acc[i][jj] = __builtin_amdgcn_mfma_f32_16x16x32_bf16(al[i], bh[jj], acc[i][jj], 0, 0, 0);
                }
        }
        __syncthreads();
    }

    if (r0 == c0) {
#pragma unroll
        for (int d = 0; d < 2; ++d)
            if (lg == (lr >> 2)) gd[16 * (r0 + d) + lr] = acc[d][d][lr & 3];
    }
    __syncthreads();
    if (t < 64) rn[t] = 1.0 / fmax(sqrt((double)gd[t]), 1e-12);
    __syncthreads();

    float* sp = simpart + (size_t)b * 4096;
#pragma unroll
    for (int i = 0; i < 2; ++i)
#pragma unroll
        for (int jj = 0; jj < 2; ++jj)
#pragma unroll
            for (int reg = 0; reg < 4; ++reg) {
                int rc = 16 * (r0 + i) + 4 * lg + reg;
                int cc = 16 * (c0 + jj) + lr;
                sp[rc * 64 + cc] = (float)((double)acc[i][jj][reg] * rn[rc] * rn[cc]);
            }
}

// ---------------------------------------------------------------------------
// Kernel 2: deterministic f64 reduction over batches (unchanged).
// ---------------------------------------------------------------------------
__global__ __launch_bounds__(256) void k_simreduce(const float* __restrict__ simpart,
                                                   double* __restrict__ simf64)
{
    __shared__ double s[16][17];
    const int t = threadIdx.x;
    const int el = t & 15, bl = t >> 4;
    const int e0 = blockIdx.x * 16;
    double a = 0.0;
    for (int i = 0; i < 32; ++i) {
        int b = bl + (i << 4);
        a += (double)simpart[(size_t)b * 4096 + e0 + el];
    }
    s[el][bl] = a;
    __syncthreads();
    if (t < 16) {
        double r = 0.0;
        for (int q = 0; q < 16; ++q) r += s[t][q];
        simf64[e0 + t] = r * (1.0 / 512.0);
    }
}

// ---------------------------------------------------------------------------
// Kernel 3 (NEW): wave-parallel top-K via rank-select.
// Element (c,d) chosen iff rank < 16 where rank counts strictly-greater
// values plus equal-valued lower indices -- identical selection (and
// tie-break) to iterative max with strict >, i.e. lax.top_k.
// Wave w handles rows 16w..16w+15; lane d holds sim[c][d].
// ---------------------------------------------------------------------------
__global__ __launch_bounds__(256) void k_graph(const double* __restrict__ simf64,
                                               ushort_* __restrict__ Mbout)
{
    __shared__ unsigned long long nbrm[64];
    __shared__ float dv[64];
    const int t = threadIdx.x;
    const int w = t >> 6, l = t & 63;

    for (int i = 0; i < 16; ++i) {
        const int c = 16 * w + i;
        const double v = simf64[c * 64 + l];
        int rank = 0;
#pragma unroll
        for (int d = 0; d < 64; ++d) {
            double vv = __shfl(v, d, 64);
            rank += (vv > v || (vv == v && d < l)) ? 1 : 0;
        }
        unsigned long long m = __ballot(rank < 16);
        if (l == 0) nbrm[c] = m;
    }
    __syncthreads();

    if (t < 64) {
        int deg = 1;                      // self-loop
        for (int c = 0; c < 64; ++c) deg += (int)((nbrm[c] >> t) & 1ull);
        dv[t] = 1.0f / sqrtf((float)deg);
    }
    __syncthreads();

    for (int e = t; e < 4096; e += 256) {
        int d = e >> 6, c = e & 63;
        float wgt = (float)((int)((nbrm[c] >> d) & 1ull) + (d == c ? 1 : 0));
        Mbout[e] = f2bf(wgt * dv[c] * dv[d]);   // Mb[d*64+c]
    }
}

// ---------------------------------------------------------------------------
// Weight prep (unchanged): bf16 transposed weights.
// ---------------------------------------------------------------------------
__global__ __launch_bounds__(256) void k_prepw(const float* __restrict__ W1,
    const float* __restrict__ W2, const float* __restrict__ W3,
    ushort_* __restrict__ Wt1, ushort_* __restrict__ Wt2, ushort_* __restrict__ Wt3)
{
    __shared__ float L[64 * 132];
    const int blk = blockIdx.x, t = threadIdx.x;

    if (blk < 8) {
        for (int it = 0; it < 8; ++it) {
            int i = t + 256 * it;
            int ri = i >> 5, f4 = i & 31;
            int m = ri >> 3, cr = ri & 7;
            *(float4*)&L[ri * 132 + 4 * f4] =
                *(const float4*)&W1[(size_t)(64 * m + 8 * blk + cr) * H_ + 4 * f4];
        }
        __syncthreads();
        int f = t >> 1, half = t & 1;
        uint_ buf[16];
#pragma unroll
        for (int jj = 0; jj < 16; ++jj) {
            int k0 = 32 * half + 2 * jj;
            int c0 = k0 >> 3, m0 = k0 & 7;
            int c1 = (k0 + 1) >> 3, m1 = (k0 + 1) & 7;
            buf[jj] = (uint_)f2bf(L[(m0 * 8 + c0) * 132 + f]) |
                      ((uint_)f2bf(L[(m1 * 8 + c1) * 132 + f]) << 16);
        }
        ushort_* dst = Wt1 + (size_t)f * 512 + 64 * blk + 32 * half;
#pragma unroll
        for (int q = 0; q < 4; ++q) {
            uint4 vv = {buf[4 * q], buf[4 * q + 1], buf[4 * q + 2], buf[4 * q + 3]};
            *(uint4*)&dst[8 * q] = vv;
        }
    } else {
        const float* W = (blk < 10) ? W2 : W3;
        ushort_*     O = (blk < 10) ? Wt2 : Wt3;
        int kb = (blk - 8) & 1;
        for (int it = 0; it < 8; ++it) {
            int i = t + 256 * it;
            int ri = i >> 5, f4 = i & 31;
            *(float4*)&L[ri * 132 + 4 * f4] =
                *(const float4*)&W[(size_t)(64 * kb + ri) * H_ + 4 * f4];
        }
        __syncthreads();
        int f = t >> 1, half = t & 1;
        uint_ buf[16];
#pragma unroll
        for (int jj = 0; jj < 16; ++jj) {
            int k0 = 32 * half + 2 * jj;
            buf[jj] = (uint_)f2bf(L[k0 * 132 + f]) |
                      ((uint_)f2bf(L[(k0 + 1) * 132 + f]) << 16);
        }
        ushort_* dst = O + (size_t)f * 128 + 64 * kb + 32 * half;
#pragma unroll
        for (int q = 0; q < 4; ++q) {
            uint4 vv = {buf[4 * q], buf[4 * q + 1], buf[4 * q + 2], buf[4 * q + 3]};
            *(uint4*)&dst[8 * q] = vv;
        }
    }
}

// ---------------------------------------------------------------------------
// Shared MFMA epilogue (unchanged)
// ---------------------------------------------------------------------------
__device__ __forceinline__ void mfma_epilogue(char* smem, int b, int t,
    f4v acc[8], const float* __restrict__ bias, const ushort_* __restrict__ Mb,
    ushort_* __restrict__ Zout, float* __restrict__ bnpart)
{
    const int l = t & 63, w = t >> 6;
    const int lr = l & 15, lg = l >> 4;

    ushort_* Yt  = (ushort_*)smem;             // [128][88]
    ushort_* Ml  = (ushort_*)(smem + 22528);   // [64][88]
    ushort_* Zst = (ushort_*)(smem + 33792);   // [64][136]

#pragma unroll
    for (int nt = 0; nt < 8; ++nt) {
        uint2 p;
        p.x = (uint_)f2bf(acc[nt][0]) | ((uint_)f2bf(acc[nt][1]) << 16);
        p.y = (uint_)f2bf(acc[nt][2]) | ((uint_)f2bf(acc[nt][3]) << 16);
        *(uint2*)&Yt[(16 * nt + lr) * 88 + 16 * w + 4 * lg] = p;
    }
#pragma unroll
    for (int it = 0; it < 2; ++it) {
        int i = t + 256 * it;
        int d = i >> 3, seg = i & 7;
        *(uint4*)&Ml[d * 88 + 8 * seg] = *(const uint4*)&Mb[d * 64 + 8 * seg];
    }
    __syncthreads();

    f4v z[8];
#pragma unroll
    for (int nt = 0; nt < 8; ++nt) z[nt] = (f4v)0.f;
#pragma unroll
    for (int cs = 0; cs < 2; ++cs) {
        bf8v mf = *(const bf8v*)&Ml[(16 * w + lr) * 88 + 32 * cs + 8 * lg];
#pragma unroll
        for (int nt = 0; nt < 8; ++nt) {
            bf8v yf = *(const bf8v*)&Yt[(16 * nt + lr) * 88 + 32 * cs + 8 * lg];
            z[nt] = __builtin_amdgcn_mfma_f32_16x16x32_bf16(mf, yf, z[nt], 0, 0, 0);
        }
    }

#pragma unroll
    for (int nt = 0; nt < 8; ++nt) {
        float bv = bias[16 * nt + lr];
#pragma unroll
        for (int reg = 0; reg < 4; ++reg)
            Zst[(16 * w + 4 * lg + reg) * 136 + 16 * nt + lr] = f2bf(z[nt][reg] + bv);
    }
    __syncthreads();

    if (t < 128) {
        float s = 0.f, s2 = 0.f;
        for (int r = 0; r < 64; ++r) {
            float v = bf2f(Zst[r * 136 + t]);
            s += v; s2 += v * v;
        }
        bnpart[b * 256 + t]       = s;
        bnpart[b * 256 + 128 + t] = s2;
    }
#pragma unroll
    for (int it = 0; it < 4; ++it) {
        int i = t + 256 * it;
        int r = i >> 4, seg = i & 15;
        *(uint4*)&Zout[((size_t)(b * 64 + r)) * 128 + 8 * seg] =
            *(const uint4*)&Zst[r * 136 + 8 * seg];
    }
}

// ---------------------------------------------------------------------------
// Layer 1 (unchanged): kappa-permuted K so x[b] is read contiguously once.
// ---------------------------------------------------------------------------
__global__ __launch_bounds__(256) void k_mgemm1(const float* __restrict__ x,
    const ushort_* __restrict__ Wt, const float* __restrict__ bias,
    const ushort_* __restrict__ Mb, ushort_* __restrict__ Zout,
    float* __restrict__ bnpart)
{
    __shared__ __align__(16) char smem[51456];
    ushort_* Al = (ushort_*)smem;              // [16][520] per chunk
    ushort_* Wl = (ushort_*)(smem + 16640);    // [128][136] per chunk

    const int b = blockIdx.x;
    const int t = threadIdx.x;
    const int l = t & 63, w = t >> 6;
    const int lr = l & 15, lg = l >> 4;

    f4v acc[8];
#pragma unroll
    for (int nt = 0; nt < 8; ++nt) acc[nt] = (f4v)0.f;

    const float* xb = x + (size_t)b * (C_ * T_);

    for (int j = 0; j < 4; ++j) {
#pragma unroll
        for (int it = 0; it < 8; ++it) {
            int i = t + 256 * it;
            int cr = i >> 7, t4 = i & 127;
            float4 v = *(const float4*)&xb[(size_t)(16 * j + cr) * T_ + 4 * t4];
            uint2 p;
            p.x = (uint_)f2bf(v.x) | ((uint_)f2bf(v.y) << 16);
            p.y = (uint_)f2bf(v.z) | ((uint_)f2bf(v.w) << 16);
            *(uint2*)&Al[cr * 520 + 4 * t4] = p;
        }
#pragma unroll
        for (int it = 0; it < 8; ++it) {
            int i = t + 256 * it;
            int f = i >> 4, seg = i & 15;
            *(uint4*)&Wl[f * 136 + 8 * seg] =
                *(const uint4*)&Wt[(size_t)f * 512 + 128 * j + 8 * seg];
        }
        __syncthreads();
#pragma unroll
        for (int s = 0; s < 4; ++s) {
            bf8v af = *(const bf8v*)&Al[(4 * s + lg) * 520 + 128 * w + 8 * lr];
#pragma unroll
            for (int nt = 0; nt < 8; ++nt) {
                bf8v bfv = *(const bf8v*)&Wl[(16 * nt + lr) * 136 + 32 * s + 8 * lg];
                acc[nt] = __builtin_amdgcn_mfma_f32_16x16x32_bf16(af, bfv, acc[nt], 0, 0, 0);
            }
        }
        __syncthreads();
    }
    mfma_epilogue(smem, b, t, acc, bias, Mb, Zout, bnpart);
}

// ---------------------------------------------------------------------------
// Layers 2/3 (unchanged)
// ---------------------------------------------------------------------------
__global__ __launch_bounds__(256) void k_mgemm23(const ushort_* __restrict__ Zin,
    const float* __restrict__ ss, const ushort_* __restrict__ Wt,
    const float* __restrict__ bias, const ushort_* __restrict__ Mb,
    ushort_* __restrict__ Zout, float* __restrict__ bnpart)
{
    __shared__ __align__(16) char smem[52224];
    __shared__ float ssL[256];
    ushort_* Al = (ushort_*)smem;              // [64][136]
    ushort_* Wl = (ushort_*)(smem + 17408);    // [128][136]

    const int b = blockIdx.x;
    const int t = threadIdx.x;
    const int l = t & 63, w = t >> 6;
    const int lr = l & 15, lg = l >> 4;

    ssL[t] = ss[t];
    __syncthreads();

    f4v acc[8];
#pragma unroll
    for (int nt = 0; nt < 8; ++nt) acc[nt] = (f4v)0.f;

#pragma unroll
    for (int it = 0; it < 4; ++it) {
        int i = t + 256 * it;
        int r = i >> 4, seg = i & 15;
        uint4 v = *(const uint4*)&Zin[((size_t)(b * 64 + r)) * 128 + 8 * seg];
        uint_ w0[4] = {v.x, v.y, v.z, v.w};
        uint_ o[4];
#pragma unroll
        for (int p = 0; p < 4; ++p) {
            int f0 = 8 * seg + 2 * p;
            float z0 = bf2f((ushort_)(w0[p] & 0xFFFF));
            float z1 = bf2f((ushort_)(w0[p] >> 16));
            float h0 = fmaxf(fmaf(z0, ssL[f0],     ssL[128 + f0]),     0.f);
            float h1 = fmaxf(fmaf(z1, ssL[f0 + 1], ssL[128 + f0 + 1]), 0.f);
            o[p] = (uint_)f2bf(h0) | ((uint_)f2bf(h1) << 16);
        }
        uint4 ov = {o[0], o[1], o[2], o[3]};
        *(uint4*)&Al[r * 136 + 8 * seg] = ov;
    }
#pragma unroll
    for (int it = 0; it < 8; ++it) {
        int i = t + 256 * it;
        int f = i >> 4, seg = i & 15;
        *(uint4*)&Wl[f * 136 + 8 * seg] =
            *(const uint4*)&Wt[(size_t)f * 128 + 8 * seg];
    }
    __syncthreads();
#pragma unroll
    for (int s = 0; s < 4; ++s) {
        bf8v af = *(const bf8v*)&Al[(16 * w + lr) * 136 + 32 * s + 8 * lg];
#pragma unroll
        for (int nt = 0; nt < 8; ++nt) {
            bf8v bfv = *(const bf8v*)&Wl[(16 * nt + lr) * 136 + 32 * s + 8 * lg];
            acc[nt] = __builtin_amdgcn_mfma_f32_16x16x32_bf16(af, bfv, acc[nt], 0, 0, 0);
        }
    }
    __syncthreads();
    mfma_epilogue(smem, b, t, acc, bias, Mb, Zout, bnpart);
}

// ---------------------------------------------------------------------------
// BN reduce stage A (unchanged)
// ---------------------------------------------------------------------------
__global__ __launch_bounds__(256) void k_bnA(const float* __restrict__ bnpart,
                                             double* __restrict__ bnp2)
{
    const int t = threadIdx.x, g = blockIdx.x;
    double a = 0.0;
    for (int i = 0; i < 16; ++i)
        a += (double)bnpart[(size_t)(16 * g + i) * 256 + t];
    bnp2[(size_t)g * 256 + t] = a;
}

// ---------------------------------------------------------------------------
// BN reduce stage B + finalize (unchanged)
// ---------------------------------------------------------------------------
__global__ __launch_bounds__(256) void k_bnB(const double* __restrict__ bnp2,
    const float* __restrict__ g, const float* __restrict__ be, float* __restrict__ ss)
{
    __shared__ double sums[256];
    const int t = threadIdx.x;
    double a = 0.0;
    for (int q = 0; q < 32; ++q) a += bnp2[(size_t)q * 256 + t];
    sums[t] = a;
    __syncthreads();
    if (t < 128) {
        double s = sums[t], s2 = sums[128 + t];
        double mean = s * (1.0 / 32768.0);
        double var  = s2 * (1.0 / 32768.0) - mean * mean;
        double rstd = 1.0 / sqrt(var + 1e-5);
        float sc = (float)((double)g[t] * rstd);
        ss[t]       = sc;
        ss[128 + t] = (float)((double)be[t] - mean * (double)sc);
    }
}

// ---------------------------------------------------------------------------
// Final BN + ReLU (unchanged)
// ---------------------------------------------------------------------------
__global__ __launch_bounds__(256) void k_out(const ushort_* __restrict__ Z,
    const float* __restrict__ ss, float* __restrict__ out)
{
    int i = blockIdx.x * 256 + threadIdx.x;
    int n = i >> 4, seg = i & 15;
    uint4 v = *(const uint4*)&Z[(size_t)n * 128 + 8 * seg];
    float4 sc0 = *(const float4*)&ss[8 * seg];
    float4 sc1 = *(const float4*)&ss[8 * seg + 4];
    float4 sh0 = *(const float4*)&ss[128 + 8 * seg];
    float4 sh1 = *(const float4*)&ss[128 + 8 * seg + 4];
    uint_ wv[4] = {v.x, v.y, v.z, v.w};
    float zz[8];
#pragma unroll
    for (int p = 0; p < 4; ++p) {
        zz[2 * p]     = bf2f((ushort_)(wv[p] & 0xFFFF));
        zz[2 * p + 1] = bf2f((ushort_)(wv[p] >> 16));
    }
    float4 o0, o1;
    o0.x = fmaxf(fmaf(zz[0], sc0.x, sh0.x), 0.f);
    o0.y = fmaxf(fmaf(zz[1], sc0.y, sh0.y), 0.f);
    o0.z = fmaxf(fmaf(zz[2], sc0.z, sh0.z), 0.f);
    o0.w = fmaxf(fmaf(zz[3], sc0.w, sh0.w), 0.f);
    o1.x = fmaxf(fmaf(zz[4], sc1.x, sh1.x), 0.f);
    o1.y = fmaxf(fmaf(zz[5], sc1.y, sh1.y), 0.f);
    o1.z = fmaxf(fmaf(zz[6], sc1.z, sh1.z), 0.f);
    o1.w = fmaxf(fmaf(zz[7], sc1.w, sh1.w), 0.f);
    *(float4*)&out[(size_t)n * 128 + 8 * seg]     = o0;
    *(float4*)&out[(size_t)n * 128 + 8 * seg + 4] = o1;
}

// ---------------------------------------------------------------------------
extern "C" void kernel_launch(void* const* d_in, const int* in_sizes, int n_in,
                              void* d_out, int out_size, void* d_ws, size_t ws_size,
                              hipStream_t stream)
{
    (void)in_sizes; (void)n_in; (void)out_size; (void)ws_size;

    const float* x   = (const float*)d_in[0];
    const float* W1  = (const float*)d_in[9];
    const float* b1  = (const float*)d_in[10];
    const float* g1  = (const float*)d_in[11];
    const float* be1 = (const float*)d_in[12];
    const float* W2  = (const float*)d_in[13];
    const float* b2  = (const float*)d_in[14];
    const float* g2  = (const float*)d_in[15];
    const float* be2 = (const float*)d_in[16];
    const float* W3  = (const float*)d_in[17];
    const float* b3  = (const float*)d_in[18];
    const float* g3  = (const float*)d_in[19];
    const float* be3 = (const float*)d_in[20];

    char* ws = (char*)d_ws;
    float*   simp   = (float*)(ws + OFF_SIMP);
    double*  simf64 = (double*)(ws + OFF_SIMF64);
    ushort_* Mb     = (ushort_*)(ws + OFF_MB);
    ushort_* Wt1    = (ushort_*)(ws + OFF_WT1);
    ushort_* Wt2    = (ushort_*)(ws + OFF_WT2);
    ushort_* Wt3    = (ushort_*)(ws + OFF_WT3);
    float*   ss1    = (float*)(ws + OFF_SS1);
    float*   ss2    = (float*)(ws + OFF_SS2);
    float*   ss3    = (float*)(ws + OFF_SS3);
    float*   bnpart = (float*)(ws + OFF_BNPART);
    double*  bnp2   = (double*)(ws + OFF_BNP2);
    ushort_* Z1     = (ushort_*)(ws + OFF_Z1);
    ushort_* Z2     = (ushort_*)(ws + OFF_Z2);   // reuses simpart region
    ushort_* Z3     = (ushort_*)(ws + OFF_Z3);
    float*   out    = (float*)d_out;

    k_prepw<<<dim3(12), dim3(256), 0, stream>>>(W1, W2, W3, Wt1, Wt2, Wt3);
    k_gram<<<dim3(512), dim3(256), 0, stream>>>(x, simp);
    k_simreduce<<<dim3(256), dim3(256), 0, stream>>>(simp, simf64);
    k_graph<<<dim3(1), dim3(256), 0, stream>>>(simf64, Mb);

    k_mgemm1<<<dim3(512), dim3(256), 0, stream>>>(x, Wt1, b1, Mb, Z1, bnpart);
    k_bnA<<<dim3(32), dim3(256), 0, stream>>>(bnpart, bnp2);
    k_bnB<<<dim3(1), dim3(256), 0, stream>>>(bnp2, g1, be1, ss1);

    k_mgemm23<<<dim3(512), dim3(256), 0, stream>>>(Z1, ss1, Wt2, b2, Mb, Z2, bnpart);
    k_bnA<<<dim3(32), dim3(256), 0, stream>>>(bnpart, bnp2);
    k_bnB<<<dim3(1), dim3(256), 0, stream>>>(bnp2, g2, be2, ss2);

    k_mgemm23<<<dim3(512), dim3(256), 0, stream>>>(Z2, ss2, Wt3, b3, Mb, Z3, bnpart);
    k_bnA<<<dim3(32), dim3(256), 0, stream>>>(bnpart, bnp2);
    k_bnB<<<dim3(1), dim3(256), 0, stream>>>(bnp2, g3, be3, ss3);

    k_out<<<dim3(2048), dim3(256), 0, stream>>>(Z3, ss3, out);
}

// Round 5
// 107.061 us; speedup vs baseline: 3.3072x; 1.4383x over previous
//
#include <hip/hip_runtime.h>
#include <math.h>

// Problem constants
#define B_  512
#define C_  64
#define T_  512
#define H_  128
#define N_  (B_*C_)   // 32768

typedef unsigned int   uint_;
typedef unsigned short ushort_;
typedef unsigned long long ull_;

typedef __attribute__((ext_vector_type(8))) short bf8v;   // 8 bf16 (4 VGPRs)
typedef __attribute__((ext_vector_type(4))) float f4v;    // MFMA accumulator

// Workspace byte offsets (total ~26 MB; harness provides >= 34 MB)
#define OFF_SIMP   0u            // 512*4096*4 = 8,388,608 ; reused as Z2 later
#define OFF_Z2     0u
#define OFF_Z1     8388608u      // 8,388,608 (bf16 32768x128)
#define OFF_Z3     16777216u     // 8,388,608
#define OFF_WT1    25165824u     // 128*512*2 = 131,072
#define OFF_WT2    25296896u     // 32,768
#define OFF_WT3    25329664u     // 32,768
#define OFF_MASKS  25362432u     // 64*8 = 512
#define OFF_MB     25395200u     // 8,192
#define OFF_SS1    25403392u
#define OFF_SS2    25404416u
#define OFF_SS3    25405440u
#define OFF_BNPART 25406464u     // 512*256*4 = 524,288 -> end 25,930,752
#define OFF_BNP2   25930752u     // 32*256*8  = 65,536  -> end 25,996,288

__device__ __forceinline__ ushort_ f2bf(float f) {
    uint_ u = __float_as_uint(f);
    u = (u + 0x7FFFu + ((u >> 16) & 1u)) >> 16;    // RNE (finite values only)
    return (ushort_)u;
}
__device__ __forceinline__ float bf2f(ushort_ s) {
    return __uint_as_float(((uint_)s) << 16);
}

// ---------------------------------------------------------------------------
// Kernel 1: per-batch cosine gram via split-precision bf16 MFMA (unchanged).
// ---------------------------------------------------------------------------
__global__ __launch_bounds__(256) void k_gram(const float* __restrict__ x,
                                              float* __restrict__ simpart)
{
    __shared__ ushort_ Xh[64 * 136];
    __shared__ ushort_ Xl[64 * 136];
    __shared__ float  gd[64];
    __shared__ double rn[64];

    const int b = blockIdx.x;
    const int t = threadIdx.x;
    const int w = t >> 6, l = t & 63;
    const int lr = l & 15, lg = l >> 4;
    const int r0 = (w >> 1) * 2, c0 = (w & 1) * 2;   // tile-pair origins

    f4v acc[2][2];
#pragma unroll
    for (int i = 0; i < 2; ++i)
#pragma unroll
        for (int j = 0; j < 2; ++j) acc[i][j] = (f4v)0.f;

    const float* xb = x + (size_t)b * (C_ * T_);

    for (int j = 0; j < 4; ++j) {
#pragma unroll
        for (int it = 0; it < 8; ++it) {
            int i = t + 256 * it;              // 2048 float4s
            int c = i >> 5, t4 = i & 31;
            float4 v = *(const float4*)&xb[(size_t)c * T_ + 128 * j + 4 * t4];
            ushort_ h0 = f2bf(v.x), h1 = f2bf(v.y), h2 = f2bf(v.z), h3 = f2bf(v.w);
            uint2 ph;
            ph.x = (uint_)h0 | ((uint_)h1 << 16);
            ph.y = (uint_)h2 | ((uint_)h3 << 16);
            float e0 = v.x - bf2f(h0), e1 = v.y - bf2f(h1);
            float e2 = v.z - bf2f(h2), e3 = v.w - bf2f(h3);
            uint2 pl;
            pl.x = (uint_)f2bf(e0) | ((uint_)f2bf(e1) << 16);
            pl.y = (uint_)f2bf(e2) | ((uint_)f2bf(e3) << 16);
            *(uint2*)&Xh[c * 136 + 4 * t4] = ph;
            *(uint2*)&Xl[c * 136 + 4 * t4] = pl;
        }
        __syncthreads();

#pragma unroll
        for (int s = 0; s < 4; ++s) {
            bf8v ah[2], al[2], bh[2], bl[2];
#pragma unroll
            for (int i = 0; i < 2; ++i) {
                ah[i] = *(const bf8v*)&Xh[(16 * (r0 + i) + lr) * 136 + 32 * s + 8 * lg];
                al[i] = *(const bf8v*)&Xl[(16 * (r0 + i) + lr) * 136 + 32 * s + 8 * lg];
                bh[i] = *(const bf8v*)&Xh[(16 * (c0 + i) + lr) * 136 + 32 * s + 8 * lg];
                bl[i] = *(const bf8v*)&Xl[(16 * (c0 + i) + lr) * 136 + 32 * s + 8 * lg];
            }
#pragma unroll
            for (int i = 0; i < 2; ++i)
#pragma unroll
                for (int jj = 0; jj < 2; ++jj) {
                    acc[i][jj] = __builtin_amdgcn_mfma_f32_16x16x32_bf16(ah[i], bh[jj], acc[i][jj], 0, 0, 0);
                    acc[i][jj] = __builtin_amdgcn_mfma_f32_16x16x32_bf16(ah[i], bl[jj], acc[i][jj], 0, 0, 0);
                    acc[i][jj] = __builtin_amdgcn_mfma_f32_16x16x32_bf16(al[i], bh[jj], acc[i][jj], 0, 0, 0);
                }
        }
        __syncthreads();
    }

    if (r0 == c0) {
#pragma unroll
        for (int d = 0; d < 2; ++d)
            if (lg == (lr >> 2)) gd[16 * (r0 + d) + lr] = acc[d][d][lr & 3];
    }
    __syncthreads();
    if (t < 64) rn[t] = 1.0 / fmax(sqrt((double)gd[t]), 1e-12);
    __syncthreads();

    float* sp = simpart + (size_t)b * 4096;
#pragma unroll
    for (int i = 0; i < 2; ++i)
#pragma unroll
        for (int jj = 0; jj < 2; ++jj)
#pragma unroll
            for (int reg = 0; reg < 4; ++reg) {
                int rc = 16 * (r0 + i) + 4 * lg + reg;
                int cc = 16 * (c0 + jj) + lr;
                sp[rc * 64 + cc] = (float)((double)acc[i][jj][reg] * rn[rc] * rn[cc]);
            }
}

// ---------------------------------------------------------------------------
// Kernel 2 (NEW): fused batch-reduction + rank-select top-K. 64 blocks, one
// per row c. 256 thr = 4 waves; wave g sums batches b == g (mod 4) of
// sim[.][c][d] (coalesced 256B reads), f64 LDS tree, then wave 0 does the
// rank-select from LDS broadcasts (no global latency, no bpermute).
// rank(d) = #{d' : v[d'] > v[d] || (v[d'] == v[d] && d' < d)}; chosen iff
// rank < 16  == lax.top_k selection (value desc, index asc).
// Scaling by 1/512 dropped: rank-invariant, sim unused elsewhere.
// ---------------------------------------------------------------------------
__global__ __launch_bounds__(256) void k_simrank(const float* __restrict__ simpart,
                                                 ull_* __restrict__ masks)
{
    __shared__ double part[4][64];
    __shared__ double sd[64];
    const int c = blockIdx.x;
    const int t = threadIdx.x;
    const int d = t & 63, g = t >> 6;

    double a = 0.0;
    const float* sp = simpart + (size_t)c * 64 + d;
    for (int i = 0; i < 128; ++i)
        a += (double)sp[(size_t)(g + 4 * i) * 4096];
    part[g][d] = a;
    __syncthreads();

    if (t < 64) {
        double s = ((part[0][t] + part[1][t]) + part[2][t]) + part[3][t];
        sd[t] = s;
        // intra-wave LDS visibility: compiler orders via lgkmcnt
        int rank = 0;
#pragma unroll
        for (int dp = 0; dp < 64; ++dp) {
            double w = sd[dp];
            rank += (w > s || (w == s && dp < t)) ? 1 : 0;
        }
        ull_ m = __ballot(rank < 16);
        if (t == 0) masks[c] = m;
    }
}

// ---------------------------------------------------------------------------
// Kernel 3 (NEW): masks -> degrees (ballot column-popcount) -> Mb bf16.
// 1 block, 256 threads; critical path ~1 global round-trip + ~500 ops.
// ---------------------------------------------------------------------------
__global__ __launch_bounds__(256) void k_mkM(const ull_* __restrict__ masks,
                                             ushort_* __restrict__ Mbout)
{
    __shared__ ull_  nbrm[64];
    __shared__ float dv[64];
    const int t = threadIdx.x;

    if (t < 64) {                      // wave 0 only
        ull_ mask = masks[t];
        nbrm[t] = mask;
        int deg = 1;                   // self-loop
#pragma unroll
        for (int d = 0; d < 64; ++d) {
            ull_ bal = __ballot((int)((mask >> d) & 1ull));
            if (t == d) deg += (int)__popcll(bal);
        }
        dv[t] = 1.0f / sqrtf((float)deg);
    }
    __syncthreads();

    const int d = t >> 2, q = t & 3;   // thread builds Mb[d][16q..16q+15]
    const float dvd = dv[d];
    uint_ buf[8];
#pragma unroll
    for (int p = 0; p < 8; ++p) {
        int c0 = 16 * q + 2 * p, c1 = c0 + 1;
        float w0 = (float)((int)((nbrm[c0] >> d) & 1ull) + (c0 == d ? 1 : 0));
        float w1 = (float)((int)((nbrm[c1] >> d) & 1ull) + (c1 == d ? 1 : 0));
        buf[p] = (uint_)f2bf(w0 * dv[c0] * dvd) |
                 ((uint_)f2bf(w1 * dv[c1] * dvd) << 16);
    }
    ushort_* dst = Mbout + d * 64 + 16 * q;
    uint4 v0 = {buf[0], buf[1], buf[2], buf[3]};
    uint4 v1 = {buf[4], buf[5], buf[6], buf[7]};
    *(uint4*)&dst[0] = v0;
    *(uint4*)&dst[8] = v1;
}

// ---------------------------------------------------------------------------
// Weight prep (unchanged): bf16 transposed weights.
// ---------------------------------------------------------------------------
__global__ __launch_bounds__(256) void k_prepw(const float* __restrict__ W1,
    const float* __restrict__ W2, const float* __restrict__ W3,
    ushort_* __restrict__ Wt1, ushort_* __restrict__ Wt2, ushort_* __restrict__ Wt3)
{
    __shared__ float L[64 * 132];
    const int blk = blockIdx.x, t = threadIdx.x;

    if (blk < 8) {
        for (int it = 0; it < 8; ++it) {
            int i = t + 256 * it;
            int ri = i >> 5, f4 = i & 31;
            int m = ri >> 3, cr = ri & 7;
            *(float4*)&L[ri * 132 + 4 * f4] =
                *(const float4*)&W1[(size_t)(64 * m + 8 * blk + cr) * H_ + 4 * f4];
        }
        __syncthreads();
        int f = t >> 1, half = t & 1;
        uint_ buf[16];
#pragma unroll
        for (int jj = 0; jj < 16; ++jj) {
            int k0 = 32 * half + 2 * jj;
            int c0 = k0 >> 3, m0 = k0 & 7;
            int c1 = (k0 + 1) >> 3, m1 = (k0 + 1) & 7;
            buf[jj] = (uint_)f2bf(L[(m0 * 8 + c0) * 132 + f]) |
                      ((uint_)f2bf(L[(m1 * 8 + c1) * 132 + f]) << 16);
        }
        ushort_* dst = Wt1 + (size_t)f * 512 + 64 * blk + 32 * half;
#pragma unroll
        for (int q = 0; q < 4; ++q) {
            uint4 vv = {buf[4 * q], buf[4 * q + 1], buf[4 * q + 2], buf[4 * q + 3]};
            *(uint4*)&dst[8 * q] = vv;
        }
    } else {
        const float* W = (blk < 10) ? W2 : W3;
        ushort_*     O = (blk < 10) ? Wt2 : Wt3;
        int kb = (blk - 8) & 1;
        for (int it = 0; it < 8; ++it) {
            int i = t + 256 * it;
            int ri = i >> 5, f4 = i & 31;
            *(float4*)&L[ri * 132 + 4 * f4] =
                *(const float4*)&W[(size_t)(64 * kb + ri) * H_ + 4 * f4];
        }
        __syncthreads();
        int f = t >> 1, half = t & 1;
        uint_ buf[16];
#pragma unroll
        for (int jj = 0; jj < 16; ++jj) {
            int k0 = 32 * half + 2 * jj;
            buf[jj] = (uint_)f2bf(L[k0 * 132 + f]) |
                      ((uint_)f2bf(L[(k0 + 1) * 132 + f]) << 16);
        }
        ushort_* dst = O + (size_t)f * 128 + 64 * kb + 32 * half;
#pragma unroll
        for (int q = 0; q < 4; ++q) {
            uint4 vv = {buf[4 * q], buf[4 * q + 1], buf[4 * q + 2], buf[4 * q + 3]};
            *(uint4*)&dst[8 * q] = vv;
        }
    }
}

// ---------------------------------------------------------------------------
// Shared MFMA epilogue (unchanged)
// ---------------------------------------------------------------------------
__device__ __forceinline__ void mfma_epilogue(char* smem, int b, int t,
    f4v acc[8], const float* __restrict__ bias, const ushort_* __restrict__ Mb,
    ushort_* __restrict__ Zout, float* __restrict__ bnpart)
{
    const int l = t & 63, w = t >> 6;
    const int lr = l & 15, lg = l >> 4;

    ushort_* Yt  = (ushort_*)smem;             // [128][88]
    ushort_* Ml  = (ushort_*)(smem + 22528);   // [64][88]
    ushort_* Zst = (ushort_*)(smem + 33792);   // [64][136]

#pragma unroll
    for (int nt = 0; nt < 8; ++nt) {
        uint2 p;
        p.x = (uint_)f2bf(acc[nt][0]) | ((uint_)f2bf(acc[nt][1]) << 16);
        p.y = (uint_)f2bf(acc[nt][2]) | ((uint_)f2bf(acc[nt][3]) << 16);
        *(uint2*)&Yt[(16 * nt + lr) * 88 + 16 * w + 4 * lg] = p;
    }
#pragma unroll
    for (int it = 0; it < 2; ++it) {
        int i = t + 256 * it;
        int d = i >> 3, seg = i & 7;
        *(uint4*)&Ml[d * 88 + 8 * seg] = *(const uint4*)&Mb[d * 64 + 8 * seg];
    }
    __syncthreads();

    f4v z[8];
#pragma unroll
    for (int nt = 0; nt < 8; ++nt) z[nt] = (f4v)0.f;
#pragma unroll
    for (int cs = 0; cs < 2; ++cs) {
        bf8v mf = *(const bf8v*)&Ml[(16 * w + lr) * 88 + 32 * cs + 8 * lg];
#pragma unroll
        for (int nt = 0; nt < 8; ++nt) {
            bf8v yf = *(const bf8v*)&Yt[(16 * nt + lr) * 88 + 32 * cs + 8 * lg];
            z[nt] = __builtin_amdgcn_mfma_f32_16x16x32_bf16(mf, yf, z[nt], 0, 0, 0);
        }
    }

#pragma unroll
    for (int nt = 0; nt < 8; ++nt) {
        float bv = bias[16 * nt + lr];
#pragma unroll
        for (int reg = 0; reg < 4; ++reg)
            Zst[(16 * w + 4 * lg + reg) * 136 + 16 * nt + lr] = f2bf(z[nt][reg] + bv);
    }
    __syncthreads();

    if (t < 128) {
        float s = 0.f, s2 = 0.f;
        for (int r = 0; r < 64; ++r) {
            float v = bf2f(Zst[r * 136 + t]);
            s += v; s2 += v * v;
        }
        bnpart[b * 256 + t]       = s;
        bnpart[b * 256 + 128 + t] = s2;
    }
#pragma unroll
    for (int it = 0; it < 4; ++it) {
        int i = t + 256 * it;
        int r = i >> 4, seg = i & 15;
        *(uint4*)&Zout[((size_t)(b * 64 + r)) * 128 + 8 * seg] =
            *(const uint4*)&Zst[r * 136 + 8 * seg];
    }
}

// ---------------------------------------------------------------------------
// Layer 1 (unchanged): kappa-permuted K so x[b] is read contiguously once.
// ---------------------------------------------------------------------------
__global__ __launch_bounds__(256) void k_mgemm1(const float* __restrict__ x,
    const ushort_* __restrict__ Wt, const float* __restrict__ bias,
    const ushort_* __restrict__ Mb, ushort_* __restrict__ Zout,
    float* __restrict__ bnpart)
{
    __shared__ __align__(16) char smem[51456];
    ushort_* Al = (ushort_*)smem;              // [16][520] per chunk
    ushort_* Wl = (ushort_*)(smem + 16640);    // [128][136] per chunk

    const int b = blockIdx.x;
    const int t = threadIdx.x;
    const int l = t & 63, w = t >> 6;
    const int lr = l & 15, lg = l >> 4;

    f4v acc[8];
#pragma unroll
    for (int nt = 0; nt < 8; ++nt) acc[nt] = (f4v)0.f;

    const float* xb = x + (size_t)b * (C_ * T_);

    for (int j = 0; j < 4; ++j) {
#pragma unroll
        for (int it = 0; it < 8; ++it) {
            int i = t + 256 * it;
            int cr = i >> 7, t4 = i & 127;
            float4 v = *(const float4*)&xb[(size_t)(16 * j + cr) * T_ + 4 * t4];
            uint2 p;
            p.x = (uint_)f2bf(v.x) | ((uint_)f2bf(v.y) << 16);
            p.y = (uint_)f2bf(v.z) | ((uint_)f2bf(v.w) << 16);
            *(uint2*)&Al[cr * 520 + 4 * t4] = p;
        }
#pragma unroll
        for (int it = 0; it < 8; ++it) {
            int i = t + 256 * it;
            int f = i >> 4, seg = i & 15;
            *(uint4*)&Wl[f * 136 + 8 * seg] =
                *(const uint4*)&Wt[(size_t)f * 512 + 128 * j + 8 * seg];
        }
        __syncthreads();
#pragma unroll
        for (int s = 0; s < 4; ++s) {
            bf8v af = *(const bf8v*)&Al[(4 * s + lg) * 520 + 128 * w + 8 * lr];
#pragma unroll
            for (int nt = 0; nt < 8; ++nt) {
                bf8v bfv = *(const bf8v*)&Wl[(16 * nt + lr) * 136 + 32 * s + 8 * lg];
                acc[nt] = __builtin_amdgcn_mfma_f32_16x16x32_bf16(af, bfv, acc[nt], 0, 0, 0);
            }
        }
        __syncthreads();
    }
    mfma_epilogue(smem, b, t, acc, bias, Mb, Zout, bnpart);
}

// ---------------------------------------------------------------------------
// Layers 2/3 (unchanged)
// ---------------------------------------------------------------------------
__global__ __launch_bounds__(256) void k_mgemm23(const ushort_* __restrict__ Zin,
    const float* __restrict__ ss, const ushort_* __restrict__ Wt,
    const float* __restrict__ bias, const ushort_* __restrict__ Mb,
    ushort_* __restrict__ Zout, float* __restrict__ bnpart)
{
    __shared__ __align__(16) char smem[52224];
    __shared__ float ssL[256];
    ushort_* Al = (ushort_*)smem;              // [64][136]
    ushort_* Wl = (ushort_*)(smem + 17408);    // [128][136]

    const int b = blockIdx.x;
    const int t = threadIdx.x;
    const int l = t & 63, w = t >> 6;
    const int lr = l & 15, lg = l >> 4;

    ssL[t] = ss[t];
    __syncthreads();

    f4v acc[8];
#pragma unroll
    for (int nt = 0; nt < 8; ++nt) acc[nt] = (f4v)0.f;

#pragma unroll
    for (int it = 0; it < 4; ++it) {
        int i = t + 256 * it;
        int r = i >> 4, seg = i & 15;
        uint4 v = *(const uint4*)&Zin[((size_t)(b * 64 + r)) * 128 + 8 * seg];
        uint_ w0[4] = {v.x, v.y, v.z, v.w};
        uint_ o[4];
#pragma unroll
        for (int p = 0; p < 4; ++p) {
            int f0 = 8 * seg + 2 * p;
            float z0 = bf2f((ushort_)(w0[p] & 0xFFFF));
            float z1 = bf2f((ushort_)(w0[p] >> 16));
            float h0 = fmaxf(fmaf(z0, ssL[f0],     ssL[128 + f0]),     0.f);
            float h1 = fmaxf(fmaf(z1, ssL[f0 + 1], ssL[128 + f0 + 1]), 0.f);
            o[p] = (uint_)f2bf(h0) | ((uint_)f2bf(h1) << 16);
        }
        uint4 ov = {o[0], o[1], o[2], o[3]};
        *(uint4*)&Al[r * 136 + 8 * seg] = ov;
    }
#pragma unroll
    for (int it = 0; it < 8; ++it) {
        int i = t + 256 * it;
        int f = i >> 4, seg = i & 15;
        *(uint4*)&Wl[f * 136 + 8 * seg] =
            *(const uint4*)&Wt[(size_t)f * 128 + 8 * seg];
    }
    __syncthreads();
#pragma unroll
    for (int s = 0; s < 4; ++s) {
        bf8v af = *(const bf8v*)&Al[(16 * w + lr) * 136 + 32 * s + 8 * lg];
#pragma unroll
        for (int nt = 0; nt < 8; ++nt) {
            bf8v bfv = *(const bf8v*)&Wl[(16 * nt + lr) * 136 + 32 * s + 8 * lg];
            acc[nt] = __builtin_amdgcn_mfma_f32_16x16x32_bf16(af, bfv, acc[nt], 0, 0, 0);
        }
    }
    __syncthreads();
    mfma_epilogue(smem, b, t, acc, bias, Mb, Zout, bnpart);
}

// ---------------------------------------------------------------------------
// BN reduce stage A (unchanged)
// ---------------------------------------------------------------------------
__global__ __launch_bounds__(256) void k_bnA(const float* __restrict__ bnpart,
                                             double* __restrict__ bnp2)
{
    const int t = threadIdx.x, g = blockIdx.x;
    double a = 0.0;
    for (int i = 0; i < 16; ++i)
        a += (double)bnpart[(size_t)(16 * g + i) * 256 + t];
    bnp2[(size_t)g * 256 + t] = a;
}

// ---------------------------------------------------------------------------
// BN reduce stage B + finalize (unchanged)
// ---------------------------------------------------------------------------
__global__ __launch_bounds__(256) void k_bnB(const double* __restrict__ bnp2,
    const float* __restrict__ g, const float* __restrict__ be, float* __restrict__ ss)
{
    __shared__ double sums[256];
    const int t = threadIdx.x;
    double a = 0.0;
    for (int q = 0; q < 32; ++q) a += bnp2[(size_t)q * 256 + t];
    sums[t] = a;
    __syncthreads();
    if (t < 128) {
        double s = sums[t], s2 = sums[128 + t];
        double mean = s * (1.0 / 32768.0);
        double var  = s2 * (1.0 / 32768.0) - mean * mean;
        double rstd = 1.0 / sqrt(var + 1e-5);
        float sc = (float)((double)g[t] * rstd);
        ss[t]       = sc;
        ss[128 + t] = (float)((double)be[t] - mean * (double)sc);
    }
}

// ---------------------------------------------------------------------------
// Final BN + ReLU (unchanged)
// ---------------------------------------------------------------------------
__global__ __launch_bounds__(256) void k_out(const ushort_* __restrict__ Z,
    const float* __restrict__ ss, float* __restrict__ out)
{
    int i = blockIdx.x * 256 + threadIdx.x;
    int n = i >> 4, seg = i & 15;
    uint4 v = *(const uint4*)&Z[(size_t)n * 128 + 8 * seg];
    float4 sc0 = *(const float4*)&ss[8 * seg];
    float4 sc1 = *(const float4*)&ss[8 * seg + 4];
    float4 sh0 = *(const float4*)&ss[128 + 8 * seg];
    float4 sh1 = *(const float4*)&ss[128 + 8 * seg + 4];
    uint_ wv[4] = {v.x, v.y, v.z, v.w};
    float zz[8];
#pragma unroll
    for (int p = 0; p < 4; ++p) {
        zz[2 * p]     = bf2f((ushort_)(wv[p] & 0xFFFF));
        zz[2 * p + 1] = bf2f((ushort_)(wv[p] >> 16));
    }
    float4 o0, o1;
    o0.x = fmaxf(fmaf(zz[0], sc0.x, sh0.x), 0.f);
    o0.y = fmaxf(fmaf(zz[1], sc0.y, sh0.y), 0.f);
    o0.z = fmaxf(fmaf(zz[2], sc0.z, sh0.z), 0.f);
    o0.w = fmaxf(fmaf(zz[3], sc0.w, sh0.w), 0.f);
    o1.x = fmaxf(fmaf(zz[4], sc1.x, sh1.x), 0.f);
    o1.y = fmaxf(fmaf(zz[5], sc1.y, sh1.y), 0.f);
    o1.z = fmaxf(fmaf(zz[6], sc1.z, sh1.z), 0.f);
    o1.w = fmaxf(fmaf(zz[7], sc1.w, sh1.w), 0.f);
    *(float4*)&out[(size_t)n * 128 + 8 * seg]     = o0;
    *(float4*)&out[(size_t)n * 128 + 8 * seg + 4] = o1;
}

// ---------------------------------------------------------------------------
extern "C" void kernel_launch(void* const* d_in, const int* in_sizes, int n_in,
                              void* d_out, int out_size, void* d_ws, size_t ws_size,
                              hipStream_t stream)
{
    (void)in_sizes; (void)n_in; (void)out_size; (void)ws_size;

    const float* x   = (const float*)d_in[0];
    const float* W1  = (const float*)d_in[9];
    const float* b1  = (const float*)d_in[10];
    const float* g1  = (const float*)d_in[11];
    const float* be1 = (const float*)d_in[12];
    const float* W2  = (const float*)d_in[13];
    const float* b2  = (const float*)d_in[14];
    const float* g2  = (const float*)d_in[15];
    const float* be2 = (const float*)d_in[16];
    const float* W3  = (const float*)d_in[17];
    const float* b3  = (const float*)d_in[18];
    const float* g3  = (const float*)d_in[19];
    const float* be3 = (const float*)d_in[20];

    char* ws = (char*)d_ws;
    float*   simp   = (float*)(ws + OFF_SIMP);
    ull_*    masks  = (ull_*)(ws + OFF_MASKS);
    ushort_* Mb     = (ushort_*)(ws + OFF_MB);
    ushort_* Wt1    = (ushort_*)(ws + OFF_WT1);
    ushort_* Wt2    = (ushort_*)(ws + OFF_WT2);
    ushort_* Wt3    = (ushort_*)(ws + OFF_WT3);
    float*   ss1    = (float*)(ws + OFF_SS1);
    float*   ss2    = (float*)(ws + OFF_SS2);
    float*   ss3    = (float*)(ws + OFF_SS3);
    float*   bnpart = (float*)(ws + OFF_BNPART);
    double*  bnp2   = (double*)(ws + OFF_BNP2);
    ushort_* Z1     = (ushort_*)(ws + OFF_Z1);
    ushort_* Z2     = (ushort_*)(ws + OFF_Z2);   // reuses simpart region
    ushort_* Z3     = (ushort_*)(ws + OFF_Z3);
    float*   out    = (float*)d_out;

    k_prepw<<<dim3(12), dim3(256), 0, stream>>>(W1, W2, W3, Wt1, Wt2, Wt3);
    k_gram<<<dim3(512), dim3(256), 0, stream>>>(x, simp);
    k_simrank<<<dim3(64), dim3(256), 0, stream>>>(simp, masks);
    k_mkM<<<dim3(1), dim3(256), 0, stream>>>(masks, Mb);

    k_mgemm1<<<dim3(512), dim3(256), 0, stream>>>(x, Wt1, b1, Mb, Z1, bnpart);
    k_bnA<<<dim3(32), dim3(256), 0, stream>>>(bnpart, bnp2);
    k_bnB<<<dim3(1), dim3(256), 0, stream>>>(bnp2, g1, be1, ss1);

    k_mgemm23<<<dim3(512), dim3(256), 0, stream>>>(Z1, ss1, Wt2, b2, Mb, Z2, bnpart);
    k_bnA<<<dim3(32), dim3(256), 0, stream>>>(bnpart, bnp2);
    k_bnB<<<dim3(1), dim3(256), 0, stream>>>(bnp2, g2, be2, ss2);

    k_mgemm23<<<dim3(512), dim3(256), 0, stream>>>(Z2, ss2, Wt3, b3, Mb, Z3, bnpart);
    k_bnA<<<dim3(32), dim3(256), 0, stream>>>(bnpart, bnp2);
    k_bnB<<<dim3(1), dim3(256), 0, stream>>>(bnp2, g3, be3, ss3);

    k_out<<<dim3(2048), dim3(256), 0, stream>>>(Z3, ss3, out);
}

// Round 6
// 99.923 us; speedup vs baseline: 3.5434x; 1.0714x over previous
//
#include <hip/hip_runtime.h>
#include <math.h>

// Problem constants
#define B_  512
#define C_  64
#define T_  512
#define H_  128
#define N_  (B_*C_)   // 32768

typedef unsigned int   uint_;
typedef unsigned short ushort_;
typedef unsigned long long ull_;

typedef __attribute__((ext_vector_type(8))) short bf8v;   // 8 bf16 (4 VGPRs)
typedef __attribute__((ext_vector_type(4))) float f4v;    // MFMA accumulator

// Workspace byte offsets
#define OFF_SIMP   0u            // 512*4096*4 = 8,388,608 ; reused as Z2 later
#define OFF_Z2     0u
#define OFF_Z1     8388608u      // 8,388,608 (bf16 32768x128)
#define OFF_Z3     16777216u     // 8,388,608
#define OFF_WT1    25165824u     // 128*512*2 = 131,072
#define OFF_WT2    25296896u     // 32,768
#define OFF_WT3    25329664u     // 32,768
#define OFF_MASKS  25362432u     // 64*8 = 512
#define OFF_BNPART 25406464u     // 512*256*4 = 524,288 -> end 25,930,752
#define OFF_BNP2   25930752u     // 32*256*8  = 65,536  -> end 25,996,288

__device__ __forceinline__ ushort_ f2bf(float f) {
    uint_ u = __float_as_uint(f);
    u = (u + 0x7FFFu + ((u >> 16) & 1u)) >> 16;    // RNE (finite values only)
    return (ushort_)u;
}
__device__ __forceinline__ float bf2f(ushort_ s) {
    return __uint_as_float(((uint_)s) << 16);
}

// ---------------------------------------------------------------------------
// Inline graph-matrix preamble (replaces k_mkM): wave 0 computes degrees via
// ballot column-popcount; every thread then builds its 16 bf16 M-entries
// (row d = t>>2, cols 16*(t&3)..+16) into 8 packed uints held in VGPRs.
// Must be followed by the caller's __syncthreads() before m8 build reads LDS.
// ---------------------------------------------------------------------------
__device__ __forceinline__ void m_preamble_wave0(const ull_* __restrict__ masks,
                                                 ull_* nbrmS, float* dvS, int t)
{
    if (t < 64) {
        ull_ mask = masks[t];
        nbrmS[t] = mask;
        int deg = 1;                   // self-loop
#pragma unroll
        for (int d = 0; d < 64; ++d) {
            ull_ bal = __ballot((int)((mask >> d) & 1ull));
            if (t == d) deg += (int)__popcll(bal);
        }
        dvS[t] = 1.0f / sqrtf((float)deg);
    }
}

__device__ __forceinline__ void m_build(const ull_* nbrmS, const float* dvS,
                                        int t, uint_ m8[8])
{
    const int d = t >> 2, q = t & 3;
    const float dvd = dvS[d];
#pragma unroll
    for (int p = 0; p < 8; ++p) {
        int c0 = 16 * q + 2 * p, c1 = c0 + 1;
        float w0 = (float)((int)((nbrmS[c0] >> d) & 1ull) + (c0 == d ? 1 : 0));
        float w1 = (float)((int)((nbrmS[c1] >> d) & 1ull) + (c1 == d ? 1 : 0));
        m8[p] = (uint_)f2bf(w0 * dvS[c0] * dvd) |
                ((uint_)f2bf(w1 * dvS[c1] * dvd) << 16);
    }
}

// ---------------------------------------------------------------------------
// Kernel 1 (FUSED): blocks <512 = per-batch split-precision bf16 MFMA gram;
// blocks 512..523 = bf16 transposed weight prep (old k_prepw).
// ---------------------------------------------------------------------------
__global__ __launch_bounds__(256) void k_gramw(const float* __restrict__ x,
    float* __restrict__ simpart,
    const float* __restrict__ W1, const float* __restrict__ W2,
    const float* __restrict__ W3,
    ushort_* __restrict__ Wt1, ushort_* __restrict__ Wt2, ushort_* __restrict__ Wt3)
{
    __shared__ __align__(16) char smem[35584];
    __shared__ float  gd[64];
    __shared__ double rn[64];
    const int blk = blockIdx.x;
    const int t = threadIdx.x;

    if (blk < 512) {
        ushort_* Xh = (ushort_*)smem;              // [64][136]
        ushort_* Xl = (ushort_*)(smem + 17408);    // [64][136]
        const int b = blk;
        const int w = t >> 6, l = t & 63;
        const int lr = l & 15, lg = l >> 4;
        const int r0 = (w >> 1) * 2, c0 = (w & 1) * 2;

        f4v acc[2][2];
#pragma unroll
        for (int i = 0; i < 2; ++i)
#pragma unroll
            for (int j = 0; j < 2; ++j) acc[i][j] = (f4v)0.f;

        const float* xb = x + (size_t)b * (C_ * T_);

        for (int j = 0; j < 4; ++j) {
#pragma unroll
            for (int it = 0; it < 8; ++it) {
                int i = t + 256 * it;              // 2048 float4s
                int c = i >> 5, t4 = i & 31;
                float4 v = *(const float4*)&xb[(size_t)c * T_ + 128 * j + 4 * t4];
                ushort_ h0 = f2bf(v.x), h1 = f2bf(v.y), h2 = f2bf(v.z), h3 = f2bf(v.w);
                uint2 ph;
                ph.x = (uint_)h0 | ((uint_)h1 << 16);
                ph.y = (uint_)h2 | ((uint_)h3 << 16);
                float e0 = v.x - bf2f(h0), e1 = v.y - bf2f(h1);
                float e2 = v.z - bf2f(h2), e3 = v.w - bf2f(h3);
                uint2 pl;
                pl.x = (uint_)f2bf(e0) | ((uint_)f2bf(e1) << 16);
                pl.y = (uint_)f2bf(e2) | ((uint_)f2bf(e3) << 16);
                *(uint2*)&Xh[c * 136 + 4 * t4] = ph;
                *(uint2*)&Xl[c * 136 + 4 * t4] = pl;
            }
            __syncthreads();

#pragma unroll
            for (int s = 0; s < 4; ++s) {
                bf8v ah[2], al[2], bh[2], bl[2];
#pragma unroll
                for (int i = 0; i < 2; ++i) {
                    ah[i] = *(const bf8v*)&Xh[(16 * (r0 + i) + lr) * 136 + 32 * s + 8 * lg];
                    al[i] = *(const bf8v*)&Xl[(16 * (r0 + i) + lr) * 136 + 32 * s + 8 * lg];
                    bh[i] = *(const bf8v*)&Xh[(16 * (c0 + i) + lr) * 136 + 32 * s + 8 * lg];
                    bl[i] = *(const bf8v*)&Xl[(16 * (c0 + i) + lr) * 136 + 32 * s + 8 * lg];
                }
#pragma unroll
                for (int i = 0; i < 2; ++i)
#pragma unroll
                    for (int jj = 0; jj < 2; ++jj) {
                        acc[i][jj] = __builtin_amdgcn_mfma_f32_16x16x32_bf16(ah[i], bh[jj], acc[i][jj], 0, 0, 0);
                        acc[i][jj] = __builtin_amdgcn_mfma_f32_16x16x32_bf16(ah[i], bl[jj], acc[i][jj], 0, 0, 0);
                        acc[i][jj] = __builtin_amdgcn_mfma_f32_16x16x32_bf16(al[i], bh[jj], acc[i][jj], 0, 0, 0);
                    }
            }
            __syncthreads();
        }

        if (r0 == c0) {
#pragma unroll
            for (int d = 0; d < 2; ++d)
                if (lg == (lr >> 2)) gd[16 * (r0 + d) + lr] = acc[d][d][lr & 3];
        }
        __syncthreads();
        if (t < 64) rn[t] = 1.0 / fmax(sqrt((double)gd[t]), 1e-12);
        __syncthreads();

        float* sp = simpart + (size_t)b * 4096;
#pragma unroll
        for (int i = 0; i < 2; ++i)
#pragma unroll
            for (int jj = 0; jj < 2; ++jj)
#pragma unroll
                for (int reg = 0; reg < 4; ++reg) {
                    int rc = 16 * (r0 + i) + 4 * lg + reg;
                    int cc = 16 * (c0 + jj) + lr;
                    sp[rc * 64 + cc] = (float)((double)acc[i][jj][reg] * rn[rc] * rn[cc]);
                }
    } else {
        // ---- weight prep (old k_prepw), pblk in 0..11 ----
        float* L = (float*)smem;                   // [64][132]
        const int pblk = blk - 512;
        if (pblk < 8) {
            for (int it = 0; it < 8; ++it) {
                int i = t + 256 * it;
                int ri = i >> 5, f4 = i & 31;
                int m = ri >> 3, cr = ri & 7;
                *(float4*)&L[ri * 132 + 4 * f4] =
                    *(const float4*)&W1[(size_t)(64 * m + 8 * pblk + cr) * H_ + 4 * f4];
            }
            __syncthreads();
            int f = t >> 1, half = t & 1;
            uint_ buf[16];
#pragma unroll
            for (int jj = 0; jj < 16; ++jj) {
                int k0 = 32 * half + 2 * jj;
                int c0 = k0 >> 3, m0 = k0 & 7;
                int c1 = (k0 + 1) >> 3, m1 = (k0 + 1) & 7;
                buf[jj] = (uint_)f2bf(L[(m0 * 8 + c0) * 132 + f]) |
                          ((uint_)f2bf(L[(m1 * 8 + c1) * 132 + f]) << 16);
            }
            ushort_* dst = Wt1 + (size_t)f * 512 + 64 * pblk + 32 * half;
#pragma unroll
            for (int q = 0; q < 4; ++q) {
                uint4 vv = {buf[4 * q], buf[4 * q + 1], buf[4 * q + 2], buf[4 * q + 3]};
                *(uint4*)&dst[8 * q] = vv;
            }
        } else {
            const float* W = (pblk < 10) ? W2 : W3;
            ushort_*     O = (pblk < 10) ? Wt2 : Wt3;
            int kb = (pblk - 8) & 1;
            for (int it = 0; it < 8; ++it) {
                int i = t + 256 * it;
                int ri = i >> 5, f4 = i & 31;
                *(float4*)&L[ri * 132 + 4 * f4] =
                    *(const float4*)&W[(size_t)(64 * kb + ri) * H_ + 4 * f4];
            }
            __syncthreads();
            int f = t >> 1, half = t & 1;
            uint_ buf[16];
#pragma unroll
            for (int jj = 0; jj < 16; ++jj) {
                int k0 = 32 * half + 2 * jj;
                buf[jj] = (uint_)f2bf(L[k0 * 132 + f]) |
                          ((uint_)f2bf(L[(k0 + 1) * 132 + f]) << 16);
            }
            ushort_* dst = O + (size_t)f * 128 + 64 * kb + 32 * half;
#pragma unroll
            for (int q = 0; q < 4; ++q) {
                uint4 vv = {buf[4 * q], buf[4 * q + 1], buf[4 * q + 2], buf[4 * q + 3]};
                *(uint4*)&dst[8 * q] = vv;
            }
        }
    }
}

// ---------------------------------------------------------------------------
// Kernel 2: fused batch-reduction + rank-select top-K (unchanged).
// ---------------------------------------------------------------------------
__global__ __launch_bounds__(256) void k_simrank(const float* __restrict__ simpart,
                                                 ull_* __restrict__ masks)
{
    __shared__ double part[4][64];
    __shared__ double sd[64];
    const int c = blockIdx.x;
    const int t = threadIdx.x;
    const int d = t & 63, g = t >> 6;

    double a = 0.0;
    const float* sp = simpart + (size_t)c * 64 + d;
    for (int i = 0; i < 128; ++i)
        a += (double)sp[(size_t)(g + 4 * i) * 4096];
    part[g][d] = a;
    __syncthreads();

    if (t < 64) {
        double s = ((part[0][t] + part[1][t]) + part[2][t]) + part[3][t];
        sd[t] = s;
        int rank = 0;
#pragma unroll
        for (int dp = 0; dp < 64; ++dp) {
            double w = sd[dp];
            rank += (w > s || (w == s && dp < t)) ? 1 : 0;
        }
        ull_ m = __ballot(rank < 16);
        if (t == 0) masks[c] = m;
    }
}

// ---------------------------------------------------------------------------
// Shared MFMA epilogue: Ml now written from per-thread registers (m8).
// ---------------------------------------------------------------------------
__device__ __forceinline__ void mfma_epilogue(char* smem, int b, int t,
    f4v acc[8], const float* __restrict__ bias, const uint_ m8[8],
    ushort_* __restrict__ Zout, float* __restrict__ bnpart)
{
    const int l = t & 63, w = t >> 6;
    const int lr = l & 15, lg = l >> 4;

    ushort_* Yt  = (ushort_*)smem;             // [128][88]
    ushort_* Ml  = (ushort_*)(smem + 22528);   // [64][88]
    ushort_* Zst = (ushort_*)(smem + 33792);   // [64][136]

#pragma unroll
    for (int nt = 0; nt < 8; ++nt) {
        uint2 p;
        p.x = (uint_)f2bf(acc[nt][0]) | ((uint_)f2bf(acc[nt][1]) << 16);
        p.y = (uint_)f2bf(acc[nt][2]) | ((uint_)f2bf(acc[nt][3]) << 16);
        *(uint2*)&Yt[(16 * nt + lr) * 88 + 16 * w + 4 * lg] = p;
    }
    // Ml from registers: thread t owns row d=t>>2, cols 16*(t&3)..+16
    {
        const int d = t >> 2, q = t & 3;
        uint4 v0 = {m8[0], m8[1], m8[2], m8[3]};
        uint4 v1 = {m8[4], m8[5], m8[6], m8[7]};
        *(uint4*)&Ml[d * 88 + 16 * q]     = v0;
        *(uint4*)&Ml[d * 88 + 16 * q + 8] = v1;
    }
    __syncthreads();

    f4v z[8];
#pragma unroll
    for (int nt = 0; nt < 8; ++nt) z[nt] = (f4v)0.f;
#pragma unroll
    for (int cs = 0; cs < 2; ++cs) {
        bf8v mf = *(const bf8v*)&Ml[(16 * w + lr) * 88 + 32 * cs + 8 * lg];
#pragma unroll
        for (int nt = 0; nt < 8; ++nt) {
            bf8v yf = *(const bf8v*)&Yt[(16 * nt + lr) * 88 + 32 * cs + 8 * lg];
            z[nt] = __builtin_amdgcn_mfma_f32_16x16x32_bf16(mf, yf, z[nt], 0, 0, 0);
        }
    }

#pragma unroll
    for (int nt = 0; nt < 8; ++nt) {
        float bv = bias[16 * nt + lr];
#pragma unroll
        for (int reg = 0; reg < 4; ++reg)
            Zst[(16 * w + 4 * lg + reg) * 136 + 16 * nt + lr] = f2bf(z[nt][reg] + bv);
    }
    __syncthreads();

    if (t < 128) {
        float s = 0.f, s2 = 0.f;
        for (int r = 0; r < 64; ++r) {
            float v = bf2f(Zst[r * 136 + t]);
            s += v; s2 += v * v;
        }
        bnpart[b * 256 + t]       = s;
        bnpart[b * 256 + 128 + t] = s2;
    }
#pragma unroll
    for (int it = 0; it < 4; ++it) {
        int i = t + 256 * it;
        int r = i >> 4, seg = i & 15;
        *(uint4*)&Zout[((size_t)(b * 64 + r)) * 128 + 8 * seg] =
            *(const uint4*)&Zst[r * 136 + 8 * seg];
    }
}

// ---------------------------------------------------------------------------
// Layer 1: kappa-permuted K GEMM + inline-M preamble.
// ---------------------------------------------------------------------------
__global__ __launch_bounds__(256) void k_mgemm1(const float* __restrict__ x,
    const ushort_* __restrict__ Wt, const float* __restrict__ bias,
    const ull_* __restrict__ masks, ushort_* __restrict__ Zout,
    float* __restrict__ bnpart)
{
    __shared__ __align__(16) char smem[51456];
    __shared__ ull_  nbrmS[64];
    __shared__ float dvS[64];
    ushort_* Al = (ushort_*)smem;              // [16][520] per chunk
    ushort_* Wl = (ushort_*)(smem + 16640);    // [128][136] per chunk

    const int b = blockIdx.x;
    const int t = threadIdx.x;
    const int l = t & 63, w = t >> 6;
    const int lr = l & 15, lg = l >> 4;

    m_preamble_wave0(masks, nbrmS, dvS, t);

    f4v acc[8];
#pragma unroll
    for (int nt = 0; nt < 8; ++nt) acc[nt] = (f4v)0.f;

    const float* xb = x + (size_t)b * (C_ * T_);

    for (int j = 0; j < 4; ++j) {
#pragma unroll
        for (int it = 0; it < 8; ++it) {
            int i = t + 256 * it;
            int cr = i >> 7, t4 = i & 127;
            float4 v = *(const float4*)&xb[(size_t)(16 * j + cr) * T_ + 4 * t4];
            uint2 p;
            p.x = (uint_)f2bf(v.x) | ((uint_)f2bf(v.y) << 16);
            p.y = (uint_)f2bf(v.z) | ((uint_)f2bf(v.w) << 16);
            *(uint2*)&Al[cr * 520 + 4 * t4] = p;
        }
#pragma unroll
        for (int it = 0; it < 8; ++it) {
            int i = t + 256 * it;
            int f = i >> 4, seg = i & 15;
            *(uint4*)&Wl[f * 136 + 8 * seg] =
                *(const uint4*)&Wt[(size_t)f * 512 + 128 * j + 8 * seg];
        }
        __syncthreads();
#pragma unroll
        for (int s = 0; s < 4; ++s) {
            bf8v af = *(const bf8v*)&Al[(4 * s + lg) * 520 + 128 * w + 8 * lr];
#pragma unroll
            for (int nt = 0; nt < 8; ++nt) {
                bf8v bfv = *(const bf8v*)&Wl[(16 * nt + lr) * 136 + 32 * s + 8 * lg];
                acc[nt] = __builtin_amdgcn_mfma_f32_16x16x32_bf16(af, bfv, acc[nt], 0, 0, 0);
            }
        }
        __syncthreads();
    }

    uint_ m8[8];
    m_build(nbrmS, dvS, t, m8);   // LDS written by wave0 pre-loop; syncs passed since
    mfma_epilogue(smem, b, t, acc, bias, m8, Zout, bnpart);
}

// ---------------------------------------------------------------------------
// Layers 2/3: inline BN-finalize (from bnp2) + inline-M + GEMM.
// ---------------------------------------------------------------------------
__global__ __launch_bounds__(256) void k_mgemm23(const ushort_* __restrict__ Zin,
    const double* __restrict__ bnp2, const float* __restrict__ g,
    const float* __restrict__ be, const ushort_* __restrict__ Wt,
    const float* __restrict__ bias, const ull_* __restrict__ masks,
    ushort_* __restrict__ Zout, float* __restrict__ bnpart)
{
    __shared__ __align__(16) char smem[52224];
    __shared__ float ssL[256];
    __shared__ ull_  nbrmS[64];
    __shared__ float dvS[64];
    ushort_* Al = (ushort_*)smem;              // [64][136]
    ushort_* Wl = (ushort_*)(smem + 17408);    // [128][136]

    const int b = blockIdx.x;
    const int t = threadIdx.x;
    const int l = t & 63, w = t >> 6;
    const int lr = l & 15, lg = l >> 4;

    // --- BN finalize preamble: sums overlay the (not-yet-used) Al region ---
    {
        double* sumsL = (double*)smem;         // 256 f64 = 2 KB, temporary
        double a = 0.0;
        for (int q = 0; q < 32; ++q) a += bnp2[(size_t)q * 256 + t];
        sumsL[t] = a;
        m_preamble_wave0(masks, nbrmS, dvS, t);
        __syncthreads();
        if (t < 128) {
            double s = sumsL[t], s2 = sumsL[128 + t];
            double mean = s * (1.0 / 32768.0);
            double var  = s2 * (1.0 / 32768.0) - mean * mean;
            double rstd = 1.0 / sqrt(var + 1e-5);
            float sc = (float)((double)g[t] * rstd);
            ssL[t]       = sc;
            ssL[128 + t] = (float)((double)be[t] - mean * (double)sc);
        }
        __syncthreads();
    }

    f4v acc[8];
#pragma unroll
    for (int nt = 0; nt < 8; ++nt) acc[nt] = (f4v)0.f;

    // stage A with BN fold + relu
#pragma unroll
    for (int it = 0; it < 4; ++it) {
        int i = t + 256 * it;
        int r = i >> 4, seg = i & 15;
        uint4 v = *(const uint4*)&Zin[((size_t)(b * 64 + r)) * 128 + 8 * seg];
        uint_ w0[4] = {v.x, v.y, v.z, v.w};
        uint_ o[4];
#pragma unroll
        for (int p = 0; p < 4; ++p) {
            int f0 = 8 * seg + 2 * p;
            float z0 = bf2f((ushort_)(w0[p] & 0xFFFF));
            float z1 = bf2f((ushort_)(w0[p] >> 16));
            float h0 = fmaxf(fmaf(z0, ssL[f0],     ssL[128 + f0]),     0.f);
            float h1 = fmaxf(fmaf(z1, ssL[f0 + 1], ssL[128 + f0 + 1]), 0.f);
            o[p] = (uint_)f2bf(h0) | ((uint_)f2bf(h1) << 16);
        }
        uint4 ov = {o[0], o[1], o[2], o[3]};
        *(uint4*)&Al[r * 136 + 8 * seg] = ov;
    }
#pragma unroll
    for (int it = 0; it < 8; ++it) {
        int i = t + 256 * it;
        int f = i >> 4, seg = i & 15;
        *(uint4*)&Wl[f * 136 + 8 * seg] =
            *(const uint4*)&Wt[(size_t)f * 128 + 8 * seg];
    }
    __syncthreads();
#pragma unroll
    for (int s = 0; s < 4; ++s) {
        bf8v af = *(const bf8v*)&Al[(16 * w + lr) * 136 + 32 * s + 8 * lg];
#pragma unroll
        for (int nt = 0; nt < 8; ++nt) {
            bf8v bfv = *(const bf8v*)&Wl[(16 * nt + lr) * 136 + 32 * s + 8 * lg];
            acc[nt] = __builtin_amdgcn_mfma_f32_16x16x32_bf16(af, bfv, acc[nt], 0, 0, 0);
        }
    }
    __syncthreads();

    uint_ m8[8];
    m_build(nbrmS, dvS, t, m8);
    mfma_epilogue(smem, b, t, acc, bias, m8, Zout, bnpart);
}

// ---------------------------------------------------------------------------
// BN reduce stage A (unchanged): 32 blocks, 512 -> 32 partials in f64.
// ---------------------------------------------------------------------------
__global__ __launch_bounds__(256) void k_bnA(const float* __restrict__ bnpart,
                                             double* __restrict__ bnp2)
{
    const int t = threadIdx.x, g = blockIdx.x;
    double a = 0.0;
    for (int i = 0; i < 16; ++i)
        a += (double)bnpart[(size_t)(16 * g + i) * 256 + t];
    bnp2[(size_t)g * 256 + t] = a;
}

// ---------------------------------------------------------------------------
// Final BN + ReLU with inline BN-finalize: 512 blocks, 64 nodes each.
// ---------------------------------------------------------------------------
__global__ __launch_bounds__(256) void k_out(const ushort_* __restrict__ Z,
    const double* __restrict__ bnp2, const float* __restrict__ g,
    const float* __restrict__ be, float* __restrict__ out)
{
    __shared__ double sumsL[256];
    __shared__ float  ssL[256];
    const int b = blockIdx.x;
    const int t = threadIdx.x;

    double a = 0.0;
    for (int q = 0; q < 32; ++q) a += bnp2[(size_t)q * 256 + t];
    sumsL[t] = a;
    __syncthreads();
    if (t < 128) {
        double s = sumsL[t], s2 = sumsL[128 + t];
        double mean = s * (1.0 / 32768.0);
        double var  = s2 * (1.0 / 32768.0) - mean * mean;
        double rstd = 1.0 / sqrt(var + 1e-5);
        float sc = (float)((double)g[t] * rstd);
        ssL[t]       = sc;
        ssL[128 + t] = (float)((double)be[t] - mean * (double)sc);
    }
    __syncthreads();

    const size_t base = (size_t)b * 64 * 128;
#pragma unroll
    for (int it = 0; it < 8; ++it) {
        int i = t + 256 * it;            // 2048: (row r, float4-seg s)
        int r = i >> 5, s = i & 31;
        uint2 v = *(const uint2*)&Z[base + (size_t)r * 128 + 4 * s];
        float4 sc = *(const float4*)&ssL[4 * s];
        float4 sh = *(const float4*)&ssL[128 + 4 * s];
        float z0 = bf2f((ushort_)(v.x & 0xFFFF));
        float z1 = bf2f((ushort_)(v.x >> 16));
        float z2 = bf2f((ushort_)(v.y & 0xFFFF));
        float z3 = bf2f((ushort_)(v.y >> 16));
        float4 o;
        o.x = fmaxf(fmaf(z0, sc.x, sh.x), 0.f);
        o.y = fmaxf(fmaf(z1, sc.y, sh.y), 0.f);
        o.z = fmaxf(fmaf(z2, sc.z, sh.z), 0.f);
        o.w = fmaxf(fmaf(z3, sc.w, sh.w), 0.f);
        *(float4*)&out[base + (size_t)r * 128 + 4 * s] = o;
    }
}

// ---------------------------------------------------------------------------
extern "C" void kernel_launch(void* const* d_in, const int* in_sizes, int n_in,
                              void* d_out, int out_size, void* d_ws, size_t ws_size,
                              hipStream_t stream)
{
    (void)in_sizes; (void)n_in; (void)out_size; (void)ws_size;

    const float* x   = (const float*)d_in[0];
    const float* W1  = (const float*)d_in[9];
    const float* b1  = (const float*)d_in[10];
    const float* g1  = (const float*)d_in[11];
    const float* be1 = (const float*)d_in[12];
    const float* W2  = (const float*)d_in[13];
    const float* b2  = (const float*)d_in[14];
    const float* g2  = (const float*)d_in[15];
    const float* be2 = (const float*)d_in[16];
    const float* W3  = (const float*)d_in[17];
    const float* b3  = (const float*)d_in[18];
    const float* g3  = (const float*)d_in[19];
    const float* be3 = (const float*)d_in[20];

    char* ws = (char*)d_ws;
    float*   simp   = (float*)(ws + OFF_SIMP);
    ull_*    masks  = (ull_*)(ws + OFF_MASKS);
    ushort_* Wt1    = (ushort_*)(ws + OFF_WT1);
    ushort_* Wt2    = (ushort_*)(ws + OFF_WT2);
    ushort_* Wt3    = (ushort_*)(ws + OFF_WT3);
    float*   bnpart = (float*)(ws + OFF_BNPART);
    double*  bnp2   = (double*)(ws + OFF_BNP2);
    ushort_* Z1     = (ushort_*)(ws + OFF_Z1);
    ushort_* Z2     = (ushort_*)(ws + OFF_Z2);   // reuses simp region
    ushort_* Z3     = (ushort_*)(ws + OFF_Z3);
    float*   out    = (float*)d_out;

    k_gramw<<<dim3(524), dim3(256), 0, stream>>>(x, simp, W1, W2, W3, Wt1, Wt2, Wt3);
    k_simrank<<<dim3(64), dim3(256), 0, stream>>>(simp, masks);

    k_mgemm1<<<dim3(512), dim3(256), 0, stream>>>(x, Wt1, b1, masks, Z1, bnpart);
    k_bnA<<<dim3(32), dim3(256), 0, stream>>>(bnpart, bnp2);

    k_mgemm23<<<dim3(512), dim3(256), 0, stream>>>(Z1, bnp2, g1, be1, Wt2, b2, masks, Z2, bnpart);
    k_bnA<<<dim3(32), dim3(256), 0, stream>>>(bnpart, bnp2);

    k_mgemm23<<<dim3(512), dim3(256), 0, stream>>>(Z2, bnp2, g2, be2, Wt3, b3, masks, Z3, bnpart);
    k_bnA<<<dim3(32), dim3(256), 0, stream>>>(bnpart, bnp2);

    k_out<<<dim3(512), dim3(256), 0, stream>>>(Z3, bnp2, g3, be3, out);
}

// Round 7
// 99.020 us; speedup vs baseline: 3.5758x; 1.0091x over previous
//
#include <hip/hip_runtime.h>
#include <math.h>

// Problem constants
#define B_  512
#define C_  64
#define T_  512
#define H_  128
#define N_  (B_*C_)   // 32768

typedef unsigned int   uint_;
typedef unsigned short ushort_;
typedef unsigned long long ull_;

typedef __attribute__((ext_vector_type(8))) short bf8v;   // 8 bf16 (4 VGPRs)
typedef __attribute__((ext_vector_type(4))) float f4v;    // MFMA accumulator

// Workspace byte offsets (ws >= 256 MB per harness fill profile)
#define OFF_SIMP   0u            // 512*4096*4 = 8,388,608 ; reused as Z2 later
#define OFF_Z2     0u
#define OFF_Z1     8388608u      // 8,388,608 (bf16 32768x128)
#define OFF_Z3     16777216u     // 8,388,608
#define OFF_WT1    25165824u     // 128*512*2 = 131,072
#define OFF_WT2    25296896u     // 32,768
#define OFF_WT3    25329664u     // 32,768
#define OFF_MASKS  25362432u     // 64*8 = 512
#define OFF_BNPART 25406464u     // 512*256*4 = 524,288 -> end 25,930,752
#define OFF_BNP2   25930752u     // 32*256*8  = 65,536  -> end 25,996,288
#define OFF_XH     33554432u     // 512*64*512*2 = 33,554,432 -> end 67,108,864

__device__ __forceinline__ ushort_ f2bf(float f) {
    uint_ u = __float_as_uint(f);
    u = (u + 0x7FFFu + ((u >> 16) & 1u)) >> 16;    // RNE (finite values only)
    return (ushort_)u;
}
__device__ __forceinline__ float bf2f(ushort_ s) {
    return __uint_as_float(((uint_)s) << 16);
}

// global -> LDS direct DMA, 16 bytes per lane. LDS dest must be
// wave-uniform-base + lane*16 (callers pass base + t*16, linear in t).
__device__ __forceinline__ void gload_lds16(const void* g, void* l) {
    __builtin_amdgcn_global_load_lds(
        (const __attribute__((address_space(1))) void*)g,
        (__attribute__((address_space(3))) void*)l, 16, 0, 0);
}

// ---------------------------------------------------------------------------
// Inline graph-matrix preamble: wave 0 computes degrees via ballot
// column-popcount; m_build later makes per-thread bf16 M entries.
// ---------------------------------------------------------------------------
__device__ __forceinline__ void m_preamble_wave0(const ull_* __restrict__ masks,
                                                 ull_* nbrmS, float* dvS, int t)
{
    if (t < 64) {
        ull_ mask = masks[t];
        nbrmS[t] = mask;
        int deg = 1;                   // self-loop
#pragma unroll
        for (int d = 0; d < 64; ++d) {
            ull_ bal = __ballot((int)((mask >> d) & 1ull));
            if (t == d) deg += (int)__popcll(bal);
        }
        dvS[t] = 1.0f / sqrtf((float)deg);
    }
}

__device__ __forceinline__ void m_build(const ull_* nbrmS, const float* dvS,
                                        int t, uint_ m8[8])
{
    const int d = t >> 2, q = t & 3;
    const float dvd = dvS[d];
#pragma unroll
    for (int p = 0; p < 8; ++p) {
        int c0 = 16 * q + 2 * p, c1 = c0 + 1;
        float w0 = (float)((int)((nbrmS[c0] >> d) & 1ull) + (c0 == d ? 1 : 0));
        float w1 = (float)((int)((nbrmS[c1] >> d) & 1ull) + (c1 == d ? 1 : 0));
        m8[p] = (uint_)f2bf(w0 * dvS[c0] * dvd) |
                ((uint_)f2bf(w1 * dvS[c1] * dvd) << 16);
    }
}

// ---------------------------------------------------------------------------
// Kernel 1 (FUSED): blocks <512 = per-batch split-precision bf16 MFMA gram,
// now ALSO persisting Xh (bf16 hi of x) to global [b][c][512] for k_mgemm1.
// Blocks 512..523 = bf16 transposed weight prep.
// ---------------------------------------------------------------------------
__global__ __launch_bounds__(256) void k_gramw(const float* __restrict__ x,
    float* __restrict__ simpart, ushort_* __restrict__ Xhg,
    const float* __restrict__ W1, const float* __restrict__ W2,
    const float* __restrict__ W3,
    ushort_* __restrict__ Wt1, ushort_* __restrict__ Wt2, ushort_* __restrict__ Wt3)
{
    __shared__ __align__(16) char smem[35584];
    __shared__ float  gd[64];
    __shared__ double rn[64];
    const int blk = blockIdx.x;
    const int t = threadIdx.x;

    if (blk < 512) {
        ushort_* Xh = (ushort_*)smem;              // [64][136]
        ushort_* Xl = (ushort_*)(smem + 17408);    // [64][136]
        const int b = blk;
        const int w = t >> 6, l = t & 63;
        const int lr = l & 15, lg = l >> 4;
        const int r0 = (w >> 1) * 2, c0 = (w & 1) * 2;

        f4v acc[2][2];
#pragma unroll
        for (int i = 0; i < 2; ++i)
#pragma unroll
            for (int j = 0; j < 2; ++j) acc[i][j] = (f4v)0.f;

        const float* xb = x + (size_t)b * (C_ * T_);

        for (int j = 0; j < 4; ++j) {
#pragma unroll
            for (int it = 0; it < 8; ++it) {
                int i = t + 256 * it;              // 2048 float4s
                int c = i >> 5, t4 = i & 31;
                float4 v = *(const float4*)&xb[(size_t)c * T_ + 128 * j + 4 * t4];
                ushort_ h0 = f2bf(v.x), h1 = f2bf(v.y), h2 = f2bf(v.z), h3 = f2bf(v.w);
                uint2 ph;
                ph.x = (uint_)h0 | ((uint_)h1 << 16);
                ph.y = (uint_)h2 | ((uint_)h3 << 16);
                float e0 = v.x - bf2f(h0), e1 = v.y - bf2f(h1);
                float e2 = v.z - bf2f(h2), e3 = v.w - bf2f(h3);
                uint2 pl;
                pl.x = (uint_)f2bf(e0) | ((uint_)f2bf(e1) << 16);
                pl.y = (uint_)f2bf(e2) | ((uint_)f2bf(e3) << 16);
                *(uint2*)&Xh[c * 136 + 4 * t4] = ph;
                *(uint2*)&Xl[c * 136 + 4 * t4] = pl;
                // persist hi bits for layer-1 GEMM (bit-identical reuse)
                *(uint2*)&Xhg[(((size_t)(b * 64 + c)) << 9) + 128 * j + 4 * t4] = ph;
            }
            __syncthreads();

#pragma unroll
            for (int s = 0; s < 4; ++s) {
                bf8v ah[2], al[2], bh[2], bl[2];
#pragma unroll
                for (int i = 0; i < 2; ++i) {
                    ah[i] = *(const bf8v*)&Xh[(16 * (r0 + i) + lr) * 136 + 32 * s + 8 * lg];
                    al[i] = *(const bf8v*)&Xl[(16 * (r0 + i) + lr) * 136 + 32 * s + 8 * lg];
                    bh[i] = *(const bf8v*)&Xh[(16 * (c0 + i) + lr) * 136 + 32 * s + 8 * lg];
                    bl[i] = *(const bf8v*)&Xl[(16 * (c0 + i) + lr) * 136 + 32 * s + 8 * lg];
                }
#pragma unroll
                for (int i = 0; i < 2; ++i)
#pragma unroll
                    for (int jj = 0; jj < 2; ++jj) {
                        acc[i][jj] = __builtin_amdgcn_mfma_f32_16x16x32_bf16(ah[i], bh[jj], acc[i][jj], 0, 0, 0);
                        acc[i][jj] = __builtin_amdgcn_mfma_f32_16x16x32_bf16(ah[i], bl[jj], acc[i][jj], 0, 0, 0);
                        acc[i][jj] = __builtin_amdgcn_mfma_f32_16x16x32_bf16(al[i], bh[jj], acc[i][jj], 0, 0, 0);
                    }
            }
            __syncthreads();
        }

        if (r0 == c0) {
#pragma unroll
            for (int d = 0; d < 2; ++d)
                if (lg == (lr >> 2)) gd[16 * (r0 + d) + lr] = acc[d][d][lr & 3];
        }
        __syncthreads();
        if (t < 64) rn[t] = 1.0 / fmax(sqrt((double)gd[t]), 1e-12);
        __syncthreads();

        float* sp = simpart + (size_t)b * 4096;
#pragma unroll
        for (int i = 0; i < 2; ++i)
#pragma unroll
            for (int jj = 0; jj < 2; ++jj)
#pragma unroll
                for (int reg = 0; reg < 4; ++reg) {
                    int rc = 16 * (r0 + i) + 4 * lg + reg;
                    int cc = 16 * (c0 + jj) + lr;
                    sp[rc * 64 + cc] = (float)((double)acc[i][jj][reg] * rn[rc] * rn[cc]);
                }
    } else {
        // ---- weight prep, pblk in 0..11 ----
        float* L = (float*)smem;                   // [64][132]
        const int pblk = blk - 512;
        if (pblk < 8) {
            for (int it = 0; it < 8; ++it) {
                int i = t + 256 * it;
                int ri = i >> 5, f4 = i & 31;
                int m = ri >> 3, cr = ri & 7;
                *(float4*)&L[ri * 132 + 4 * f4] =
                    *(const float4*)&W1[(size_t)(64 * m + 8 * pblk + cr) * H_ + 4 * f4];
            }
            __syncthreads();
            int f = t >> 1, half = t & 1;
            uint_ buf[16];
#pragma unroll
            for (int jj = 0; jj < 16; ++jj) {
                int k0 = 32 * half + 2 * jj;
                int c0 = k0 >> 3, m0 = k0 & 7;
                int c1 = (k0 + 1) >> 3, m1 = (k0 + 1) & 7;
                buf[jj] = (uint_)f2bf(L[(m0 * 8 + c0) * 132 + f]) |
                          ((uint_)f2bf(L[(m1 * 8 + c1) * 132 + f]) << 16);
            }
            ushort_* dst = Wt1 + (size_t)f * 512 + 64 * pblk + 32 * half;
#pragma unroll
            for (int q = 0; q < 4; ++q) {
                uint4 vv = {buf[4 * q], buf[4 * q + 1], buf[4 * q + 2], buf[4 * q + 3]};
                *(uint4*)&dst[8 * q] = vv;
            }
        } else {
            const float* W = (pblk < 10) ? W2 : W3;
            ushort_*     O = (pblk < 10) ? Wt2 : Wt3;
            int kb = (pblk - 8) & 1;
            for (int it = 0; it < 8; ++it) {
                int i = t + 256 * it;
                int ri = i >> 5, f4 = i & 31;
                *(float4*)&L[ri * 132 + 4 * f4] =
                    *(const float4*)&W[(size_t)(64 * kb + ri) * H_ + 4 * f4];
            }
            __syncthreads();
            int f = t >> 1, half = t & 1;
            uint_ buf[16];
#pragma unroll
            for (int jj = 0; jj < 16; ++jj) {
                int k0 = 32 * half + 2 * jj;
                buf[jj] = (uint_)f2bf(L[k0 * 132 + f]) |
                          ((uint_)f2bf(L[(k0 + 1) * 132 + f]) << 16);
            }
            ushort_* dst = O + (size_t)f * 128 + 64 * kb + 32 * half;
#pragma unroll
            for (int q = 0; q < 4; ++q) {
                uint4 vv = {buf[4 * q], buf[4 * q + 1], buf[4 * q + 2], buf[4 * q + 3]};
                *(uint4*)&dst[8 * q] = vv;
            }
        }
    }
}

// ---------------------------------------------------------------------------
// Kernel 2: fused batch-reduction + rank-select top-K. Now 1024 threads
// (16-way batch split) for memory-level parallelism on its 64 blocks.
// ---------------------------------------------------------------------------
__global__ __launch_bounds__(1024) void k_simrank(const float* __restrict__ simpart,
                                                  ull_* __restrict__ masks)
{
    __shared__ double part[16][64];
    __shared__ double sd[64];
    const int c = blockIdx.x;
    const int t = threadIdx.x;
    const int d = t & 63, g = t >> 6;

    double a = 0.0;
    const float* sp = simpart + (size_t)c * 64 + d;
    for (int i = 0; i < 32; ++i)
        a += (double)sp[(size_t)(g + 16 * i) * 4096];
    part[g][d] = a;
    __syncthreads();

    if (t < 64) {
        double s = 0.0;
#pragma unroll
        for (int q = 0; q < 16; ++q) s += part[q][t];
        sd[t] = s;
        int rank = 0;
#pragma unroll
        for (int dp = 0; dp < 64; ++dp) {
            double w = sd[dp];
            rank += (w > s || (w == s && dp < t)) ? 1 : 0;
        }
        ull_ m = __ballot(rank < 16);
        if (t == 0) masks[c] = m;
    }
}

// ---------------------------------------------------------------------------
// Shared MFMA epilogue (unchanged): Z = M@Y + bias, BN partials, Z store.
// ---------------------------------------------------------------------------
__device__ __forceinline__ void mfma_epilogue(char* smem, int b, int t,
    f4v acc[8], const float* __restrict__ bias, const uint_ m8[8],
    ushort_* __restrict__ Zout, float* __restrict__ bnpart)
{
    const int l = t & 63, w = t >> 6;
    const int lr = l & 15, lg = l >> 4;

    ushort_* Yt  = (ushort_*)smem;             // [128][88]
    ushort_* Ml  = (ushort_*)(smem + 22528);   // [64][88]
    ushort_* Zst = (ushort_*)(smem + 33792);   // [64][136]

#pragma unroll
    for (int nt = 0; nt < 8; ++nt) {
        uint2 p;
        p.x = (uint_)f2bf(acc[nt][0]) | ((uint_)f2bf(acc[nt][1]) << 16);
        p.y = (uint_)f2bf(acc[nt][2]) | ((uint_)f2bf(acc[nt][3]) << 16);
        *(uint2*)&Yt[(16 * nt + lr) * 88 + 16 * w + 4 * lg] = p;
    }
    {
        const int d = t >> 2, q = t & 3;
        uint4 v0 = {m8[0], m8[1], m8[2], m8[3]};
        uint4 v1 = {m8[4], m8[5], m8[6], m8[7]};
        *(uint4*)&Ml[d * 88 + 16 * q]     = v0;
        *(uint4*)&Ml[d * 88 + 16 * q + 8] = v1;
    }
    __syncthreads();

    f4v z[8];
#pragma unroll
    for (int nt = 0; nt < 8; ++nt) z[nt] = (f4v)0.f;
#pragma unroll
    for (int cs = 0; cs < 2; ++cs) {
        bf8v mf = *(const bf8v*)&Ml[(16 * w + lr) * 88 + 32 * cs + 8 * lg];
#pragma unroll
        for (int nt = 0; nt < 8; ++nt) {
            bf8v yf = *(const bf8v*)&Yt[(16 * nt + lr) * 88 + 32 * cs + 8 * lg];
            z[nt] = __builtin_amdgcn_mfma_f32_16x16x32_bf16(mf, yf, z[nt], 0, 0, 0);
        }
    }

#pragma unroll
    for (int nt = 0; nt < 8; ++nt) {
        float bv = bias[16 * nt + lr];
#pragma unroll
        for (int reg = 0; reg < 4; ++reg)
            Zst[(16 * w + 4 * lg + reg) * 136 + 16 * nt + lr] = f2bf(z[nt][reg] + bv);
    }
    __syncthreads();

    if (t < 128) {
        float s = 0.f, s2 = 0.f;
        for (int r = 0; r < 64; ++r) {
            float v = bf2f(Zst[r * 136 + t]);
            s += v; s2 += v * v;
        }
        bnpart[b * 256 + t]       = s;
        bnpart[b * 256 + 128 + t] = s2;
    }
#pragma unroll
    for (int it = 0; it < 4; ++it) {
        int i = t + 256 * it;
        int r = i >> 4, seg = i & 15;
        *(uint4*)&Zout[((size_t)(b * 64 + r)) * 128 + 8 * seg] =
            *(const uint4*)&Zst[r * 136 + 8 * seg];
    }
}

// ---------------------------------------------------------------------------
// Layer 1: A and W staged via global_load_lds DMA (no VALU, no VGPR roundtrip).
// A source = persisted Xh [b][c][512] bf16 (bit-identical to old inline cvt).
// Unpadded LDS tiles: [16][512] and [128][128] — 256B-aligned row strides make
// full-wave ds_read_b128 exactly the 8-cycle bank floor (conflict-free).
// ---------------------------------------------------------------------------
__global__ __launch_bounds__(256) void k_mgemm1(const ushort_* __restrict__ Xh,
    const ushort_* __restrict__ Wt, const float* __restrict__ bias,
    const ull_* __restrict__ masks, ushort_* __restrict__ Zout,
    float* __restrict__ bnpart)
{
    __shared__ __align__(16) char smem[51456];
    __shared__ ull_  nbrmS[64];
    __shared__ float dvS[64];
    ushort_* Al = (ushort_*)smem;              // [16][512] per chunk
    ushort_* Wl = (ushort_*)(smem + 16384);    // [128][128] per chunk

    const int b = blockIdx.x;
    const int t = threadIdx.x;
    const int l = t & 63, w = t >> 6;
    const int lr = l & 15, lg = l >> 4;

    m_preamble_wave0(masks, nbrmS, dvS, t);

    f4v acc[8];
#pragma unroll
    for (int nt = 0; nt < 8; ++nt) acc[nt] = (f4v)0.f;

    for (int j = 0; j < 4; ++j) {
        // A chunk: channels [16j,16j+16) x T as bf16, linear 16 KB stream
        {
            const char* asrc = (const char*)(Xh + (((size_t)(b * 64 + 16 * j)) << 9)) + t * 16;
            char* adst = smem + t * 16;
#pragma unroll
            for (int i2 = 0; i2 < 4; ++i2)
                gload_lds16(asrc + i2 * 4096, adst + i2 * 4096);
        }
        // W chunk: Wl[f][128] <- Wt[f][128j..+128]; 16 f-rows per call
        {
            const int fr = t >> 4, seg = t & 15;
            const char* wsrc = (const char*)(Wt + (size_t)fr * 512 + 128 * j + seg * 8);
            char* wdst = smem + 16384 + t * 16;
#pragma unroll
            for (int i2 = 0; i2 < 8; ++i2)
                gload_lds16(wsrc + i2 * 16384, wdst + i2 * 4096);
        }
        __syncthreads();
#pragma unroll
        for (int s = 0; s < 4; ++s) {
            bf8v af = *(const bf8v*)&Al[(4 * s + lg) * 512 + 128 * w + 8 * lr];
#pragma unroll
            for (int nt = 0; nt < 8; ++nt) {
                bf8v bfv = *(const bf8v*)&Wl[(16 * nt + lr) * 128 + 32 * s + 8 * lg];
                acc[nt] = __builtin_amdgcn_mfma_f32_16x16x32_bf16(af, bfv, acc[nt], 0, 0, 0);
            }
        }
        __syncthreads();
    }

    uint_ m8[8];
    m_build(nbrmS, dvS, t, m8);
    mfma_epilogue(smem, b, t, acc, bias, m8, Zout, bnpart);
}

// ---------------------------------------------------------------------------
// Layers 2/3: inline BN-finalize + inline-M + GEMM; W staged via
// global_load_lds (linear 32 KB), unpadded Wl[128][128].
// ---------------------------------------------------------------------------
__global__ __launch_bounds__(256) void k_mgemm23(const ushort_* __restrict__ Zin,
    const double* __restrict__ bnp2, const float* __restrict__ g,
    const float* __restrict__ be, const ushort_* __restrict__ Wt,
    const float* __restrict__ bias, const ull_* __restrict__ masks,
    ushort_* __restrict__ Zout, float* __restrict__ bnpart)
{
    __shared__ __align__(16) char smem[52224];
    __shared__ float ssL[256];
    __shared__ ull_  nbrmS[64];
    __shared__ float dvS[64];
    ushort_* Al = (ushort_*)smem;              // [64][136]
    ushort_* Wl = (ushort_*)(smem + 17408);    // [128][128]

    const int b = blockIdx.x;
    const int t = threadIdx.x;
    const int l = t & 63, w = t >> 6;
    const int lr = l & 15, lg = l >> 4;

    // --- BN finalize preamble (sums overlay Al region temporarily) ---
    {
        double* sumsL = (double*)smem;
        double a = 0.0;
        for (int q = 0; q < 32; ++q) a += bnp2[(size_t)q * 256 + t];
        sumsL[t] = a;
        m_preamble_wave0(masks, nbrmS, dvS, t);
        __syncthreads();
        if (t < 128) {
            double s = sumsL[t], s2 = sumsL[128 + t];
            double mean = s * (1.0 / 32768.0);
            double var  = s2 * (1.0 / 32768.0) - mean * mean;
            double rstd = 1.0 / sqrt(var + 1e-5);
            float sc = (float)((double)g[t] * rstd);
            ssL[t]       = sc;
            ssL[128 + t] = (float)((double)be[t] - mean * (double)sc);
        }
        __syncthreads();
    }

    // W: linear 32 KB DMA (can overlap the A-staging VALU below)
    {
        const char* wsrc = (const char*)Wt + t * 16;
        char* wdst = smem + 17408 + t * 16;
#pragma unroll
        for (int i2 = 0; i2 < 8; ++i2)
            gload_lds16(wsrc + i2 * 4096, wdst + i2 * 4096);
    }

    f4v acc[8];
#pragma unroll
    for (int nt = 0; nt < 8; ++nt) acc[nt] = (f4v)0.f;

    // stage A with BN fold + relu (conversion required -> manual path)
#pragma unroll
    for (int it = 0; it < 4; ++it) {
        int i = t + 256 * it;
        int r = i >> 4, seg = i & 15;
        uint4 v = *(const uint4*)&Zin[((size_t)(b * 64 + r)) * 128 + 8 * seg];
        uint_ w0[4] = {v.x, v.y, v.z, v.w};
        uint_ o[4];
#pragma unroll
        for (int p = 0; p < 4; ++p) {
            int f0 = 8 * seg + 2 * p;
            float z0 = bf2f((ushort_)(w0[p] & 0xFFFF));
            float z1 = bf2f((ushort_)(w0[p] >> 16));
            float h0 = fmaxf(fmaf(z0, ssL[f0],     ssL[128 + f0]),     0.f);
            float h1 = fmaxf(fmaf(z1, ssL[f0 + 1], ssL[128 + f0 + 1]), 0.f);
            o[p] = (uint_)f2bf(h0) | ((uint_)f2bf(h1) << 16);
        }
        uint4 ov = {o[0], o[1], o[2], o[3]};
        *(uint4*)&Al[r * 136 + 8 * seg] = ov;
    }
    __syncthreads();
#pragma unroll
    for (int s = 0; s < 4; ++s) {
        bf8v af = *(const bf8v*)&Al[(16 * w + lr) * 136 + 32 * s + 8 * lg];
#pragma unroll
        for (int nt = 0; nt < 8; ++nt) {
            bf8v bfv = *(const bf8v*)&Wl[(16 * nt + lr) * 128 + 32 * s + 8 * lg];
            acc[nt] = __builtin_amdgcn_mfma_f32_16x16x32_bf16(af, bfv, acc[nt], 0, 0, 0);
        }
    }
    __syncthreads();

    uint_ m8[8];
    m_build(nbrmS, dvS, t, m8);
    mfma_epilogue(smem, b, t, acc, bias, m8, Zout, bnpart);
}

// ---------------------------------------------------------------------------
// BN reduce stage A (unchanged): 32 blocks, 512 -> 32 partials in f64.
// ---------------------------------------------------------------------------
__global__ __launch_bounds__(256) void k_bnA(const float* __restrict__ bnpart,
                                             double* __restrict__ bnp2)
{
    const int t = threadIdx.x, g = blockIdx.x;
    double a = 0.0;
    for (int i = 0; i < 16; ++i)
        a += (double)bnpart[(size_t)(16 * g + i) * 256 + t];
    bnp2[(size_t)g * 256 + t] = a;
}

// ---------------------------------------------------------------------------
// Final BN + ReLU with inline BN-finalize (unchanged).
// ---------------------------------------------------------------------------
__global__ __launch_bounds__(256) void k_out(const ushort_* __restrict__ Z,
    const double* __restrict__ bnp2, const float* __restrict__ g,
    const float* __restrict__ be, float* __restrict__ out)
{
    __shared__ double sumsL[256];
    __shared__ float  ssL[256];
    const int b = blockIdx.x;
    const int t = threadIdx.x;

    double a = 0.0;
    for (int q = 0; q < 32; ++q) a += bnp2[(size_t)q * 256 + t];
    sumsL[t] = a;
    __syncthreads();
    if (t < 128) {
        double s = sumsL[t], s2 = sumsL[128 + t];
        double mean = s * (1.0 / 32768.0);
        double var  = s2 * (1.0 / 32768.0) - mean * mean;
        double rstd = 1.0 / sqrt(var + 1e-5);
        float sc = (float)((double)g[t] * rstd);
        ssL[t]       = sc;
        ssL[128 + t] = (float)((double)be[t] - mean * (double)sc);
    }
    __syncthreads();

    const size_t base = (size_t)b * 64 * 128;
#pragma unroll
    for (int it = 0; it < 8; ++it) {
        int i = t + 256 * it;
        int r = i >> 5, s = i & 31;
        uint2 v = *(const uint2*)&Z[base + (size_t)r * 128 + 4 * s];
        float4 sc = *(const float4*)&ssL[4 * s];
        float4 sh = *(const float4*)&ssL[128 + 4 * s];
        float z0 = bf2f((ushort_)(v.x & 0xFFFF));
        float z1 = bf2f((ushort_)(v.x >> 16));
        float z2 = bf2f((ushort_)(v.y & 0xFFFF));
        float z3 = bf2f((ushort_)(v.y >> 16));
        float4 o;
        o.x = fmaxf(fmaf(z0, sc.x, sh.x), 0.f);
        o.y = fmaxf(fmaf(z1, sc.y, sh.y), 0.f);
        o.z = fmaxf(fmaf(z2, sc.z, sh.z), 0.f);
        o.w = fmaxf(fmaf(z3, sc.w, sh.w), 0.f);
        *(float4*)&out[base + (size_t)r * 128 + 4 * s] = o;
    }
}

// ---------------------------------------------------------------------------
extern "C" void kernel_launch(void* const* d_in, const int* in_sizes, int n_in,
                              void* d_out, int out_size, void* d_ws, size_t ws_size,
                              hipStream_t stream)
{
    (void)in_sizes; (void)n_in; (void)out_size; (void)ws_size;

    const float* x   = (const float*)d_in[0];
    const float* W1  = (const float*)d_in[9];
    const float* b1  = (const float*)d_in[10];
    const float* g1  = (const float*)d_in[11];
    const float* be1 = (const float*)d_in[12];
    const float* W2  = (const float*)d_in[13];
    const float* b2  = (const float*)d_in[14];
    const float* g2  = (const float*)d_in[15];
    const float* be2 = (const float*)d_in[16];
    const float* W3  = (const float*)d_in[17];
    const float* b3  = (const float*)d_in[18];
    const float* g3  = (const float*)d_in[19];
    const float* be3 = (const float*)d_in[20];

    char* ws = (char*)d_ws;
    float*   simp   = (float*)(ws + OFF_SIMP);
    ull_*    masks  = (ull_*)(ws + OFF_MASKS);
    ushort_* Wt1    = (ushort_*)(ws + OFF_WT1);
    ushort_* Wt2    = (ushort_*)(ws + OFF_WT2);
    ushort_* Wt3    = (ushort_*)(ws + OFF_WT3);
    float*   bnpart = (float*)(ws + OFF_BNPART);
    double*  bnp2   = (double*)(ws + OFF_BNP2);
    ushort_* Xh     = (ushort_*)(ws + OFF_XH);
    ushort_* Z1     = (ushort_*)(ws + OFF_Z1);
    ushort_* Z2     = (ushort_*)(ws + OFF_Z2);   // reuses simp region
    ushort_* Z3     = (ushort_*)(ws + OFF_Z3);
    float*   out    = (float*)d_out;

    k_gramw<<<dim3(524), dim3(256), 0, stream>>>(x, simp, Xh, W1, W2, W3, Wt1, Wt2, Wt3);
    k_simrank<<<dim3(64), dim3(1024), 0, stream>>>(simp, masks);

    k_mgemm1<<<dim3(512), dim3(256), 0, stream>>>(Xh, Wt1, b1, masks, Z1, bnpart);
    k_bnA<<<dim3(32), dim3(256), 0, stream>>>(bnpart, bnp2);

    k_mgemm23<<<dim3(512), dim3(256), 0, stream>>>(Z1, bnp2, g1, be1, Wt2, b2, masks, Z2, bnpart);
    k_bnA<<<dim3(32), dim3(256), 0, stream>>>(bnpart, bnp2);

    k_mgemm23<<<dim3(512), dim3(256), 0, stream>>>(Z2, bnp2, g2, be2, Wt3, b3, masks, Z3, bnpart);
    k_bnA<<<dim3(32), dim3(256), 0, stream>>>(bnpart, bnp2);

    k_out<<<dim3(512), dim3(256), 0, stream>>>(Z3, bnp2, g3, be3, out);
}

// Round 8
// 96.222 us; speedup vs baseline: 3.6797x; 1.0291x over previous
//
#include <hip/hip_runtime.h>
#include <math.h>

// Problem constants
#define B_  512
#define C_  64
#define T_  512
#define H_  128
#define N_  (B_*C_)   // 32768

typedef unsigned int   uint_;
typedef unsigned short ushort_;
typedef unsigned long long ull_;

typedef __attribute__((ext_vector_type(8))) short bf8v;   // 8 bf16 (4 VGPRs)
typedef __attribute__((ext_vector_type(4))) float f4v;    // MFMA accumulator

// Workspace byte offsets (ws >= 256 MB per harness fill profile)
#define OFF_SIMP   0u            // 512*4096*4 = 8,388,608 ; reused as Z2 later
#define OFF_Z2     0u
#define OFF_Z1     8388608u      // 8,388,608 (bf16 32768x128)
#define OFF_Z3     16777216u     // 8,388,608
#define OFF_WT1    25165824u     // 128*512*2 = 131,072
#define OFF_WT2    25296896u     // 32,768
#define OFF_WT3    25329664u     // 32,768
#define OFF_MASKS  25362432u     // 64*8 = 512
#define OFF_BNPART 25406464u     // 512*256*4 = 524,288 -> end 25,930,752
#define OFF_BNP2   25930752u     // 32*256*8  = 65,536  -> end 25,996,288
#define OFF_XH     33554432u     // 512*64*512*2 = 33,554,432 -> end 67,108,864

__device__ __forceinline__ ushort_ f2bf(float f) {
    uint_ u = __float_as_uint(f);
    u = (u + 0x7FFFu + ((u >> 16) & 1u)) >> 16;    // RNE (finite values only)
    return (ushort_)u;
}
__device__ __forceinline__ float bf2f(ushort_ s) {
    return __uint_as_float(((uint_)s) << 16);
}

// global -> LDS direct DMA, 16 bytes per lane (wave-uniform base + lane*16).
__device__ __forceinline__ void gload_lds16(const void* g, void* l) {
    __builtin_amdgcn_global_load_lds(
        (const __attribute__((address_space(1))) void*)g,
        (__attribute__((address_space(3))) void*)l, 16, 0, 0);
}

// ---------------------------------------------------------------------------
// Inline graph-matrix preamble: wave 0 computes degrees via ballot
// column-popcount; m_build later makes per-thread bf16 M entries.
// ---------------------------------------------------------------------------
__device__ __forceinline__ void m_preamble_wave0(const ull_* __restrict__ masks,
                                                 ull_* nbrmS, float* dvS, int t)
{
    if (t < 64) {
        ull_ mask = masks[t];
        nbrmS[t] = mask;
        int deg = 1;                   // self-loop
#pragma unroll
        for (int d = 0; d < 64; ++d) {
            ull_ bal = __ballot((int)((mask >> d) & 1ull));
            if (t == d) deg += (int)__popcll(bal);
        }
        dvS[t] = 1.0f / sqrtf((float)deg);
    }
}

__device__ __forceinline__ void m_build(const ull_* nbrmS, const float* dvS,
                                        int t, uint_ m8[8])
{
    const int d = t >> 2, q = t & 3;
    const float dvd = dvS[d];
#pragma unroll
    for (int p = 0; p < 8; ++p) {
        int c0 = 16 * q + 2 * p, c1 = c0 + 1;
        float w0 = (float)((int)((nbrmS[c0] >> d) & 1ull) + (c0 == d ? 1 : 0));
        float w1 = (float)((int)((nbrmS[c1] >> d) & 1ull) + (c1 == d ? 1 : 0));
        m8[p] = (uint_)f2bf(w0 * dvS[c0] * dvd) |
                ((uint_)f2bf(w1 * dvS[c1] * dvd) << 16);
    }
}

// ---------------------------------------------------------------------------
// Kernel 1 (512 threads / 8 waves): blocks <512 = per-batch split-precision
// bf16 MFMA gram (+ persist Xh); blocks 512..523 = weight prep.
// 16 output tiles split 2-per-wave: wave w -> row-tile rp=w>>1, col-tiles
// 2*(w&1), 2*(w&1)+1. Per-tile K order identical to the 4-wave version
// -> bit-identical results. 8 waves/block raises occupancy 2x (latency fix).
// ---------------------------------------------------------------------------
__global__ __launch_bounds__(512, 4) void k_gramw(const float* __restrict__ x,
    float* __restrict__ simpart, ushort_* __restrict__ Xhg,
    const float* __restrict__ W1, const float* __restrict__ W2,
    const float* __restrict__ W3,
    ushort_* __restrict__ Wt1, ushort_* __restrict__ Wt2, ushort_* __restrict__ Wt3)
{
    __shared__ __align__(16) char smem[35584];
    __shared__ float  gd[64];
    __shared__ double rn[64];
    const int blk = blockIdx.x;
    const int t = threadIdx.x;

    if (blk < 512) {
        ushort_* Xh = (ushort_*)smem;              // [64][136]
        ushort_* Xl = (ushort_*)(smem + 17408);    // [64][136]
        const int b = blk;
        const int w = t >> 6, l = t & 63;
        const int lr = l & 15, lg = l >> 4;
        const int rp = w >> 1, ch = w & 1;         // row-tile, col-half

        f4v acc[2];
#pragma unroll
        for (int i = 0; i < 2; ++i) acc[i] = (f4v)0.f;

        const float* xb = x + (size_t)b * (C_ * T_);

        for (int j = 0; j < 4; ++j) {
#pragma unroll
            for (int it = 0; it < 4; ++it) {
                int i = t + 512 * it;              // 2048 float4s
                int c = i >> 5, t4 = i & 31;
                float4 v = *(const float4*)&xb[(size_t)c * T_ + 128 * j + 4 * t4];
                ushort_ h0 = f2bf(v.x), h1 = f2bf(v.y), h2 = f2bf(v.z), h3 = f2bf(v.w);
                uint2 ph;
                ph.x = (uint_)h0 | ((uint_)h1 << 16);
                ph.y = (uint_)h2 | ((uint_)h3 << 16);
                float e0 = v.x - bf2f(h0), e1 = v.y - bf2f(h1);
                float e2 = v.z - bf2f(h2), e3 = v.w - bf2f(h3);
                uint2 pl;
                pl.x = (uint_)f2bf(e0) | ((uint_)f2bf(e1) << 16);
                pl.y = (uint_)f2bf(e2) | ((uint_)f2bf(e3) << 16);
                *(uint2*)&Xh[c * 136 + 4 * t4] = ph;
                *(uint2*)&Xl[c * 136 + 4 * t4] = pl;
                // persist hi bits for layer-1 GEMM (bit-identical reuse)
                *(uint2*)&Xhg[(((size_t)(b * 64 + c)) << 9) + 128 * j + 4 * t4] = ph;
            }
            __syncthreads();

#pragma unroll
            for (int s = 0; s < 4; ++s) {
                bf8v ah = *(const bf8v*)&Xh[(16 * rp + lr) * 136 + 32 * s + 8 * lg];
                bf8v al = *(const bf8v*)&Xl[(16 * rp + lr) * 136 + 32 * s + 8 * lg];
#pragma unroll
                for (int i = 0; i < 2; ++i) {
                    const int ct = 2 * ch + i;
                    bf8v bh = *(const bf8v*)&Xh[(16 * ct + lr) * 136 + 32 * s + 8 * lg];
                    bf8v bl = *(const bf8v*)&Xl[(16 * ct + lr) * 136 + 32 * s + 8 * lg];
                    acc[i] = __builtin_amdgcn_mfma_f32_16x16x32_bf16(ah, bh, acc[i], 0, 0, 0);
                    acc[i] = __builtin_amdgcn_mfma_f32_16x16x32_bf16(ah, bl, acc[i], 0, 0, 0);
                    acc[i] = __builtin_amdgcn_mfma_f32_16x16x32_bf16(al, bh, acc[i], 0, 0, 0);
                }
            }
            __syncthreads();
        }

        // diagonal extraction: wave holds diag tile iff rp - 2*ch in {0,1}
        {
            const int di = rp - 2 * ch;
            if ((di == 0 || di == 1) && lg == (lr >> 2))
                gd[16 * rp + lr] = acc[di][lr & 3];
        }
        __syncthreads();
        if (t < 64) rn[t] = 1.0 / fmax(sqrt((double)gd[t]), 1e-12);
        __syncthreads();

        float* sp = simpart + (size_t)b * 4096;
#pragma unroll
        for (int i = 0; i < 2; ++i)
#pragma unroll
            for (int reg = 0; reg < 4; ++reg) {
                int rc = 16 * rp + 4 * lg + reg;
                int cc = 16 * (2 * ch + i) + lr;
                sp[rc * 64 + cc] = (float)((double)acc[i][reg] * rn[rc] * rn[cc]);
            }
    } else {
        // ---- weight prep (512-thread variant), pblk in 0..11 ----
        float* L = (float*)smem;                   // [64][132]
        const int pblk = blk - 512;
        if (pblk < 8) {
#pragma unroll
            for (int it = 0; it < 4; ++it) {
                int i = t + 512 * it;
                int ri = i >> 5, f4 = i & 31;
                int m = ri >> 3, cr = ri & 7;
                *(float4*)&L[ri * 132 + 4 * f4] =
                    *(const float4*)&W1[(size_t)(64 * m + 8 * pblk + cr) * H_ + 4 * f4];
            }
            __syncthreads();
            int f = t >> 2, q = t & 3;
            uint_ buf[8];
#pragma unroll
            for (int jj = 0; jj < 8; ++jj) {
                int k0 = 16 * q + 2 * jj;
                int c0 = k0 >> 3, m0 = k0 & 7;
                int c1 = (k0 + 1) >> 3, m1 = (k0 + 1) & 7;
                buf[jj] = (uint_)f2bf(L[(m0 * 8 + c0) * 132 + f]) |
                          ((uint_)f2bf(L[(m1 * 8 + c1) * 132 + f]) << 16);
            }
            ushort_* dst = Wt1 + (size_t)f * 512 + 64 * pblk + 16 * q;
            uint4 v0 = {buf[0], buf[1], buf[2], buf[3]};
            uint4 v1 = {buf[4], buf[5], buf[6], buf[7]};
            *(uint4*)&dst[0] = v0;
            *(uint4*)&dst[8] = v1;
        } else {
            const float* W = (pblk < 10) ? W2 : W3;
            ushort_*     O = (pblk < 10) ? Wt2 : Wt3;
            int kb = (pblk - 8) & 1;
#pragma unroll
            for (int it = 0; it < 4; ++it) {
                int i = t + 512 * it;
                int ri = i >> 5, f4 = i & 31;
                *(float4*)&L[ri * 132 + 4 * f4] =
                    *(const float4*)&W[(size_t)(64 * kb + ri) * H_ + 4 * f4];
            }
            __syncthreads();
            int f = t >> 2, q = t & 3;
            uint_ buf[8];
#pragma unroll
            for (int jj = 0; jj < 8; ++jj) {
                int k0 = 16 * q + 2 * jj;
                buf[jj] = (uint_)f2bf(L[k0 * 132 + f]) |
                          ((uint_)f2bf(L[(k0 + 1) * 132 + f]) << 16);
            }
            ushort_* dst = O + (size_t)f * 128 + 64 * kb + 16 * q;
            uint4 v0 = {buf[0], buf[1], buf[2], buf[3]};
            uint4 v1 = {buf[4], buf[5], buf[6], buf[7]};
            *(uint4*)&dst[0] = v0;
            *(uint4*)&dst[8] = v1;
        }
    }
}

// ---------------------------------------------------------------------------
// Kernel 2: fused batch-reduction + rank-select top-K (1024 threads).
// ---------------------------------------------------------------------------
__global__ __launch_bounds__(1024) void k_simrank(const float* __restrict__ simpart,
                                                  ull_* __restrict__ masks)
{
    __shared__ double part[16][64];
    __shared__ double sd[64];
    const int c = blockIdx.x;
    const int t = threadIdx.x;
    const int d = t & 63, g = t >> 6;

    double a = 0.0;
    const float* sp = simpart + (size_t)c * 64 + d;
    for (int i = 0; i < 32; ++i)
        a += (double)sp[(size_t)(g + 16 * i) * 4096];
    part[g][d] = a;
    __syncthreads();

    if (t < 64) {
        double s = 0.0;
#pragma unroll
        for (int q = 0; q < 16; ++q) s += part[q][t];
        sd[t] = s;
        int rank = 0;
#pragma unroll
        for (int dp = 0; dp < 64; ++dp) {
            double w = sd[dp];
            rank += (w > s || (w == s && dp < t)) ? 1 : 0;
        }
        ull_ m = __ballot(rank < 16);
        if (t == 0) masks[c] = m;
    }
}

// ---------------------------------------------------------------------------
// Shared MFMA epilogue: Z = M@Y + bias, BN partials, Z store.
// ---------------------------------------------------------------------------
__device__ __forceinline__ void mfma_epilogue(char* smem, int b, int t,
    f4v acc[8], const float* __restrict__ bias, const uint_ m8[8],
    ushort_* __restrict__ Zout, float* __restrict__ bnpart)
{
    const int l = t & 63, w = t >> 6;
    const int lr = l & 15, lg = l >> 4;

    ushort_* Yt  = (ushort_*)smem;             // [128][88]
    ushort_* Ml  = (ushort_*)(smem + 22528);   // [64][88]
    ushort_* Zst = (ushort_*)(smem + 33792);   // [64][136]

#pragma unroll
    for (int nt = 0; nt < 8; ++nt) {
        uint2 p;
        p.x = (uint_)f2bf(acc[nt][0]) | ((uint_)f2bf(acc[nt][1]) << 16);
        p.y = (uint_)f2bf(acc[nt][2]) | ((uint_)f2bf(acc[nt][3]) << 16);
        *(uint2*)&Yt[(16 * nt + lr) * 88 + 16 * w + 4 * lg] = p;
    }
    {
        const int d = t >> 2, q = t & 3;
        uint4 v0 = {m8[0], m8[1], m8[2], m8[3]};
        uint4 v1 = {m8[4], m8[5], m8[6], m8[7]};
        *(uint4*)&Ml[d * 88 + 16 * q]     = v0;
        *(uint4*)&Ml[d * 88 + 16 * q + 8] = v1;
    }
    __syncthreads();

    f4v z[8];
#pragma unroll
    for (int nt = 0; nt < 8; ++nt) z[nt] = (f4v)0.f;
#pragma unroll
    for (int cs = 0; cs < 2; ++cs) {
        bf8v mf = *(const bf8v*)&Ml[(16 * w + lr) * 88 + 32 * cs + 8 * lg];
#pragma unroll
        for (int nt = 0; nt < 8; ++nt) {
            bf8v yf = *(const bf8v*)&Yt[(16 * nt + lr) * 88 + 32 * cs + 8 * lg];
            z[nt] = __builtin_amdgcn_mfma_f32_16x16x32_bf16(mf, yf, z[nt], 0, 0, 0);
        }
    }

#pragma unroll
    for (int nt = 0; nt < 8; ++nt) {
        float bv = bias[16 * nt + lr];
#pragma unroll
        for (int reg = 0; reg < 4; ++reg)
            Zst[(16 * w + 4 * lg + reg) * 136 + 16 * nt + lr] = f2bf(z[nt][reg] + bv);
    }
    __syncthreads();

    if (t < 128) {
        float s = 0.f, s2 = 0.f;
        for (int r = 0; r < 64; ++r) {
            float v = bf2f(Zst[r * 136 + t]);
            s += v; s2 += v * v;
        }
        bnpart[b * 256 + t]       = s;
        bnpart[b * 256 + 128 + t] = s2;
    }
#pragma unroll
    for (int it = 0; it < 4; ++it) {
        int i = t + 256 * it;
        int r = i >> 4, seg = i & 15;
        *(uint4*)&Zout[((size_t)(b * 64 + r)) * 128 + 8 * seg] =
            *(const uint4*)&Zst[r * 136 + 8 * seg];
    }
}

// ---------------------------------------------------------------------------
// Layer 1: A and W staged via global_load_lds DMA; A = persisted Xh.
// ---------------------------------------------------------------------------
__global__ __launch_bounds__(256) void k_mgemm1(const ushort_* __restrict__ Xh,
    const ushort_* __restrict__ Wt, const float* __restrict__ bias,
    const ull_* __restrict__ masks, ushort_* __restrict__ Zout,
    float* __restrict__ bnpart)
{
    __shared__ __align__(16) char smem[51456];
    __shared__ ull_  nbrmS[64];
    __shared__ float dvS[64];
    ushort_* Al = (ushort_*)smem;              // [16][512] per chunk
    ushort_* Wl = (ushort_*)(smem + 16384);    // [128][128] per chunk

    const int b = blockIdx.x;
    const int t = threadIdx.x;
    const int l = t & 63, w = t >> 6;
    const int lr = l & 15, lg = l >> 4;

    m_preamble_wave0(masks, nbrmS, dvS, t);

    f4v acc[8];
#pragma unroll
    for (int nt = 0; nt < 8; ++nt) acc[nt] = (f4v)0.f;

    for (int j = 0; j < 4; ++j) {
        {
            const char* asrc = (const char*)(Xh + (((size_t)(b * 64 + 16 * j)) << 9)) + t * 16;
            char* adst = smem + t * 16;
#pragma unroll
            for (int i2 = 0; i2 < 4; ++i2)
                gload_lds16(asrc + i2 * 4096, adst + i2 * 4096);
        }
        {
            const int fr = t >> 4, seg = t & 15;
            const char* wsrc = (const char*)(Wt + (size_t)fr * 512 + 128 * j + seg * 8);
            char* wdst = smem + 16384 + t * 16;
#pragma unroll
            for (int i2 = 0; i2 < 8; ++i2)
                gload_lds16(wsrc + i2 * 16384, wdst + i2 * 4096);
        }
        __syncthreads();
#pragma unroll
        for (int s = 0; s < 4; ++s) {
            bf8v af = *(const bf8v*)&Al[(4 * s + lg) * 512 + 128 * w + 8 * lr];
#pragma unroll
            for (int nt = 0; nt < 8; ++nt) {
                bf8v bfv = *(const bf8v*)&Wl[(16 * nt + lr) * 128 + 32 * s + 8 * lg];
                acc[nt] = __builtin_amdgcn_mfma_f32_16x16x32_bf16(af, bfv, acc[nt], 0, 0, 0);
            }
        }
        __syncthreads();
    }

    uint_ m8[8];
    m_build(nbrmS, dvS, t, m8);
    mfma_epilogue(smem, b, t, acc, bias, m8, Zout, bnpart);
}

// ---------------------------------------------------------------------------
// Layers 2/3: inline BN-finalize + inline-M + GEMM; W via global_load_lds.
// ---------------------------------------------------------------------------
__global__ __launch_bounds__(256) void k_mgemm23(const ushort_* __restrict__ Zin,
    const double* __restrict__ bnp2, const float* __restrict__ g,
    const float* __restrict__ be, const ushort_* __restrict__ Wt,
    const float* __restrict__ bias, const ull_* __restrict__ masks,
    ushort_* __restrict__ Zout, float* __restrict__ bnpart)
{
    __shared__ __align__(16) char smem[52224];
    __shared__ float ssL[256];
    __shared__ ull_  nbrmS[64];
    __shared__ float dvS[64];
    ushort_* Al = (ushort_*)smem;              // [64][136]
    ushort_* Wl = (ushort_*)(smem + 17408);    // [128][128]

    const int b = blockIdx.x;
    const int t = threadIdx.x;
    const int l = t & 63, w = t >> 6;
    const int lr = l & 15, lg = l >> 4;

    // --- BN finalize preamble (sums overlay Al region temporarily) ---
    {
        double* sumsL = (double*)smem;
        double a = 0.0;
        for (int q = 0; q < 32; ++q) a += bnp2[(size_t)q * 256 + t];
        sumsL[t] = a;
        m_preamble_wave0(masks, nbrmS, dvS, t);
        __syncthreads();
        if (t < 128) {
            double s = sumsL[t], s2 = sumsL[128 + t];
            double mean = s * (1.0 / 32768.0);
            double var  = s2 * (1.0 / 32768.0) - mean * mean;
            double rstd = 1.0 / sqrt(var + 1e-5);
            float sc = (float)((double)g[t] * rstd);
            ssL[t]       = sc;
            ssL[128 + t] = (float)((double)be[t] - mean * (double)sc);
        }
        __syncthreads();
    }

    // W: linear 32 KB DMA (overlaps the A-staging VALU below)
    {
        const char* wsrc = (const char*)Wt + t * 16;
        char* wdst = smem + 17408 + t * 16;
#pragma unroll
        for (int i2 = 0; i2 < 8; ++i2)
            gload_lds16(wsrc + i2 * 4096, wdst + i2 * 4096);
    }

    f4v acc[8];
#pragma unroll
    for (int nt = 0; nt < 8; ++nt) acc[nt] = (f4v)0.f;

    // stage A with BN fold + relu
#pragma unroll
    for (int it = 0; it < 4; ++it) {
        int i = t + 256 * it;
        int r = i >> 4, seg = i & 15;
        uint4 v = *(const uint4*)&Zin[((size_t)(b * 64 + r)) * 128 + 8 * seg];
        uint_ w0[4] = {v.x, v.y, v.z, v.w};
        uint_ o[4];
#pragma unroll
        for (int p = 0; p < 4; ++p) {
            int f0 = 8 * seg + 2 * p;
            float z0 = bf2f((ushort_)(w0[p] & 0xFFFF));
            float z1 = bf2f((ushort_)(w0[p] >> 16));
            float h0 = fmaxf(fmaf(z0, ssL[f0],     ssL[128 + f0]),     0.f);
            float h1 = fmaxf(fmaf(z1, ssL[f0 + 1], ssL[128 + f0 + 1]), 0.f);
            o[p] = (uint_)f2bf(h0) | ((uint_)f2bf(h1) << 16);
        }
        uint4 ov = {o[0], o[1], o[2], o[3]};
        *(uint4*)&Al[r * 136 + 8 * seg] = ov;
    }
    __syncthreads();
#pragma unroll
    for (int s = 0; s < 4; ++s) {
        bf8v af = *(const bf8v*)&Al[(16 * w + lr) * 136 + 32 * s + 8 * lg];
#pragma unroll
        for (int nt = 0; nt < 8; ++nt) {
            bf8v bfv = *(const bf8v*)&Wl[(16 * nt + lr) * 128 + 32 * s + 8 * lg];
            acc[nt] = __builtin_amdgcn_mfma_f32_16x16x32_bf16(af, bfv, acc[nt], 0, 0, 0);
        }
    }
    __syncthreads();

    uint_ m8[8];
    m_build(nbrmS, dvS, t, m8);
    mfma_epilogue(smem, b, t, acc, bias, m8, Zout, bnpart);
}

// ---------------------------------------------------------------------------
// BN reduce stage A: 32 blocks, 512 -> 32 partials in f64.
// ---------------------------------------------------------------------------
__global__ __launch_bounds__(256) void k_bnA(const float* __restrict__ bnpart,
                                             double* __restrict__ bnp2)
{
    const int t = threadIdx.x, g = blockIdx.x;
    double a = 0.0;
    for (int i = 0; i < 16; ++i)
        a += (double)bnpart[(size_t)(16 * g + i) * 256 + t];
    bnp2[(size_t)g * 256 + t] = a;
}

// ---------------------------------------------------------------------------
// Final BN + ReLU with inline BN-finalize.
// ---------------------------------------------------------------------------
__global__ __launch_bounds__(256) void k_out(const ushort_* __restrict__ Z,
    const double* __restrict__ bnp2, const float* __restrict__ g,
    const float* __restrict__ be, float* __restrict__ out)
{
    __shared__ double sumsL[256];
    __shared__ float  ssL[256];
    const int b = blockIdx.x;
    const int t = threadIdx.x;

    double a = 0.0;
    for (int q = 0; q < 32; ++q) a += bnp2[(size_t)q * 256 + t];
    sumsL[t] = a;
    __syncthreads();
    if (t < 128) {
        double s = sumsL[t], s2 = sumsL[128 + t];
        double mean = s * (1.0 / 32768.0);
        double var  = s2 * (1.0 / 32768.0) - mean * mean;
        double rstd = 1.0 / sqrt(var + 1e-5);
        float sc = (float)((double)g[t] * rstd);
        ssL[t]       = sc;
        ssL[128 + t] = (float)((double)be[t] - mean * (double)sc);
    }
    __syncthreads();

    const size_t base = (size_t)b * 64 * 128;
#pragma unroll
    for (int it = 0; it < 8; ++it) {
        int i = t + 256 * it;
        int r = i >> 5, s = i & 31;
        uint2 v = *(const uint2*)&Z[base + (size_t)r * 128 + 4 * s];
        float4 sc = *(const float4*)&ssL[4 * s];
        float4 sh = *(const float4*)&ssL[128 + 4 * s];
        float z0 = bf2f((ushort_)(v.x & 0xFFFF));
        float z1 = bf2f((ushort_)(v.x >> 16));
        float z2 = bf2f((ushort_)(v.y & 0xFFFF));
        float z3 = bf2f((ushort_)(v.y >> 16));
        float4 o;
        o.x = fmaxf(fmaf(z0, sc.x, sh.x), 0.f);
        o.y = fmaxf(fmaf(z1, sc.y, sh.y), 0.f);
        o.z = fmaxf(fmaf(z2, sc.z, sh.z), 0.f);
        o.w = fmaxf(fmaf(z3, sc.w, sh.w), 0.f);
        *(float4*)&out[base + (size_t)r * 128 + 4 * s] = o;
    }
}

// ---------------------------------------------------------------------------
extern "C" void kernel_launch(void* const* d_in, const int* in_sizes, int n_in,
                              void* d_out, int out_size, void* d_ws, size_t ws_size,
                              hipStream_t stream)
{
    (void)in_sizes; (void)n_in; (void)out_size; (void)ws_size;

    const float* x   = (const float*)d_in[0];
    const float* W1  = (const float*)d_in[9];
    const float* b1  = (const float*)d_in[10];
    const float* g1  = (const float*)d_in[11];
    const float* be1 = (const float*)d_in[12];
    const float* W2  = (const float*)d_in[13];
    const float* b2  = (const float*)d_in[14];
    const float* g2  = (const float*)d_in[15];
    const float* be2 = (const float*)d_in[16];
    const float* W3  = (const float*)d_in[17];
    const float* b3  = (const float*)d_in[18];
    const float* g3  = (const float*)d_in[19];
    const float* be3 = (const float*)d_in[20];

    char* ws = (char*)d_ws;
    float*   simp   = (float*)(ws + OFF_SIMP);
    ull_*    masks  = (ull_*)(ws + OFF_MASKS);
    ushort_* Wt1    = (ushort_*)(ws + OFF_WT1);
    ushort_* Wt2    = (ushort_*)(ws + OFF_WT2);
    ushort_* Wt3    = (ushort_*)(ws + OFF_WT3);
    float*   bnpart = (float*)(ws + OFF_BNPART);
    double*  bnp2   = (double*)(ws + OFF_BNP2);
    ushort_* Xh     = (ushort_*)(ws + OFF_XH);
    ushort_* Z1     = (ushort_*)(ws + OFF_Z1);
    ushort_* Z2     = (ushort_*)(ws + OFF_Z2);   // reuses simp region
    ushort_* Z3     = (ushort_*)(ws + OFF_Z3);
    float*   out    = (float*)d_out;

    k_gramw<<<dim3(524), dim3(512), 0, stream>>>(x, simp, Xh, W1, W2, W3, Wt1, Wt2, Wt3);
    k_simrank<<<dim3(64), dim3(1024), 0, stream>>>(simp, masks);

    k_mgemm1<<<dim3(512), dim3(256), 0, stream>>>(Xh, Wt1, b1, masks, Z1, bnpart);
    k_bnA<<<dim3(32), dim3(256), 0, stream>>>(bnpart, bnp2);

    k_mgemm23<<<dim3(512), dim3(256), 0, stream>>>(Z1, bnp2, g1, be1, Wt2, b2, masks, Z2, bnpart);
    k_bnA<<<dim3(32), dim3(256), 0, stream>>>(bnpart, bnp2);

    k_mgemm23<<<dim3(512), dim3(256), 0, stream>>>(Z2, bnp2, g2, be2, Wt3, b3, masks, Z3, bnpart);
    k_bnA<<<dim3(32), dim3(256), 0, stream>>>(bnpart, bnp2);

    k_out<<<dim3(512), dim3(256), 0, stream>>>(Z3, bnp2, g3, be3, out);
}